// Round 1
// baseline (1836.017 us; speedup 1.0000x reference)
//
#include <hip/hip_runtime.h>
#include <math.h>

#define DD 1024
#define TT 2048
#define BB 4
#define HH 4
#define HDIM 256
#define NLAYER 2
#define MM (BB*TT)          // 8192 rows
#define NCHUNK 32
#define CHUNK (TT/NCHUNK)   // 64

typedef unsigned short u16;
typedef __bf16 bf16x8 __attribute__((ext_vector_type(8)));
typedef float f32x4 __attribute__((ext_vector_type(4)));

__device__ __forceinline__ float b2f(u16 h) {
  unsigned u = ((unsigned)h) << 16;
  return __builtin_bit_cast(float, u);
}
__device__ __forceinline__ u16 f2b(float f) {
  unsigned u = __builtin_bit_cast(unsigned, f);
  u += 0x7fffu + ((u >> 16) & 1u);
  return (u16)(u >> 16);
}
__device__ __forceinline__ float blo(unsigned u) { return __builtin_bit_cast(float, u << 16); }
__device__ __forceinline__ float bhi(unsigned u) { return __builtin_bit_cast(float, u & 0xffff0000u); }

#define GLD16(g, l) __builtin_amdgcn_global_load_lds( \
    (__attribute__((address_space(1))) void*)(void*)(g), \
    (__attribute__((address_space(3))) void*)(l), 16, 0, 0)

// ---------------- weight fp32 -> bf16 transpose: Wt[N][K] = W[K][N] ----------------
__global__ __launch_bounds__(256)
void transpose_cvt(const float* __restrict__ W, u16* __restrict__ Wt, int K, int N) {
  __shared__ float tile[32][33];
  const int n0 = blockIdx.x << 5, k0 = blockIdx.y << 5;
  const int tx = threadIdx.x, ty = threadIdx.y;
#pragma unroll
  for (int i = 0; i < 4; ++i)
    tile[ty + i*8][tx] = W[(size_t)(k0 + ty + i*8) * N + n0 + tx];
  __syncthreads();
#pragma unroll
  for (int i = 0; i < 4; ++i)
    Wt[(size_t)(n0 + ty + i*8) * K + k0 + tx] = f2b(tile[tx][ty + i*8]);
}

// ---------------- LayerNorm (fp32 in, bf16 out) ----------------
__global__ __launch_bounds__(256)
void ln_k(const float* __restrict__ x, const float* __restrict__ sc,
          const float* __restrict__ bi, u16* __restrict__ xn) {
  const int row = blockIdx.x;
  const int tid = threadIdx.x;
  const float4 xv = ((const float4*)(x + (size_t)row * DD))[tid];
  float s = xv.x + xv.y + xv.z + xv.w;
  float q = xv.x*xv.x + xv.y*xv.y + xv.z*xv.z + xv.w*xv.w;
#pragma unroll
  for (int o = 1; o < 64; o <<= 1) { s += __shfl_xor(s, o); q += __shfl_xor(q, o); }
  __shared__ float rs[4], rq[4];
  if ((tid & 63) == 0) { rs[tid >> 6] = s; rq[tid >> 6] = q; }
  __syncthreads();
  s = rs[0] + rs[1] + rs[2] + rs[3];
  q = rq[0] + rq[1] + rq[2] + rq[3];
  const float mean = s * (1.f / DD);
  const float var = q * (1.f / DD) - mean * mean;
  const float rstd = rsqrtf(var + 1e-5f);
  const float4 sv = ((const float4*)sc)[tid];
  const float4 bv = ((const float4*)bi)[tid];
  const u16 o0 = f2b((xv.x - mean) * rstd * sv.x + bv.x);
  const u16 o1 = f2b((xv.y - mean) * rstd * sv.y + bv.y);
  const u16 o2 = f2b((xv.z - mean) * rstd * sv.z + bv.z);
  const u16 o3 = f2b((xv.w - mean) * rstd * sv.w + bv.w);
  uint2 pk;
  pk.x = (unsigned)o0 | ((unsigned)o1 << 16);
  pk.y = (unsigned)o2 | ((unsigned)o3 << 16);
  *(uint2*)(xn + (size_t)row * DD + (tid << 2)) = pk;
}

// ---------------- bf16 MFMA GEMM: C[M,N] = A[M,K] * Wt[N,K]^T + bias ----------------
// EPI: 0 = f32 store, 1 = bf16 store, 2 = bf16 gelu store, 3 = f32 residual add (out += v)
template<int EPI>
__global__ __launch_bounds__(256)
void gemm_k(const u16* __restrict__ A, const u16* __restrict__ Wt,
            const float* __restrict__ bias, float* __restrict__ outf,
            u16* __restrict__ outb, int K, int N) {
  __shared__ u16 As[4096];   // [128][32]
  __shared__ u16 Bs[4096];   // [128][32]
  const int tid = threadIdx.x;
  const int m0 = blockIdx.y << 7;
  const int n0 = blockIdx.x << 7;
  const int lane = tid & 63;
  const int wm = (tid >> 7) & 1;
  const int wn = (tid >> 6) & 1;
  const int kr = (lane >> 4) << 3;
  const int arow = (wm << 6) + (lane & 15);
  const int brow = (wn << 6) + (lane & 15);
  const u16* Ag = A + (size_t)(m0 + (tid >> 2)) * K + ((tid & 3) << 3);
  const u16* Bg = Wt + (size_t)(n0 + (tid >> 2)) * K + ((tid & 3) << 3);
  f32x4 acc[4][4];
#pragma unroll
  for (int i = 0; i < 4; ++i)
#pragma unroll
    for (int j = 0; j < 4; ++j)
#pragma unroll
      for (int e = 0; e < 4; ++e) acc[i][j][e] = 0.f;

  for (int k0 = 0; k0 < K; k0 += 32) {
    GLD16(Ag,                 As + tid * 8);
    GLD16(Ag + (size_t)64*K,  As + 2048 + tid * 8);
    GLD16(Bg,                 Bs + tid * 8);
    GLD16(Bg + (size_t)64*K,  Bs + 2048 + tid * 8);
    Ag += 32; Bg += 32;
    __syncthreads();
    bf16x8 af[4], bfr[4];
#pragma unroll
    for (int mi = 0; mi < 4; ++mi)
      af[mi] = *(const bf16x8*)(As + ((arow + mi*16) << 5) + kr);
#pragma unroll
    for (int ni = 0; ni < 4; ++ni)
      bfr[ni] = *(const bf16x8*)(Bs + ((brow + ni*16) << 5) + kr);
#pragma unroll
    for (int mi = 0; mi < 4; ++mi)
#pragma unroll
      for (int ni = 0; ni < 4; ++ni)
        acc[mi][ni] = __builtin_amdgcn_mfma_f32_16x16x32_bf16(af[mi], bfr[ni], acc[mi][ni], 0, 0, 0);
    __syncthreads();
  }

#pragma unroll
  for (int mi = 0; mi < 4; ++mi) {
#pragma unroll
    for (int ni = 0; ni < 4; ++ni) {
      const int n = n0 + (wn << 6) + ni*16 + (lane & 15);
      const float bia = bias[n];
#pragma unroll
      for (int e = 0; e < 4; ++e) {
        const int m = m0 + (wm << 6) + mi*16 + ((lane >> 4) << 2) + e;
        float v = acc[mi][ni][e] + bia;
        const size_t idx = (size_t)m * N + n;
        if (EPI == 0) outf[idx] = v;
        else if (EPI == 1) outb[idx] = f2b(v);
        else if (EPI == 2) outb[idx] = f2b(0.5f * v * (1.f + erff(v * 0.70710678118654752f)));
        else outf[idx] += v;
      }
    }
  }
}

// ---------------- RG-LRU chunked scan: h_t = g*h_{t-1} + (1-g)*u ----------------
__global__ __launch_bounds__(256)
void scan1_k(const float* __restrict__ gpre, const float* __restrict__ u,
             float* __restrict__ aggA, float* __restrict__ aggB) {
  const int d = blockIdx.x * 256 + threadIdx.x;
  const int c = blockIdx.y, b = blockIdx.z;
  const size_t base = ((size_t)b * TT + (size_t)c * CHUNK) * DD + d;
  float a = 1.f, acc = 0.f;
  for (int t = 0; t < CHUNK; ++t) {
    const float gl = 1.f / (1.f + __expf(-gpre[base + (size_t)t * DD]));
    const float ul = u[base + (size_t)t * DD];
    acc = gl * acc + (1.f - gl) * ul;
    a *= gl;
  }
  const size_t o = ((size_t)b * NCHUNK + c) * DD + d;
  aggA[o] = a; aggB[o] = acc;
}

__global__ __launch_bounds__(256)
void scan2_k(const float* __restrict__ aggA, const float* __restrict__ aggB,
             float* __restrict__ carry) {
  const int idx = blockIdx.x * 256 + threadIdx.x;  // b*DD + d
  const int b = idx >> 10, d = idx & 1023;
  float h = 0.f;
  for (int c = 0; c < NCHUNK; ++c) {
    const size_t o = ((size_t)b * NCHUNK + c) * DD + d;
    carry[o] = h;
    h = aggA[o] * h + aggB[o];
  }
}

__global__ __launch_bounds__(256)
void scan3_k(const float* __restrict__ gpre, const float* __restrict__ u,
             const float* __restrict__ carry, u16* __restrict__ hout) {
  const int d = blockIdx.x * 256 + threadIdx.x;
  const int c = blockIdx.y, b = blockIdx.z;
  const size_t base = ((size_t)b * TT + (size_t)c * CHUNK) * DD + d;
  float h = carry[((size_t)b * NCHUNK + c) * DD + d];
  for (int t = 0; t < CHUNK; ++t) {
    const float gl = 1.f / (1.f + __expf(-gpre[base + (size_t)t * DD]));
    const float ul = u[base + (size_t)t * DD];
    h = gl * h + (1.f - gl) * ul;
    hout[base + (size_t)t * DD] = f2b(h);
  }
}

// ---------------- local causal window attention (WIN=128) ----------------
// qkv: [B*T][3072] bf16, layout [q(h*256) | k | v]; y: [B*T][1024] bf16
__global__ __launch_bounds__(256)
void attn_k(const u16* __restrict__ qkv, u16* __restrict__ y) {
  const int tid = threadIdx.x;
  const int wid = tid >> 6, lane = tid & 63;
  const int t = blockIdx.x * 4 + wid;
  const int b = blockIdx.y >> 2;
  const int h = blockIdx.y & 3;
  __shared__ float qs[4][256];
  __shared__ float ps[4][128];
#pragma unroll
  for (int i = 0; i < 4; ++i) {
    const int idx = tid + (i << 8);
    const int qi = idx >> 8, ddim = idx & 255;
    qs[qi][ddim] = b2f(qkv[((size_t)(b * TT + blockIdx.x * 4 + qi)) * 3072 + h * 256 + ddim]);
  }
  __syncthreads();
  const int j0 = t - 127 + lane;
  const int j1 = j0 + 64;
  const uint4* k0p = (const uint4*)(qkv + ((size_t)(b * TT + (j0 < 0 ? 0 : j0))) * 3072 + 1024 + h * 256);
  const uint4* k1p = (const uint4*)(qkv + ((size_t)(b * TT + (j1 < 0 ? 0 : j1))) * 3072 + 1024 + h * 256);
  float s0 = 0.f, s1 = 0.f;
#pragma unroll 4
  for (int i = 0; i < 32; ++i) {
    const uint4 ka = k0p[i];
    const uint4 kb = k1p[i];
    const float* qp = &qs[wid][i * 8];
    s0 += qp[0]*blo(ka.x) + qp[1]*bhi(ka.x) + qp[2]*blo(ka.y) + qp[3]*bhi(ka.y)
        + qp[4]*blo(ka.z) + qp[5]*bhi(ka.z) + qp[6]*blo(ka.w) + qp[7]*bhi(ka.w);
    s1 += qp[0]*blo(kb.x) + qp[1]*bhi(kb.x) + qp[2]*blo(kb.y) + qp[3]*bhi(kb.y)
        + qp[4]*blo(kb.z) + qp[5]*bhi(kb.z) + qp[6]*blo(kb.w) + qp[7]*bhi(kb.w);
  }
  s0 = (j0 >= 0) ? s0 * 0.0625f : -1e30f;
  s1 = (j1 >= 0) ? s1 * 0.0625f : -1e30f;
  float mx = fmaxf(s0, s1);
#pragma unroll
  for (int o = 1; o < 64; o <<= 1) mx = fmaxf(mx, __shfl_xor(mx, o));
  const float p0 = __expf(s0 - mx), p1 = __expf(s1 - mx);
  float sm = p0 + p1;
#pragma unroll
  for (int o = 1; o < 64; o <<= 1) sm += __shfl_xor(sm, o);
  const float inv = 1.f / sm;
  ps[wid][lane] = p0 * inv;
  ps[wid][lane + 64] = p1 * inv;
  __syncthreads();
  const int d0 = lane << 2;
  const u16* vbase = qkv + 2048 + h * 256 + d0;
  float y0 = 0.f, y1 = 0.f, y2 = 0.f, y3 = 0.f;
#pragma unroll 8
  for (int jj = 0; jj < 128; ++jj) {
    const int j = t - 127 + jj;
    const float p = ps[wid][jj];
    const uint2 vv = *(const uint2*)(vbase + ((size_t)(b * TT + (j < 0 ? 0 : j))) * 3072);
    y0 += p * blo(vv.x); y1 += p * bhi(vv.x);
    y2 += p * blo(vv.y); y3 += p * bhi(vv.y);
  }
  uint2 pk;
  pk.x = (unsigned)f2b(y0) | ((unsigned)f2b(y1) << 16);
  pk.y = (unsigned)f2b(y2) | ((unsigned)f2b(y3) << 16);
  *(uint2*)(y + ((size_t)(b * TT + t)) * 1024 + h * 256 + d0) = pk;
}

// ---------------- host orchestration ----------------
extern "C" void kernel_launch(void* const* d_in, const int* in_sizes, int n_in,
                              void* d_out, int out_size, void* d_ws, size_t ws_size,
                              hipStream_t stream) {
  const float* x_in      = (const float*)d_in[0];
  const float* ln1_s     = (const float*)d_in[1];
  const float* ln1_b     = (const float*)d_in[2];
  const float* ln2_s     = (const float*)d_in[3];
  const float* ln2_b     = (const float*)d_in[4];
  const float* ln3_s     = (const float*)d_in[5];
  const float* ln3_b     = (const float*)d_in[6];
  const float* rg_in_w   = (const float*)d_in[7];
  const float* rg_in_b   = (const float*)d_in[8];
  const float* rg_gate_w = (const float*)d_in[9];
  const float* rg_gate_b = (const float*)d_in[10];
  const float* rg_out_w  = (const float*)d_in[11];
  const float* rg_out_b  = (const float*)d_in[12];
  const float* qkv_w     = (const float*)d_in[13];
  const float* qkv_b     = (const float*)d_in[14];
  const float* attn_out_w= (const float*)d_in[15];
  const float* attn_out_b= (const float*)d_in[16];
  const float* mlp_w1    = (const float*)d_in[17];
  const float* mlp_b1    = (const float*)d_in[18];
  const float* mlp_w2    = (const float*)d_in[19];
  const float* mlp_b2    = (const float*)d_in[20];

  float* x = (float*)d_out;
  char* ws = (char*)d_ws;
  // workspace layout (bytes)
  u16*  wt     = (u16*)ws;                          // 62,914,560 (bf16 transposed weights)
  u16*  xn     = (u16*)(ws + 62914560);             // 16,777,216
  char* bigS   = ws + 62914560 + 16777216;          // 67,108,864
  char* smallS = bigS + 67108864;                   // 16,777,216
  float* aggA  = (float*)(smallS + 16777216);       // 3 * 524,288
  float* aggB  = aggA + (size_t)BB * NCHUNK * DD;
  float* carry = aggB + (size_t)BB * NCHUNK * DD;

  float* ubuf = (float*)bigS;
  float* gbuf = (float*)(bigS + 33554432);
  u16* qkvb = (u16*)bigS;
  u16* hid  = (u16*)bigS;
  u16* hbuf = (u16*)smallS;
  u16* ybuf = (u16*)smallS;

  hipMemcpyAsync(x, x_in, (size_t)MM * DD * sizeof(float), hipMemcpyDeviceToDevice, stream);

  const size_t LW = 15728640;  // bf16 elements of transposed weights per layer
  const dim3 tb(32, 8);
  for (int l = 0; l < NLAYER; ++l) {
    u16* base = wt + (size_t)l * LW;
    transpose_cvt<<<dim3(32, 32),  tb, 0, stream>>>(rg_in_w   + (size_t)l*DD*DD,   base + 0,        DD, DD);
    transpose_cvt<<<dim3(32, 32),  tb, 0, stream>>>(rg_gate_w + (size_t)l*DD*DD,   base + 1048576,  DD, DD);
    transpose_cvt<<<dim3(32, 32),  tb, 0, stream>>>(rg_out_w  + (size_t)l*DD*DD,   base + 2097152,  DD, DD);
    transpose_cvt<<<dim3(96, 32),  tb, 0, stream>>>(qkv_w     + (size_t)l*DD*3072, base + 3145728,  DD, 3072);
    transpose_cvt<<<dim3(32, 32),  tb, 0, stream>>>(attn_out_w+ (size_t)l*DD*DD,   base + 6291456,  DD, DD);
    transpose_cvt<<<dim3(128, 32), tb, 0, stream>>>(mlp_w1    + (size_t)l*DD*4096, base + 7340032,  DD, 4096);
    transpose_cvt<<<dim3(32, 128), tb, 0, stream>>>(mlp_w2    + (size_t)l*4096*DD, base + 11534336, 4096, DD);
  }

  for (int l = 0; l < NLAYER; ++l) {
    u16* base = wt + (size_t)l * LW;
    // ---- RG-LRU block
    ln_k<<<MM, 256, 0, stream>>>(x, ln1_s + l*DD, ln1_b + l*DD, xn);
    gemm_k<0><<<dim3(8, 64), 256, 0, stream>>>(xn, base + 0,       rg_in_b   + l*DD, ubuf, nullptr, DD, DD);
    gemm_k<0><<<dim3(8, 64), 256, 0, stream>>>(xn, base + 1048576, rg_gate_b + l*DD, gbuf, nullptr, DD, DD);
    scan1_k<<<dim3(4, NCHUNK, BB), 256, 0, stream>>>(gbuf, ubuf, aggA, aggB);
    scan2_k<<<16, 256, 0, stream>>>(aggA, aggB, carry);
    scan3_k<<<dim3(4, NCHUNK, BB), 256, 0, stream>>>(gbuf, ubuf, carry, hbuf);
    gemm_k<3><<<dim3(8, 64), 256, 0, stream>>>(hbuf, base + 2097152, rg_out_b + l*DD, x, nullptr, DD, DD);
    // ---- local attention block
    ln_k<<<MM, 256, 0, stream>>>(x, ln2_s + l*DD, ln2_b + l*DD, xn);
    gemm_k<1><<<dim3(24, 64), 256, 0, stream>>>(xn, base + 3145728, qkv_b + l*3072, nullptr, qkvb, DD, 3072);
    attn_k<<<dim3(TT/4, BB*HH), 256, 0, stream>>>(qkvb, ybuf);
    gemm_k<3><<<dim3(8, 64), 256, 0, stream>>>(ybuf, base + 6291456, attn_out_b + l*DD, x, nullptr, DD, DD);
    // ---- MLP block
    ln_k<<<MM, 256, 0, stream>>>(x, ln3_s + l*DD, ln3_b + l*DD, xn);
    gemm_k<2><<<dim3(32, 64), 256, 0, stream>>>(xn, base + 7340032, mlp_b1 + l*4096, nullptr, hid, DD, 4096);
    gemm_k<3><<<dim3(8, 64), 256, 0, stream>>>(hid, base + 11534336, mlp_b2 + l*DD, x, nullptr, 4096, DD);
  }
}

// Round 2
// 1203.193 us; speedup vs baseline: 1.5260x; 1.5260x over previous
//
#include <hip/hip_runtime.h>
#include <math.h>

#define DD 1024
#define TT 2048
#define BB 4
#define HH 4
#define HDIM 256
#define NLAYER 2
#define MM (BB*TT)          // 8192 rows
#define NCHUNK 32
#define CHUNK (TT/NCHUNK)   // 64

typedef unsigned short u16;
typedef __bf16 bf16x8 __attribute__((ext_vector_type(8)));
typedef float f32x4 __attribute__((ext_vector_type(4)));

__device__ __forceinline__ float b2f(u16 h) {
  unsigned u = ((unsigned)h) << 16;
  return __builtin_bit_cast(float, u);
}
__device__ __forceinline__ u16 f2b(float f) {
  unsigned u = __builtin_bit_cast(unsigned, f);
  u += 0x7fffu + ((u >> 16) & 1u);
  return (u16)(u >> 16);
}
__device__ __forceinline__ float blo(unsigned u) { return __builtin_bit_cast(float, u << 16); }
__device__ __forceinline__ float bhi(unsigned u) { return __builtin_bit_cast(float, u & 0xffff0000u); }

#define GLD16(g, l) __builtin_amdgcn_global_load_lds( \
    (__attribute__((address_space(1))) void*)(void*)(g), \
    (__attribute__((address_space(3))) void*)(l), 16, 0, 0)

// ---------------- weight fp32 -> bf16 transpose: Wt[N][K] = W[K][N] ----------------
__global__ __launch_bounds__(256)
void transpose_cvt(const float* __restrict__ W, u16* __restrict__ Wt, int K, int N) {
  __shared__ float tile[32][33];
  const int n0 = blockIdx.x << 5, k0 = blockIdx.y << 5;
  const int tx = threadIdx.x, ty = threadIdx.y;
#pragma unroll
  for (int i = 0; i < 4; ++i)
    tile[ty + i*8][tx] = W[(size_t)(k0 + ty + i*8) * N + n0 + tx];
  __syncthreads();
#pragma unroll
  for (int i = 0; i < 4; ++i)
    Wt[(size_t)(n0 + ty + i*8) * K + k0 + tx] = f2b(tile[tx][ty + i*8]);
}

// ---------------- LayerNorm (fp32 in, bf16 out) ----------------
__global__ __launch_bounds__(256)
void ln_k(const float* __restrict__ x, const float* __restrict__ sc,
          const float* __restrict__ bi, u16* __restrict__ xn) {
  const int row = blockIdx.x;
  const int tid = threadIdx.x;
  const float4 xv = ((const float4*)(x + (size_t)row * DD))[tid];
  float s = xv.x + xv.y + xv.z + xv.w;
  float q = xv.x*xv.x + xv.y*xv.y + xv.z*xv.z + xv.w*xv.w;
#pragma unroll
  for (int o = 1; o < 64; o <<= 1) { s += __shfl_xor(s, o); q += __shfl_xor(q, o); }
  __shared__ float rs[4], rq[4];
  if ((tid & 63) == 0) { rs[tid >> 6] = s; rq[tid >> 6] = q; }
  __syncthreads();
  s = rs[0] + rs[1] + rs[2] + rs[3];
  q = rq[0] + rq[1] + rq[2] + rq[3];
  const float mean = s * (1.f / DD);
  const float var = q * (1.f / DD) - mean * mean;
  const float rstd = rsqrtf(var + 1e-5f);
  const float4 sv = ((const float4*)sc)[tid];
  const float4 bv = ((const float4*)bi)[tid];
  const u16 o0 = f2b((xv.x - mean) * rstd * sv.x + bv.x);
  const u16 o1 = f2b((xv.y - mean) * rstd * sv.y + bv.y);
  const u16 o2 = f2b((xv.z - mean) * rstd * sv.z + bv.z);
  const u16 o3 = f2b((xv.w - mean) * rstd * sv.w + bv.w);
  uint2 pk;
  pk.x = (unsigned)o0 | ((unsigned)o1 << 16);
  pk.y = (unsigned)o2 | ((unsigned)o3 << 16);
  *(uint2*)(xn + (size_t)row * DD + (tid << 2)) = pk;
}

// ---------------- bf16 MFMA GEMM: C[M,N] = A[M,K] * Wt[N,K]^T + bias ----------------
// EPI: 0 = f32 store, 2 = bf16 gelu store, 3 = f32 residual add, 4 = qkv split (QK rowmajor + V transposed)
template<int EPI>
__global__ __launch_bounds__(256)
void gemm_k(const u16* __restrict__ A, const u16* __restrict__ Wt,
            const float* __restrict__ bias, float* __restrict__ outf,
            u16* __restrict__ outb, int K, int N) {
  __shared__ u16 As[4096];   // [128][32]
  __shared__ u16 Bs[4096];   // [128][32]
  const int tid = threadIdx.x;
  const int m0 = blockIdx.y << 7;
  const int n0 = blockIdx.x << 7;
  const int lane = tid & 63;
  const int wm = (tid >> 7) & 1;
  const int wn = (tid >> 6) & 1;
  const int kr = (lane >> 4) << 3;
  const int arow = (wm << 6) + (lane & 15);
  const int brow = (wn << 6) + (lane & 15);
  const u16* Ag = A + (size_t)(m0 + (tid >> 2)) * K + ((tid & 3) << 3);
  const u16* Bg = Wt + (size_t)(n0 + (tid >> 2)) * K + ((tid & 3) << 3);
  f32x4 acc[4][4];
#pragma unroll
  for (int i = 0; i < 4; ++i)
#pragma unroll
    for (int j = 0; j < 4; ++j)
#pragma unroll
      for (int e = 0; e < 4; ++e) acc[i][j][e] = 0.f;

  for (int k0 = 0; k0 < K; k0 += 32) {
    GLD16(Ag,                 As + tid * 8);
    GLD16(Ag + (size_t)64*K,  As + 2048 + tid * 8);
    GLD16(Bg,                 Bs + tid * 8);
    GLD16(Bg + (size_t)64*K,  Bs + 2048 + tid * 8);
    Ag += 32; Bg += 32;
    __syncthreads();
    bf16x8 af[4], bfr[4];
#pragma unroll
    for (int mi = 0; mi < 4; ++mi)
      af[mi] = *(const bf16x8*)(As + ((arow + mi*16) << 5) + kr);
#pragma unroll
    for (int ni = 0; ni < 4; ++ni)
      bfr[ni] = *(const bf16x8*)(Bs + ((brow + ni*16) << 5) + kr);
#pragma unroll
    for (int mi = 0; mi < 4; ++mi)
#pragma unroll
      for (int ni = 0; ni < 4; ++ni)
        acc[mi][ni] = __builtin_amdgcn_mfma_f32_16x16x32_bf16(af[mi], bfr[ni], acc[mi][ni], 0, 0, 0);
    __syncthreads();
  }

#pragma unroll
  for (int mi = 0; mi < 4; ++mi) {
#pragma unroll
    for (int ni = 0; ni < 4; ++ni) {
      const int n = n0 + (wn << 6) + ni*16 + (lane & 15);
      const float bia = bias[n];
      if (EPI == 4) {
        const int mbase = m0 + (wm << 6) + mi*16 + ((lane >> 4) << 2);
        if (n < 2048) {
#pragma unroll
          for (int e = 0; e < 4; ++e)
            outb[(size_t)(mbase + e) * 2048 + n] = f2b(acc[mi][ni][e] + bia);
        } else {
          const int hh = (n - 2048) >> 8, dim = (n - 2048) & 255;
          const int bidx = mbase >> 11, t = mbase & 2047;
          const u16 a0 = f2b(acc[mi][ni][0] + bia);
          const u16 a1 = f2b(acc[mi][ni][1] + bia);
          const u16 a2 = f2b(acc[mi][ni][2] + bia);
          const u16 a3 = f2b(acc[mi][ni][3] + bia);
          uint2 pk;
          pk.x = (unsigned)a0 | ((unsigned)a1 << 16);
          pk.y = (unsigned)a2 | ((unsigned)a3 << 16);
          u16* vtp = (u16*)outf;
          *(uint2*)(vtp + ((size_t)((bidx*4 + hh)*256 + dim)) * 2048 + t) = pk;
        }
      } else {
#pragma unroll
        for (int e = 0; e < 4; ++e) {
          const int m = m0 + (wm << 6) + mi*16 + ((lane >> 4) << 2) + e;
          float v = acc[mi][ni][e] + bia;
          const size_t idx = (size_t)m * N + n;
          if (EPI == 0) outf[idx] = v;
          else if (EPI == 2) outb[idx] = f2b(0.5f * v * (1.f + erff(v * 0.70710678118654752f)));
          else outf[idx] += v;
        }
      }
    }
  }
}

// ---------------- RG-LRU chunked scan: h_t = g*h_{t-1} + (1-g)*u ----------------
__global__ __launch_bounds__(256)
void scan1_k(const float* __restrict__ gpre, const float* __restrict__ u,
             float* __restrict__ aggA, float* __restrict__ aggB) {
  const int d = blockIdx.x * 256 + threadIdx.x;
  const int c = blockIdx.y, b = blockIdx.z;
  const size_t base = ((size_t)b * TT + (size_t)c * CHUNK) * DD + d;
  float a = 1.f, acc = 0.f;
  for (int t = 0; t < CHUNK; ++t) {
    const float gl = 1.f / (1.f + __expf(-gpre[base + (size_t)t * DD]));
    const float ul = u[base + (size_t)t * DD];
    acc = gl * acc + (1.f - gl) * ul;
    a *= gl;
  }
  const size_t o = ((size_t)b * NCHUNK + c) * DD + d;
  aggA[o] = a; aggB[o] = acc;
}

__global__ __launch_bounds__(256)
void scan2_k(const float* __restrict__ aggA, const float* __restrict__ aggB,
             float* __restrict__ carry) {
  const int idx = blockIdx.x * 256 + threadIdx.x;  // b*DD + d
  const int b = idx >> 10, d = idx & 1023;
  float h = 0.f;
  for (int c = 0; c < NCHUNK; ++c) {
    const size_t o = ((size_t)b * NCHUNK + c) * DD + d;
    carry[o] = h;
    h = aggA[o] * h + aggB[o];
  }
}

__global__ __launch_bounds__(256)
void scan3_k(const float* __restrict__ gpre, const float* __restrict__ u,
             const float* __restrict__ carry, u16* __restrict__ hout) {
  const int d = blockIdx.x * 256 + threadIdx.x;
  const int c = blockIdx.y, b = blockIdx.z;
  const size_t base = ((size_t)b * TT + (size_t)c * CHUNK) * DD + d;
  float h = carry[((size_t)b * NCHUNK + c) * DD + d];
  for (int t = 0; t < CHUNK; ++t) {
    const float gl = 1.f / (1.f + __expf(-gpre[base + (size_t)t * DD]));
    const float ul = u[base + (size_t)t * DD];
    h = gl * h + (1.f - gl) * ul;
    hout[base + (size_t)t * DD] = f2b(h);
  }
}

// ---------------- MFMA local-window attention ----------------
// qkb: [B*T][2048] bf16 (Q | K per token); vt: [(b*H+h)*256+dim][2048] bf16 (V transposed)
// y: [B*T][1024] bf16. Block = 64-query tile for one (b,h). Grid (T/64, B*H).
__global__ __launch_bounds__(256)
void attn_mfma(const u16* __restrict__ qkb, const u16* __restrict__ vt,
               u16* __restrict__ y) {
  __shared__ u16 kv[16384];        // 32KB chunk buffer (K slabs or swizzled V)
  __shared__ u16 pb[4][16][200];   // per-wave P, padded stride 200
  const int tid = threadIdx.x;
  const int lane = tid & 63;
  const int wid = tid >> 6;
  const int g = lane >> 4;
  const int lc = lane & 15;
  const int t0 = blockIdx.x << 6;
  const int bh = blockIdx.y;
  const int bT = (bh >> 2) * TT;
  const int h = bh & 3;

  // Q fragments: rows t0+wid*16+lc, dims ks*32+g*8..+8
  bf16x8 afq[8];
  {
    const u16* qg = qkb + (size_t)(bT + t0 + wid*16 + lc) * 2048 + h*256 + g*8;
#pragma unroll
    for (int ks = 0; ks < 8; ++ks)
      afq[ks] = __builtin_bit_cast(bf16x8, *(const uint4*)(qg + ks*32));
  }

  f32x4 sc[12];
#pragma unroll
  for (int f = 0; f < 12; ++f)
#pragma unroll
    for (int e = 0; e < 4; ++e) sc[f][e] = 0.f;

  const int koff = 1024 + h*256;
#pragma unroll
  for (int c = 0; c < 3; ++c) {
    const int j0 = t0 + (c - 2) * 64;
    if (j0 < 0) {
#pragma unroll
      for (int nt = 0; nt < 4; ++nt)
#pragma unroll
        for (int e = 0; e < 4; ++e) sc[c*4+nt][e] = -1e30f;
      continue;
    }
    __syncthreads();
    {  // stage K chunk: [8 slabs][64 keys][32 dims]
      const u16* kg = qkb + (size_t)(bT + j0) * 2048 + koff;
#pragma unroll
      for (int i = 0; i < 8; ++i) {
        const int o16 = i*256 + tid;
        const int slab = o16 >> 8, key = (o16 >> 2) & 63, ds = o16 & 3;
        GLD16(kg + (size_t)key*2048 + slab*32 + ds*8, kv + o16*8);
      }
    }
    __syncthreads();
#pragma unroll
    for (int nt = 0; nt < 4; ++nt) {
      f32x4 s = sc[c*4+nt];
#pragma unroll
      for (int ks = 0; ks < 8; ++ks) {
        const bf16x8 kb = *(const bf16x8*)(kv + ks*2048 + (nt*16 + lc)*32 + g*8);
        s = __builtin_amdgcn_mfma_f32_16x16x32_bf16(afq[ks], kb, s, 0, 0, 0);
      }
      sc[c*4+nt] = s;
    }
#pragma unroll
    for (int nt = 0; nt < 4; ++nt)
#pragma unroll
      for (int e = 0; e < 4; ++e) {
        const int tl = wid*16 + g*4 + e;       // tile-local query
        const int jl = nt*16 + lc;             // chunk-local key
        const bool ok = (c == 1) || (c == 2 ? (jl <= tl) : (jl >= tl + 1));
        sc[c*4+nt][e] = ok ? sc[c*4+nt][e] * 0.0625f : -1e30f;
      }
  }

  // in-register softmax over 192 cols (row spread over 16-lane group)
#pragma unroll
  for (int e = 0; e < 4; ++e) {
    float m = -1e30f;
#pragma unroll
    for (int f = 0; f < 12; ++f) m = fmaxf(m, sc[f][e]);
    m = fmaxf(m, __shfl_xor(m, 1)); m = fmaxf(m, __shfl_xor(m, 2));
    m = fmaxf(m, __shfl_xor(m, 4)); m = fmaxf(m, __shfl_xor(m, 8));
    float s = 0.f;
#pragma unroll
    for (int f = 0; f < 12; ++f) { const float p = __expf(sc[f][e] - m); sc[f][e] = p; s += p; }
    s += __shfl_xor(s, 1); s += __shfl_xor(s, 2);
    s += __shfl_xor(s, 4); s += __shfl_xor(s, 8);
    const float is = 1.f / s;
#pragma unroll
    for (int f = 0; f < 12; ++f) sc[f][e] *= is;
  }
  // P -> LDS (wave-private; A-frag friendly layout)
#pragma unroll
  for (int c = 0; c < 3; ++c)
#pragma unroll
    for (int nt = 0; nt < 4; ++nt)
#pragma unroll
      for (int e = 0; e < 4; ++e)
        pb[wid][g*4 + e][c*64 + nt*16 + lc] = f2b(sc[c*4+nt][e]);

  f32x4 acc[16];
#pragma unroll
  for (int nt = 0; nt < 16; ++nt)
#pragma unroll
    for (int e = 0; e < 4; ++e) acc[nt][e] = 0.f;

  const u16* vg = vt + (size_t)bh * 256 * 2048;
#pragma unroll
  for (int c = 0; c < 3; ++c) {
    const int j0 = t0 + (c - 2) * 64;
    if (j0 < 0) continue;
    __syncthreads();  // all waves done reading kv (K or previous V)
#pragma unroll
    for (int i = 0; i < 8; ++i) {  // stage V chunk [256 dims][64 keys], XOR-swizzled source
      const int o16 = i*256 + tid;
      const int dim = o16 >> 3, slot = o16 & 7;
      const int ss = slot ^ (dim & 7);
      GLD16(vg + (size_t)dim*2048 + j0 + ss*8, kv + o16*8);
    }
    __syncthreads();
#pragma unroll
    for (int ks = 0; ks < 2; ++ks) {
      const bf16x8 pa = *(const bf16x8*)&pb[wid][lc][(c*2 + ks)*32 + g*8];
#pragma unroll
      for (int nt = 0; nt < 16; ++nt) {
        const int dim = nt*16 + lc;
        int boff = dim*128 + ks*64 + g*16;
        boff ^= (dim & 7) << 4;                // swizzled read
        const bf16x8 vb = *(const bf16x8*)((const char*)kv + boff);
        acc[nt] = __builtin_amdgcn_mfma_f32_16x16x32_bf16(pa, vb, acc[nt], 0, 0, 0);
      }
    }
  }

#pragma unroll
  for (int nt = 0; nt < 16; ++nt)
#pragma unroll
    for (int e = 0; e < 4; ++e) {
      const int tok = bT + t0 + wid*16 + g*4 + e;
      y[(size_t)tok * 1024 + h*256 + nt*16 + lc] = f2b(acc[nt][e]);
    }
}

// ---------------- host orchestration ----------------
extern "C" void kernel_launch(void* const* d_in, const int* in_sizes, int n_in,
                              void* d_out, int out_size, void* d_ws, size_t ws_size,
                              hipStream_t stream) {
  const float* x_in      = (const float*)d_in[0];
  const float* ln1_s     = (const float*)d_in[1];
  const float* ln1_b     = (const float*)d_in[2];
  const float* ln2_s     = (const float*)d_in[3];
  const float* ln2_b     = (const float*)d_in[4];
  const float* ln3_s     = (const float*)d_in[5];
  const float* ln3_b     = (const float*)d_in[6];
  const float* rg_in_w   = (const float*)d_in[7];
  const float* rg_in_b   = (const float*)d_in[8];
  const float* rg_gate_w = (const float*)d_in[9];
  const float* rg_gate_b = (const float*)d_in[10];
  const float* rg_out_w  = (const float*)d_in[11];
  const float* rg_out_b  = (const float*)d_in[12];
  const float* qkv_w     = (const float*)d_in[13];
  const float* qkv_b     = (const float*)d_in[14];
  const float* attn_out_w= (const float*)d_in[15];
  const float* attn_out_b= (const float*)d_in[16];
  const float* mlp_w1    = (const float*)d_in[17];
  const float* mlp_b1    = (const float*)d_in[18];
  const float* mlp_w2    = (const float*)d_in[19];
  const float* mlp_b2    = (const float*)d_in[20];

  float* x = (float*)d_out;
  char* ws = (char*)d_ws;
  u16*  wt     = (u16*)ws;                          // 62,914,560 B (bf16 transposed weights)
  u16*  xn     = (u16*)(ws + 62914560);             // 16,777,216 B
  char* bigS   = ws + 62914560 + 16777216;          // 67,108,864 B
  char* smallS = bigS + 67108864;                   // 16,777,216 B
  float* aggA  = (float*)(smallS + 16777216);
  float* aggB  = aggA + (size_t)BB * NCHUNK * DD;
  float* carry = aggB + (size_t)BB * NCHUNK * DD;

  float* ubuf = (float*)bigS;                       // RG phase
  float* gbuf = (float*)(bigS + 33554432);
  u16* qkb  = (u16*)bigS;                           // attn phase: [8192][2048] QK
  u16* vtb  = (u16*)(bigS + 33554432);              // attn phase: V transposed, 16MB
  u16* hid  = (u16*)bigS;                           // MLP phase
  u16* hbuf = (u16*)smallS;
  u16* ybuf = (u16*)smallS;

  hipMemcpyAsync(x, x_in, (size_t)MM * DD * sizeof(float), hipMemcpyDeviceToDevice, stream);

  const size_t LW = 15728640;
  const dim3 tb(32, 8);
  for (int l = 0; l < NLAYER; ++l) {
    u16* base = wt + (size_t)l * LW;
    transpose_cvt<<<dim3(32, 32),  tb, 0, stream>>>(rg_in_w   + (size_t)l*DD*DD,   base + 0,        DD, DD);
    transpose_cvt<<<dim3(32, 32),  tb, 0, stream>>>(rg_gate_w + (size_t)l*DD*DD,   base + 1048576,  DD, DD);
    transpose_cvt<<<dim3(32, 32),  tb, 0, stream>>>(rg_out_w  + (size_t)l*DD*DD,   base + 2097152,  DD, DD);
    transpose_cvt<<<dim3(96, 32),  tb, 0, stream>>>(qkv_w     + (size_t)l*DD*3072, base + 3145728,  DD, 3072);
    transpose_cvt<<<dim3(32, 32),  tb, 0, stream>>>(attn_out_w+ (size_t)l*DD*DD,   base + 6291456,  DD, DD);
    transpose_cvt<<<dim3(128, 32), tb, 0, stream>>>(mlp_w1    + (size_t)l*DD*4096, base + 7340032,  DD, 4096);
    transpose_cvt<<<dim3(32, 128), tb, 0, stream>>>(mlp_w2    + (size_t)l*4096*DD, base + 11534336, 4096, DD);
  }

  for (int l = 0; l < NLAYER; ++l) {
    u16* base = wt + (size_t)l * LW;
    // ---- RG-LRU block
    ln_k<<<MM, 256, 0, stream>>>(x, ln1_s + l*DD, ln1_b + l*DD, xn);
    gemm_k<0><<<dim3(8, 64), 256, 0, stream>>>(xn, base + 0,       rg_in_b   + l*DD, ubuf, nullptr, DD, DD);
    gemm_k<0><<<dim3(8, 64), 256, 0, stream>>>(xn, base + 1048576, rg_gate_b + l*DD, gbuf, nullptr, DD, DD);
    scan1_k<<<dim3(4, NCHUNK, BB), 256, 0, stream>>>(gbuf, ubuf, aggA, aggB);
    scan2_k<<<16, 256, 0, stream>>>(aggA, aggB, carry);
    scan3_k<<<dim3(4, NCHUNK, BB), 256, 0, stream>>>(gbuf, ubuf, carry, hbuf);
    gemm_k<3><<<dim3(8, 64), 256, 0, stream>>>(hbuf, base + 2097152, rg_out_b + l*DD, x, nullptr, DD, DD);
    // ---- local attention block
    ln_k<<<MM, 256, 0, stream>>>(x, ln2_s + l*DD, ln2_b + l*DD, xn);
    gemm_k<4><<<dim3(24, 64), 256, 0, stream>>>(xn, base + 3145728, qkv_b + l*3072, (float*)vtb, qkb, DD, 3072);
    attn_mfma<<<dim3(TT/64, BB*HH), 256, 0, stream>>>(qkb, vtb, ybuf);
    gemm_k<3><<<dim3(8, 64), 256, 0, stream>>>(ybuf, base + 6291456, attn_out_b + l*DD, x, nullptr, DD, DD);
    // ---- MLP block
    ln_k<<<MM, 256, 0, stream>>>(x, ln3_s + l*DD, ln3_b + l*DD, xn);
    gemm_k<2><<<dim3(32, 64), 256, 0, stream>>>(xn, base + 7340032, mlp_b1 + l*4096, nullptr, hid, DD, 4096);
    gemm_k<3><<<dim3(8, 64), 256, 0, stream>>>(hid, base + 11534336, mlp_b2 + l*DD, x, nullptr, 4096, DD);
  }
}

// Round 3
// 1101.592 us; speedup vs baseline: 1.6667x; 1.0922x over previous
//
#include <hip/hip_runtime.h>
#include <math.h>

#define DD 1024
#define TT 2048
#define BB 4
#define HH 4
#define HDIM 256
#define NLAYER 2
#define MM (BB*TT)          // 8192 rows
#define NCHUNK 32
#define CHUNK (TT/NCHUNK)   // 64

typedef unsigned short u16;
typedef __bf16 bf16x8 __attribute__((ext_vector_type(8)));
typedef float f32x4 __attribute__((ext_vector_type(4)));

__device__ __forceinline__ float b2f(u16 h) {
  unsigned u = ((unsigned)h) << 16;
  return __builtin_bit_cast(float, u);
}
__device__ __forceinline__ u16 f2b(float f) {
  unsigned u = __builtin_bit_cast(unsigned, f);
  u += 0x7fffu + ((u >> 16) & 1u);
  return (u16)(u >> 16);
}
__device__ __forceinline__ float blo(unsigned u) { return __builtin_bit_cast(float, u << 16); }
__device__ __forceinline__ float bhi(unsigned u) { return __builtin_bit_cast(float, u & 0xffff0000u); }

#define GLD16(g, l) __builtin_amdgcn_global_load_lds( \
    (__attribute__((address_space(1))) void*)(void*)(g), \
    (__attribute__((address_space(3))) void*)(l), 16, 0, 0)

// ---------------- weight fp32 -> bf16 transpose: Wt[N][K] = W[K][N] ----------------
__global__ __launch_bounds__(256)
void transpose_cvt(const float* __restrict__ W, u16* __restrict__ Wt, int K, int N) {
  __shared__ float tile[32][33];
  const int n0 = blockIdx.x << 5, k0 = blockIdx.y << 5;
  const int tx = threadIdx.x, ty = threadIdx.y;
#pragma unroll
  for (int i = 0; i < 4; ++i)
    tile[ty + i*8][tx] = W[(size_t)(k0 + ty + i*8) * N + n0 + tx];
  __syncthreads();
#pragma unroll
  for (int i = 0; i < 4; ++i)
    Wt[(size_t)(n0 + ty + i*8) * K + k0 + tx] = f2b(tile[tx][ty + i*8]);
}

// ---------------- LayerNorm (fp32 in, bf16 out) ----------------
__global__ __launch_bounds__(256)
void ln_k(const float* __restrict__ x, const float* __restrict__ sc,
          const float* __restrict__ bi, u16* __restrict__ xn) {
  const int row = blockIdx.x;
  const int tid = threadIdx.x;
  const float4 xv = ((const float4*)(x + (size_t)row * DD))[tid];
  float s = xv.x + xv.y + xv.z + xv.w;
  float q = xv.x*xv.x + xv.y*xv.y + xv.z*xv.z + xv.w*xv.w;
#pragma unroll
  for (int o = 1; o < 64; o <<= 1) { s += __shfl_xor(s, o); q += __shfl_xor(q, o); }
  __shared__ float rs[4], rq[4];
  if ((tid & 63) == 0) { rs[tid >> 6] = s; rq[tid >> 6] = q; }
  __syncthreads();
  s = rs[0] + rs[1] + rs[2] + rs[3];
  q = rq[0] + rq[1] + rq[2] + rq[3];
  const float mean = s * (1.f / DD);
  const float var = q * (1.f / DD) - mean * mean;
  const float rstd = rsqrtf(var + 1e-5f);
  const float4 sv = ((const float4*)sc)[tid];
  const float4 bv = ((const float4*)bi)[tid];
  const u16 o0 = f2b((xv.x - mean) * rstd * sv.x + bv.x);
  const u16 o1 = f2b((xv.y - mean) * rstd * sv.y + bv.y);
  const u16 o2 = f2b((xv.z - mean) * rstd * sv.z + bv.z);
  const u16 o3 = f2b((xv.w - mean) * rstd * sv.w + bv.w);
  uint2 pk;
  pk.x = (unsigned)o0 | ((unsigned)o1 << 16);
  pk.y = (unsigned)o2 | ((unsigned)o3 << 16);
  *(uint2*)(xn + (size_t)row * DD + (tid << 2)) = pk;
}

// ---------------- bf16 MFMA GEMM, 2-phase pipelined, XCD-swizzled ----------------
// C[M,N] = A[M,K] * Wt[N,K]^T + bias
// EPI: 2 = bf16 gelu store, 3 = f32 residual add, 4 = qkv split (QK rowmajor + V transposed),
//      5 = dual f32 store (n<1024 -> outf+bias, else outf2+bias2)
template<int EPI>
__global__ __launch_bounds__(256)
void gemm_k(const u16* __restrict__ A, const u16* __restrict__ Wt,
            const float* __restrict__ bias, const float* __restrict__ bias2,
            float* __restrict__ outf, float* __restrict__ outf2,
            u16* __restrict__ outb, int K, int N) {
  __shared__ u16 As[2][4096];   // [128][32] double-buffered
  __shared__ u16 Bs[2][4096];
  const int tid = threadIdx.x;
  // XCD-chunked swizzle: same-A-panel n-blocks land on the same XCD
  const int gx = gridDim.x;
  const int nwg = gx * (int)gridDim.y;
  int lid = (int)blockIdx.y * gx + (int)blockIdx.x;
  lid = (lid & 7) * (nwg >> 3) + (lid >> 3);
  const int m0 = (lid / gx) << 7;
  const int n0 = (lid % gx) << 7;
  const int lane = tid & 63;
  const int wm = (tid >> 7) & 1;
  const int wn = (tid >> 6) & 1;
  const int g = lane >> 4;
  const int lc = lane & 15;
  const int kr = g << 3;
  const int arow = (wm << 6) + lc;
  const int brow = (wn << 6) + lc;
  const u16* Ag = A + (size_t)(m0 + (tid >> 2)) * K + ((tid & 3) << 3);
  const u16* Bg = Wt + (size_t)(n0 + (tid >> 2)) * K + ((tid & 3) << 3);
  f32x4 acc[4][4];
#pragma unroll
  for (int i = 0; i < 4; ++i)
#pragma unroll
    for (int j = 0; j < 4; ++j)
#pragma unroll
      for (int e = 0; e < 4; ++e) acc[i][j][e] = 0.f;

  const int KT = K >> 5;
  // prologue: stage tile 0 into buffer 0
  GLD16(Ag,                As[0] + tid * 8);
  GLD16(Ag + (size_t)64*K, As[0] + 2048 + tid * 8);
  GLD16(Bg,                Bs[0] + tid * 8);
  GLD16(Bg + (size_t)64*K, Bs[0] + 2048 + tid * 8);
  __syncthreads();  // implicit vmcnt(0) drain

  for (int kt = 0; kt < KT; ++kt) {
    const int cur = kt & 1;
    if (kt + 1 < KT) {  // stage next tile into other buffer (issued before compute)
      const u16* a = Ag + (kt + 1) * 32;
      const u16* b = Bg + (kt + 1) * 32;
      GLD16(a,                As[cur ^ 1] + tid * 8);
      GLD16(a + (size_t)64*K, As[cur ^ 1] + 2048 + tid * 8);
      GLD16(b,                Bs[cur ^ 1] + tid * 8);
      GLD16(b + (size_t)64*K, Bs[cur ^ 1] + 2048 + tid * 8);
    }
    bf16x8 af[4], bfr[4];
#pragma unroll
    for (int mi = 0; mi < 4; ++mi)
      af[mi] = *(const bf16x8*)(As[cur] + ((arow + mi*16) << 5) + kr);
#pragma unroll
    for (int ni = 0; ni < 4; ++ni)
      bfr[ni] = *(const bf16x8*)(Bs[cur] + ((brow + ni*16) << 5) + kr);
#pragma unroll
    for (int mi = 0; mi < 4; ++mi)
#pragma unroll
      for (int ni = 0; ni < 4; ++ni)
        acc[mi][ni] = __builtin_amdgcn_mfma_f32_16x16x32_bf16(af[mi], bfr[ni], acc[mi][ni], 0, 0, 0);
    __syncthreads();  // drains vmcnt(0): next tile staged; all waves done with cur
  }

#pragma unroll
  for (int mi = 0; mi < 4; ++mi) {
#pragma unroll
    for (int ni = 0; ni < 4; ++ni) {
      const int n = n0 + (wn << 6) + ni*16 + lc;
      const int mbase = m0 + (wm << 6) + mi*16 + (g << 2);
      if (EPI == 4) {
        const float bia = bias[n];
        if (n < 2048) {
#pragma unroll
          for (int e = 0; e < 4; ++e)
            outb[(size_t)(mbase + e) * 2048 + n] = f2b(acc[mi][ni][e] + bia);
        } else {
          const int hh = (n - 2048) >> 8, dim = (n - 2048) & 255;
          const int bidx = mbase >> 11, t = mbase & 2047;
          const u16 a0 = f2b(acc[mi][ni][0] + bia);
          const u16 a1 = f2b(acc[mi][ni][1] + bia);
          const u16 a2 = f2b(acc[mi][ni][2] + bia);
          const u16 a3 = f2b(acc[mi][ni][3] + bia);
          uint2 pk;
          pk.x = (unsigned)a0 | ((unsigned)a1 << 16);
          pk.y = (unsigned)a2 | ((unsigned)a3 << 16);
          u16* vtp = (u16*)outf;
          *(uint2*)(vtp + ((size_t)((bidx*4 + hh)*256 + dim)) * 2048 + t) = pk;
        }
      } else if (EPI == 5) {
        const float bia = (n < 1024) ? bias[n] : bias2[n - 1024];
        float* dst = (n < 1024) ? outf : outf2;
        const int nn = n & 1023;
#pragma unroll
        for (int e = 0; e < 4; ++e)
          dst[(size_t)(mbase + e) * 1024 + nn] = acc[mi][ni][e] + bia;
      } else {
        const float bia = bias[n];
#pragma unroll
        for (int e = 0; e < 4; ++e) {
          const float v = acc[mi][ni][e] + bia;
          const size_t idx = (size_t)(mbase + e) * N + n;
          if (EPI == 2) outb[idx] = f2b(0.5f * v * (1.f + erff(v * 0.70710678118654752f)));
          else outf[idx] += v;
        }
      }
    }
  }
}

// ---------------- RG-LRU chunked scan: h_t = g*h_{t-1} + (1-g)*u ----------------
__global__ __launch_bounds__(256)
void scan1_k(const float* __restrict__ gpre, const float* __restrict__ u,
             float* __restrict__ aggA, float* __restrict__ aggB) {
  const int d = blockIdx.x * 256 + threadIdx.x;
  const int c = blockIdx.y, b = blockIdx.z;
  const size_t base = ((size_t)b * TT + (size_t)c * CHUNK) * DD + d;
  float a = 1.f, acc = 0.f;
  for (int t = 0; t < CHUNK; ++t) {
    const float gl = 1.f / (1.f + __expf(-gpre[base + (size_t)t * DD]));
    const float ul = u[base + (size_t)t * DD];
    acc = gl * acc + (1.f - gl) * ul;
    a *= gl;
  }
  const size_t o = ((size_t)b * NCHUNK + c) * DD + d;
  aggA[o] = a; aggB[o] = acc;
}

__global__ __launch_bounds__(256)
void scan2_k(const float* __restrict__ aggA, const float* __restrict__ aggB,
             float* __restrict__ carry) {
  const int idx = blockIdx.x * 256 + threadIdx.x;  // b*DD + d
  const int b = idx >> 10, d = idx & 1023;
  float h = 0.f;
  for (int c = 0; c < NCHUNK; ++c) {
    const size_t o = ((size_t)b * NCHUNK + c) * DD + d;
    carry[o] = h;
    h = aggA[o] * h + aggB[o];
  }
}

__global__ __launch_bounds__(256)
void scan3_k(const float* __restrict__ gpre, const float* __restrict__ u,
             const float* __restrict__ carry, u16* __restrict__ hout) {
  const int d = blockIdx.x * 256 + threadIdx.x;
  const int c = blockIdx.y, b = blockIdx.z;
  const size_t base = ((size_t)b * TT + (size_t)c * CHUNK) * DD + d;
  float h = carry[((size_t)b * NCHUNK + c) * DD + d];
  for (int t = 0; t < CHUNK; ++t) {
    const float gl = 1.f / (1.f + __expf(-gpre[base + (size_t)t * DD]));
    const float ul = u[base + (size_t)t * DD];
    h = gl * h + (1.f - gl) * ul;
    hout[base + (size_t)t * DD] = f2b(h);
  }
}

// ---------------- MFMA local-window attention ----------------
// qkb: [B*T][2048] bf16 (Q | K per token); vt: [(b*H+h)*256+dim][2048] bf16 (V transposed)
// y: [B*T][1024] bf16. Block = 64-query tile for one (b,h). Grid (T/64, B*H).
__global__ __launch_bounds__(256)
void attn_mfma(const u16* __restrict__ qkb, const u16* __restrict__ vt,
               u16* __restrict__ y) {
  __shared__ u16 kv[16384];        // 32KB chunk buffer (K slabs or swizzled V)
  __shared__ u16 pb[4][16][200];   // per-wave P, padded stride 200
  const int tid = threadIdx.x;
  const int lane = tid & 63;
  const int wid = tid >> 6;
  const int g = lane >> 4;
  const int lc = lane & 15;
  const int t0 = blockIdx.x << 6;
  const int bh = blockIdx.y;
  const int bT = (bh >> 2) * TT;
  const int h = bh & 3;

  bf16x8 afq[8];
  {
    const u16* qg = qkb + (size_t)(bT + t0 + wid*16 + lc) * 2048 + h*256 + g*8;
#pragma unroll
    for (int ks = 0; ks < 8; ++ks)
      afq[ks] = __builtin_bit_cast(bf16x8, *(const uint4*)(qg + ks*32));
  }

  f32x4 sc[12];
#pragma unroll
  for (int f = 0; f < 12; ++f)
#pragma unroll
    for (int e = 0; e < 4; ++e) sc[f][e] = 0.f;

  const int koff = 1024 + h*256;
#pragma unroll
  for (int c = 0; c < 3; ++c) {
    const int j0 = t0 + (c - 2) * 64;
    if (j0 < 0) {
#pragma unroll
      for (int nt = 0; nt < 4; ++nt)
#pragma unroll
        for (int e = 0; e < 4; ++e) sc[c*4+nt][e] = -1e30f;
      continue;
    }
    __syncthreads();
    {  // stage K chunk: [8 slabs][64 keys][32 dims]
      const u16* kg = qkb + (size_t)(bT + j0) * 2048 + koff;
#pragma unroll
      for (int i = 0; i < 8; ++i) {
        const int o16 = i*256 + tid;
        const int slab = o16 >> 8, key = (o16 >> 2) & 63, ds = o16 & 3;
        GLD16(kg + (size_t)key*2048 + slab*32 + ds*8, kv + o16*8);
      }
    }
    __syncthreads();
#pragma unroll
    for (int nt = 0; nt < 4; ++nt) {
      f32x4 s = sc[c*4+nt];
#pragma unroll
      for (int ks = 0; ks < 8; ++ks) {
        const bf16x8 kb = *(const bf16x8*)(kv + ks*2048 + (nt*16 + lc)*32 + g*8);
        s = __builtin_amdgcn_mfma_f32_16x16x32_bf16(afq[ks], kb, s, 0, 0, 0);
      }
      sc[c*4+nt] = s;
    }
#pragma unroll
    for (int nt = 0; nt < 4; ++nt)
#pragma unroll
      for (int e = 0; e < 4; ++e) {
        const int tl = wid*16 + g*4 + e;
        const int jl = nt*16 + lc;
        const bool ok = (c == 1) || (c == 2 ? (jl <= tl) : (jl >= tl + 1));
        sc[c*4+nt][e] = ok ? sc[c*4+nt][e] * 0.0625f : -1e30f;
      }
  }

#pragma unroll
  for (int e = 0; e < 4; ++e) {
    float m = -1e30f;
#pragma unroll
    for (int f = 0; f < 12; ++f) m = fmaxf(m, sc[f][e]);
    m = fmaxf(m, __shfl_xor(m, 1)); m = fmaxf(m, __shfl_xor(m, 2));
    m = fmaxf(m, __shfl_xor(m, 4)); m = fmaxf(m, __shfl_xor(m, 8));
    float s = 0.f;
#pragma unroll
    for (int f = 0; f < 12; ++f) { const float p = __expf(sc[f][e] - m); sc[f][e] = p; s += p; }
    s += __shfl_xor(s, 1); s += __shfl_xor(s, 2);
    s += __shfl_xor(s, 4); s += __shfl_xor(s, 8);
    const float is = 1.f / s;
#pragma unroll
    for (int f = 0; f < 12; ++f) sc[f][e] *= is;
  }
#pragma unroll
  for (int c = 0; c < 3; ++c)
#pragma unroll
    for (int nt = 0; nt < 4; ++nt)
#pragma unroll
      for (int e = 0; e < 4; ++e)
        pb[wid][g*4 + e][c*64 + nt*16 + lc] = f2b(sc[c*4+nt][e]);

  f32x4 acc[16];
#pragma unroll
  for (int nt = 0; nt < 16; ++nt)
#pragma unroll
    for (int e = 0; e < 4; ++e) acc[nt][e] = 0.f;

  const u16* vg = vt + (size_t)bh * 256 * 2048;
#pragma unroll
  for (int c = 0; c < 3; ++c) {
    const int j0 = t0 + (c - 2) * 64;
    if (j0 < 0) continue;
    __syncthreads();
#pragma unroll
    for (int i = 0; i < 8; ++i) {  // stage V chunk [256 dims][64 keys], XOR-swizzled source
      const int o16 = i*256 + tid;
      const int dim = o16 >> 3, slot = o16 & 7;
      const int ss = slot ^ (dim & 7);
      GLD16(vg + (size_t)dim*2048 + j0 + ss*8, kv + o16*8);
    }
    __syncthreads();
#pragma unroll
    for (int ks = 0; ks < 2; ++ks) {
      const bf16x8 pa = *(const bf16x8*)&pb[wid][lc][(c*2 + ks)*32 + g*8];
#pragma unroll
      for (int nt = 0; nt < 16; ++nt) {
        const int dim = nt*16 + lc;
        int boff = dim*128 + ks*64 + g*16;
        boff ^= (dim & 7) << 4;
        const bf16x8 vb = *(const bf16x8*)((const char*)kv + boff);
        acc[nt] = __builtin_amdgcn_mfma_f32_16x16x32_bf16(pa, vb, acc[nt], 0, 0, 0);
      }
    }
  }

#pragma unroll
  for (int nt = 0; nt < 16; ++nt)
#pragma unroll
    for (int e = 0; e < 4; ++e) {
      const int tok = bT + t0 + wid*16 + g*4 + e;
      y[(size_t)tok * 1024 + h*256 + nt*16 + lc] = f2b(acc[nt][e]);
    }
}

// ---------------- host orchestration ----------------
extern "C" void kernel_launch(void* const* d_in, const int* in_sizes, int n_in,
                              void* d_out, int out_size, void* d_ws, size_t ws_size,
                              hipStream_t stream) {
  const float* x_in      = (const float*)d_in[0];
  const float* ln1_s     = (const float*)d_in[1];
  const float* ln1_b     = (const float*)d_in[2];
  const float* ln2_s     = (const float*)d_in[3];
  const float* ln2_b     = (const float*)d_in[4];
  const float* ln3_s     = (const float*)d_in[5];
  const float* ln3_b     = (const float*)d_in[6];
  const float* rg_in_w   = (const float*)d_in[7];
  const float* rg_in_b   = (const float*)d_in[8];
  const float* rg_gate_w = (const float*)d_in[9];
  const float* rg_gate_b = (const float*)d_in[10];
  const float* rg_out_w  = (const float*)d_in[11];
  const float* rg_out_b  = (const float*)d_in[12];
  const float* qkv_w     = (const float*)d_in[13];
  const float* qkv_b     = (const float*)d_in[14];
  const float* attn_out_w= (const float*)d_in[15];
  const float* attn_out_b= (const float*)d_in[16];
  const float* mlp_w1    = (const float*)d_in[17];
  const float* mlp_b1    = (const float*)d_in[18];
  const float* mlp_w2    = (const float*)d_in[19];
  const float* mlp_b2    = (const float*)d_in[20];

  float* x = (float*)d_out;
  char* ws = (char*)d_ws;
  u16*  wt     = (u16*)ws;                          // 62,914,560 B (bf16 transposed weights)
  u16*  xn     = (u16*)(ws + 62914560);             // 16,777,216 B
  char* bigS   = ws + 62914560 + 16777216;          // 67,108,864 B
  char* smallS = bigS + 67108864;                   // 16,777,216 B
  float* aggA  = (float*)(smallS + 16777216);
  float* aggB  = aggA + (size_t)BB * NCHUNK * DD;
  float* carry = aggB + (size_t)BB * NCHUNK * DD;

  float* ubuf = (float*)bigS;                       // RG phase
  float* gbuf = (float*)(bigS + 33554432);
  u16* qkb  = (u16*)bigS;                           // attn phase: [8192][2048] QK
  u16* vtb  = (u16*)(bigS + 33554432);              // attn phase: V transposed, 16MB
  u16* hid  = (u16*)bigS;                           // MLP phase
  u16* hbuf = (u16*)smallS;
  u16* ybuf = (u16*)smallS;

  hipMemcpyAsync(x, x_in, (size_t)MM * DD * sizeof(float), hipMemcpyDeviceToDevice, stream);

  const size_t LW = 15728640;
  const dim3 tb(32, 8);
  for (int l = 0; l < NLAYER; ++l) {
    u16* base = wt + (size_t)l * LW;
    transpose_cvt<<<dim3(32, 32),  tb, 0, stream>>>(rg_in_w   + (size_t)l*DD*DD,   base + 0,        DD, DD);
    transpose_cvt<<<dim3(32, 32),  tb, 0, stream>>>(rg_gate_w + (size_t)l*DD*DD,   base + 1048576,  DD, DD);
    transpose_cvt<<<dim3(32, 32),  tb, 0, stream>>>(rg_out_w  + (size_t)l*DD*DD,   base + 2097152,  DD, DD);
    transpose_cvt<<<dim3(96, 32),  tb, 0, stream>>>(qkv_w     + (size_t)l*DD*3072, base + 3145728,  DD, 3072);
    transpose_cvt<<<dim3(32, 32),  tb, 0, stream>>>(attn_out_w+ (size_t)l*DD*DD,   base + 6291456,  DD, DD);
    transpose_cvt<<<dim3(128, 32), tb, 0, stream>>>(mlp_w1    + (size_t)l*DD*4096, base + 7340032,  DD, 4096);
    transpose_cvt<<<dim3(32, 128), tb, 0, stream>>>(mlp_w2    + (size_t)l*4096*DD, base + 11534336, 4096, DD);
  }

  for (int l = 0; l < NLAYER; ++l) {
    u16* base = wt + (size_t)l * LW;
    // ---- RG-LRU block (rg_in + rg_gate fused: Wt rows [0,1024)=in, [1024,2048)=gate)
    ln_k<<<MM, 256, 0, stream>>>(x, ln1_s + l*DD, ln1_b + l*DD, xn);
    gemm_k<5><<<dim3(16, 64), 256, 0, stream>>>(xn, base + 0, rg_in_b + l*DD, rg_gate_b + l*DD,
                                                ubuf, gbuf, nullptr, DD, 2048);
    scan1_k<<<dim3(4, NCHUNK, BB), 256, 0, stream>>>(gbuf, ubuf, aggA, aggB);
    scan2_k<<<16, 256, 0, stream>>>(aggA, aggB, carry);
    scan3_k<<<dim3(4, NCHUNK, BB), 256, 0, stream>>>(gbuf, ubuf, carry, hbuf);
    gemm_k<3><<<dim3(8, 64), 256, 0, stream>>>(hbuf, base + 2097152, rg_out_b + l*DD, nullptr,
                                               x, nullptr, nullptr, DD, DD);
    // ---- local attention block
    ln_k<<<MM, 256, 0, stream>>>(x, ln2_s + l*DD, ln2_b + l*DD, xn);
    gemm_k<4><<<dim3(24, 64), 256, 0, stream>>>(xn, base + 3145728, qkv_b + l*3072, nullptr,
                                                (float*)vtb, nullptr, qkb, DD, 3072);
    attn_mfma<<<dim3(TT/64, BB*HH), 256, 0, stream>>>(qkb, vtb, ybuf);
    gemm_k<3><<<dim3(8, 64), 256, 0, stream>>>(ybuf, base + 6291456, attn_out_b + l*DD, nullptr,
                                               x, nullptr, nullptr, DD, DD);
    // ---- MLP block
    ln_k<<<MM, 256, 0, stream>>>(x, ln3_s + l*DD, ln3_b + l*DD, xn);
    gemm_k<2><<<dim3(32, 64), 256, 0, stream>>>(xn, base + 7340032, mlp_b1 + l*4096, nullptr,
                                                nullptr, nullptr, hid, DD, 4096);
    gemm_k<3><<<dim3(8, 64), 256, 0, stream>>>(hid, base + 11534336, mlp_b2 + l*DD, nullptr,
                                               x, nullptr, nullptr, 4096, DD);
  }
}

// Round 4
// 945.399 us; speedup vs baseline: 1.9421x; 1.1652x over previous
//
#include <hip/hip_runtime.h>
#include <math.h>

#define DD 1024
#define TT 2048
#define BB 4
#define HH 4
#define HDIM 256
#define NLAYER 2
#define MM (BB*TT)          // 8192 rows
#define NCHUNK 32
#define CHUNK (TT/NCHUNK)   // 64

typedef unsigned short u16;
typedef __bf16 bf16x8 __attribute__((ext_vector_type(8)));
typedef float f32x4 __attribute__((ext_vector_type(4)));

__device__ __forceinline__ float b2f(u16 h) {
  unsigned u = ((unsigned)h) << 16;
  return __builtin_bit_cast(float, u);
}
__device__ __forceinline__ u16 f2b(float f) {
  unsigned u = __builtin_bit_cast(unsigned, f);
  u += 0x7fffu + ((u >> 16) & 1u);
  return (u16)(u >> 16);
}
__device__ __forceinline__ float blo(unsigned u) { return __builtin_bit_cast(float, u << 16); }
__device__ __forceinline__ float bhi(unsigned u) { return __builtin_bit_cast(float, u & 0xffff0000u); }

#define GLD16(g, l) __builtin_amdgcn_global_load_lds( \
    (__attribute__((address_space(1))) void*)(void*)(g), \
    (__attribute__((address_space(3))) void*)(l), 16, 0, 0)

__device__ __forceinline__ void wg_barrier() {
  asm volatile("" ::: "memory");
  __builtin_amdgcn_s_barrier();
  asm volatile("" ::: "memory");
}

// ---------------- weight fp32 -> bf16 transpose: Wt[N][K] = W[K][N] ----------------
__global__ __launch_bounds__(256)
void transpose_cvt(const float* __restrict__ W, u16* __restrict__ Wt, int K, int N) {
  __shared__ float tile[32][33];
  const int n0 = blockIdx.x << 5, k0 = blockIdx.y << 5;
  const int tx = threadIdx.x, ty = threadIdx.y;
#pragma unroll
  for (int i = 0; i < 4; ++i)
    tile[ty + i*8][tx] = W[(size_t)(k0 + ty + i*8) * N + n0 + tx];
  __syncthreads();
#pragma unroll
  for (int i = 0; i < 4; ++i)
    Wt[(size_t)(n0 + ty + i*8) * K + k0 + tx] = f2b(tile[tx][ty + i*8]);
}

// ---------------- LayerNorm (fp32 in, bf16 out) ----------------
__global__ __launch_bounds__(256)
void ln_k(const float* __restrict__ x, const float* __restrict__ sc,
          const float* __restrict__ bi, u16* __restrict__ xn) {
  const int row = blockIdx.x;
  const int tid = threadIdx.x;
  const float4 xv = ((const float4*)(x + (size_t)row * DD))[tid];
  float s = xv.x + xv.y + xv.z + xv.w;
  float q = xv.x*xv.x + xv.y*xv.y + xv.z*xv.z + xv.w*xv.w;
#pragma unroll
  for (int o = 1; o < 64; o <<= 1) { s += __shfl_xor(s, o); q += __shfl_xor(q, o); }
  __shared__ float rs[4], rq[4];
  if ((tid & 63) == 0) { rs[tid >> 6] = s; rq[tid >> 6] = q; }
  __syncthreads();
  s = rs[0] + rs[1] + rs[2] + rs[3];
  q = rq[0] + rq[1] + rq[2] + rq[3];
  const float mean = s * (1.f / DD);
  const float var = q * (1.f / DD) - mean * mean;
  const float rstd = rsqrtf(var + 1e-5f);
  const float4 sv = ((const float4*)sc)[tid];
  const float4 bv = ((const float4*)bi)[tid];
  const u16 o0 = f2b((xv.x - mean) * rstd * sv.x + bv.x);
  const u16 o1 = f2b((xv.y - mean) * rstd * sv.y + bv.y);
  const u16 o2 = f2b((xv.z - mean) * rstd * sv.z + bv.z);
  const u16 o3 = f2b((xv.w - mean) * rstd * sv.w + bv.w);
  uint2 pk;
  pk.x = (unsigned)o0 | ((unsigned)o1 << 16);
  pk.y = (unsigned)o2 | ((unsigned)o3 << 16);
  *(uint2*)(xn + (size_t)row * DD + (tid << 2)) = pk;
}

// ---------------- bf16 MFMA GEMM: BK=64, counted-vmcnt pipeline, XOR-swizzled LDS ----
// C[M,N] = A[M,K] * Wt[N,K]^T + bias
// EPI: 2 = bf16 gelu store, 3 = f32 residual add, 4 = qkv split (QK rowmajor + V transposed),
//      5 = dual bf16 store (n<1024 -> u, else pre-sigmoid z)
template<int EPI>
__global__ __launch_bounds__(256)
void gemm_k(const u16* __restrict__ A, const u16* __restrict__ Wt,
            const float* __restrict__ bias, const float* __restrict__ bias2,
            float* __restrict__ outf, float* __restrict__ outf2,
            u16* __restrict__ outb, int K, int N) {
  __shared__ u16 As[2][8192];   // [128][64] per buffer
  __shared__ u16 Bs[2][8192];
  const int tid = threadIdx.x;
  // XCD-chunked swizzle: same-A-panel n-blocks land on the same XCD
  const int gx = gridDim.x;
  const int nwg = gx * (int)gridDim.y;
  int lid = (int)blockIdx.y * gx + (int)blockIdx.x;
  lid = (lid & 7) * (nwg >> 3) + (lid >> 3);
  const int m0 = (lid / gx) << 7;
  const int n0 = (lid % gx) << 7;
  const int lane = tid & 63;
  const int wm = (tid >> 7) & 1;
  const int wn = (tid >> 6) & 1;
  const int g = lane >> 4;
  const int lc = lane & 15;
  const int sw = lc & 7;              // read-side XOR key
  const int rowst = tid >> 3;         // staging: 0..31
  const int aslot = (tid & 7) ^ (rowst & 7);  // inverse-swizzled source slot

  const u16* Abase = A  + (size_t)m0 * K;
  const u16* Bbase = Wt + (size_t)n0 * K;

  auto stage = [&](int kt, int buf) {
    const int ko = (kt << 6) + (aslot << 3);
#pragma unroll
    for (int i = 0; i < 4; ++i) {
      GLD16(Abase + (size_t)(i*32 + rowst) * K + ko, As[buf] + (i*256 + tid)*8);
      GLD16(Bbase + (size_t)(i*32 + rowst) * K + ko, Bs[buf] + (i*256 + tid)*8);
    }
  };

  f32x4 acc[4][4];
#pragma unroll
  for (int i = 0; i < 4; ++i)
#pragma unroll
    for (int j = 0; j < 4; ++j)
#pragma unroll
      for (int e = 0; e < 4; ++e) acc[i][j][e] = 0.f;

  const int KT = K >> 6;
  stage(0, 0);
  stage(1, 1);
  for (int kt = 0; kt < KT; ++kt) {
    const int cur = kt & 1;
    if (kt + 1 < KT) asm volatile("s_waitcnt vmcnt(8)" ::: "memory");
    else             asm volatile("s_waitcnt vmcnt(0)" ::: "memory");
    __builtin_amdgcn_s_barrier();
    asm volatile("" ::: "memory");
    const u16* Ac = As[cur];
    const u16* Bc = Bs[cur];
#pragma unroll
    for (int kk = 0; kk < 2; ++kk) {
      const int ko = ((kk*4 + g) ^ sw) << 3;   // swizzled 16B-chunk within 128B row
      bf16x8 af[4], bfr[4];
#pragma unroll
      for (int mi = 0; mi < 4; ++mi)
        af[mi] = *(const bf16x8*)(Ac + ((wm*64 + mi*16 + lc) << 6) + ko);
#pragma unroll
      for (int ni = 0; ni < 4; ++ni)
        bfr[ni] = *(const bf16x8*)(Bc + ((wn*64 + ni*16 + lc) << 6) + ko);
      __builtin_amdgcn_s_setprio(1);
#pragma unroll
      for (int mi = 0; mi < 4; ++mi)
#pragma unroll
        for (int ni = 0; ni < 4; ++ni)
          acc[mi][ni] = __builtin_amdgcn_mfma_f32_16x16x32_bf16(af[mi], bfr[ni], acc[mi][ni], 0, 0, 0);
      __builtin_amdgcn_s_setprio(0);
    }
    wg_barrier();
    if (kt + 2 < KT) stage(kt + 2, cur);
  }

#pragma unroll
  for (int mi = 0; mi < 4; ++mi) {
#pragma unroll
    for (int ni = 0; ni < 4; ++ni) {
      const int n = n0 + (wn << 6) + ni*16 + lc;
      const int mbase = m0 + (wm << 6) + mi*16 + (g << 2);
      if (EPI == 4) {
        const float bia = bias[n];
        if (n < 2048) {
#pragma unroll
          for (int e = 0; e < 4; ++e)
            outb[(size_t)(mbase + e) * 2048 + n] = f2b(acc[mi][ni][e] + bia);
        } else {
          const int hh = (n - 2048) >> 8, dim = (n - 2048) & 255;
          const int bidx = mbase >> 11, t = mbase & 2047;
          const u16 a0 = f2b(acc[mi][ni][0] + bia);
          const u16 a1 = f2b(acc[mi][ni][1] + bia);
          const u16 a2 = f2b(acc[mi][ni][2] + bia);
          const u16 a3 = f2b(acc[mi][ni][3] + bia);
          uint2 pk;
          pk.x = (unsigned)a0 | ((unsigned)a1 << 16);
          pk.y = (unsigned)a2 | ((unsigned)a3 << 16);
          u16* vtp = (u16*)outf;
          *(uint2*)(vtp + ((size_t)((bidx*4 + hh)*256 + dim)) * 2048 + t) = pk;
        }
      } else if (EPI == 5) {
        const float bia = (n < 1024) ? bias[n] : bias2[n - 1024];
        u16* dst = (n < 1024) ? (u16*)outf : (u16*)outf2;
        const int nn = n & 1023;
#pragma unroll
        for (int e = 0; e < 4; ++e)
          dst[(size_t)(mbase + e) * 1024 + nn] = f2b(acc[mi][ni][e] + bia);
      } else {
        const float bia = bias[n];
#pragma unroll
        for (int e = 0; e < 4; ++e) {
          const float v = acc[mi][ni][e] + bia;
          const size_t idx = (size_t)(mbase + e) * N + n;
          if (EPI == 2) {
            // tanh-form gelu: v / (1 + exp(-2*0.7978845608*(v + 0.044715 v^3)))
            const float zc = fminf(fmaxf(1.5957691216f * (v + 0.044715f*v*v*v), -30.f), 30.f);
            outb[idx] = f2b(v / (1.f + __expf(-zc)));
          } else outf[idx] += v;
        }
      }
    }
  }
}

// ---------------- RG-LRU chunked scan (bf16 z,u inputs): h_t = g*h_{t-1} + (1-g)*u ----
__global__ __launch_bounds__(256)
void scan1_k(const u16* __restrict__ zpre, const u16* __restrict__ u,
             float* __restrict__ aggA, float* __restrict__ aggB) {
  const int d = blockIdx.x * 256 + threadIdx.x;
  const int c = blockIdx.y, b = blockIdx.z;
  const size_t base = ((size_t)b * TT + (size_t)c * CHUNK) * DD + d;
  float a = 1.f, acc = 0.f;
  for (int t = 0; t < CHUNK; ++t) {
    const float gl = 1.f / (1.f + __expf(-b2f(zpre[base + (size_t)t * DD])));
    const float ul = b2f(u[base + (size_t)t * DD]);
    acc = gl * acc + (1.f - gl) * ul;
    a *= gl;
  }
  const size_t o = ((size_t)b * NCHUNK + c) * DD + d;
  aggA[o] = a; aggB[o] = acc;
}

__global__ __launch_bounds__(256)
void scan2_k(const float* __restrict__ aggA, const float* __restrict__ aggB,
             float* __restrict__ carry) {
  const int idx = blockIdx.x * 256 + threadIdx.x;  // b*DD + d
  const int b = idx >> 10, d = idx & 1023;
  float h = 0.f;
  for (int c = 0; c < NCHUNK; ++c) {
    const size_t o = ((size_t)b * NCHUNK + c) * DD + d;
    carry[o] = h;
    h = aggA[o] * h + aggB[o];
  }
}

__global__ __launch_bounds__(256)
void scan3_k(const u16* __restrict__ zpre, const u16* __restrict__ u,
             const float* __restrict__ carry, u16* __restrict__ hout) {
  const int d = blockIdx.x * 256 + threadIdx.x;
  const int c = blockIdx.y, b = blockIdx.z;
  const size_t base = ((size_t)b * TT + (size_t)c * CHUNK) * DD + d;
  float h = carry[((size_t)b * NCHUNK + c) * DD + d];
  for (int t = 0; t < CHUNK; ++t) {
    const float gl = 1.f / (1.f + __expf(-b2f(zpre[base + (size_t)t * DD])));
    const float ul = b2f(u[base + (size_t)t * DD]);
    h = gl * h + (1.f - gl) * ul;
    hout[base + (size_t)t * DD] = f2b(h);
  }
}

// ---------------- MFMA local-window attention ----------------
// qkb: [B*T][2048] bf16 (Q | K per token); vt: [(b*H+h)*256+dim][2048] bf16 (V transposed)
// y: [B*T][1024] bf16. Block = 64-query tile for one (b,h). Grid (T/64, B*H).
__global__ __launch_bounds__(256)
void attn_mfma(const u16* __restrict__ qkb, const u16* __restrict__ vt,
               u16* __restrict__ y) {
  __shared__ u16 kv[16384];        // 32KB chunk buffer (K slabs or swizzled V)
  __shared__ u16 pb[4][16][200];   // per-wave P, padded stride 200
  const int tid = threadIdx.x;
  const int lane = tid & 63;
  const int wid = tid >> 6;
  const int g = lane >> 4;
  const int lc = lane & 15;
  const int t0 = blockIdx.x << 6;
  const int bh = blockIdx.y;
  const int bT = (bh >> 2) * TT;
  const int h = bh & 3;

  bf16x8 afq[8];
  {
    const u16* qg = qkb + (size_t)(bT + t0 + wid*16 + lc) * 2048 + h*256 + g*8;
#pragma unroll
    for (int ks = 0; ks < 8; ++ks)
      afq[ks] = __builtin_bit_cast(bf16x8, *(const uint4*)(qg + ks*32));
  }

  f32x4 sc[12];
#pragma unroll
  for (int f = 0; f < 12; ++f)
#pragma unroll
    for (int e = 0; e < 4; ++e) sc[f][e] = 0.f;

  const int koff = 1024 + h*256;
#pragma unroll
  for (int c = 0; c < 3; ++c) {
    const int j0 = t0 + (c - 2) * 64;
    if (j0 < 0) {
#pragma unroll
      for (int nt = 0; nt < 4; ++nt)
#pragma unroll
        for (int e = 0; e < 4; ++e) sc[c*4+nt][e] = -1e30f;
      continue;
    }
    __syncthreads();
    {  // stage K chunk: [8 slabs][64 keys][32 dims]
      const u16* kg = qkb + (size_t)(bT + j0) * 2048 + koff;
#pragma unroll
      for (int i = 0; i < 8; ++i) {
        const int o16 = i*256 + tid;
        const int slab = o16 >> 8, key = (o16 >> 2) & 63, ds = o16 & 3;
        GLD16(kg + (size_t)key*2048 + slab*32 + ds*8, kv + o16*8);
      }
    }
    __syncthreads();
#pragma unroll
    for (int nt = 0; nt < 4; ++nt) {
      f32x4 s = sc[c*4+nt];
#pragma unroll
      for (int ks = 0; ks < 8; ++ks) {
        const bf16x8 kb = *(const bf16x8*)(kv + ks*2048 + (nt*16 + lc)*32 + g*8);
        s = __builtin_amdgcn_mfma_f32_16x16x32_bf16(afq[ks], kb, s, 0, 0, 0);
      }
      sc[c*4+nt] = s;
    }
#pragma unroll
    for (int nt = 0; nt < 4; ++nt)
#pragma unroll
      for (int e = 0; e < 4; ++e) {
        const int tl = wid*16 + g*4 + e;
        const int jl = nt*16 + lc;
        const bool ok = (c == 1) || (c == 2 ? (jl <= tl) : (jl >= tl + 1));
        sc[c*4+nt][e] = ok ? sc[c*4+nt][e] * 0.0625f : -1e30f;
      }
  }

#pragma unroll
  for (int e = 0; e < 4; ++e) {
    float m = -1e30f;
#pragma unroll
    for (int f = 0; f < 12; ++f) m = fmaxf(m, sc[f][e]);
    m = fmaxf(m, __shfl_xor(m, 1)); m = fmaxf(m, __shfl_xor(m, 2));
    m = fmaxf(m, __shfl_xor(m, 4)); m = fmaxf(m, __shfl_xor(m, 8));
    float s = 0.f;
#pragma unroll
    for (int f = 0; f < 12; ++f) { const float p = __expf(sc[f][e] - m); sc[f][e] = p; s += p; }
    s += __shfl_xor(s, 1); s += __shfl_xor(s, 2);
    s += __shfl_xor(s, 4); s += __shfl_xor(s, 8);
    const float is = 1.f / s;
#pragma unroll
    for (int f = 0; f < 12; ++f) sc[f][e] *= is;
  }
#pragma unroll
  for (int c = 0; c < 3; ++c)
#pragma unroll
    for (int nt = 0; nt < 4; ++nt)
#pragma unroll
      for (int e = 0; e < 4; ++e)
        pb[wid][g*4 + e][c*64 + nt*16 + lc] = f2b(sc[c*4+nt][e]);

  f32x4 acc[16];
#pragma unroll
  for (int nt = 0; nt < 16; ++nt)
#pragma unroll
    for (int e = 0; e < 4; ++e) acc[nt][e] = 0.f;

  const u16* vg = vt + (size_t)bh * 256 * 2048;
#pragma unroll
  for (int c = 0; c < 3; ++c) {
    const int j0 = t0 + (c - 2) * 64;
    if (j0 < 0) continue;
    __syncthreads();
#pragma unroll
    for (int i = 0; i < 8; ++i) {  // stage V chunk [256 dims][64 keys], XOR-swizzled source
      const int o16 = i*256 + tid;
      const int dim = o16 >> 3, slot = o16 & 7;
      const int ss = slot ^ (dim & 7);
      GLD16(vg + (size_t)dim*2048 + j0 + ss*8, kv + o16*8);
    }
    __syncthreads();
#pragma unroll
    for (int ks = 0; ks < 2; ++ks) {
      const bf16x8 pa = *(const bf16x8*)&pb[wid][lc][(c*2 + ks)*32 + g*8];
#pragma unroll
      for (int nt = 0; nt < 16; ++nt) {
        const int dim = nt*16 + lc;
        int boff = dim*128 + ks*64 + g*16;
        boff ^= (dim & 7) << 4;
        const bf16x8 vb = *(const bf16x8*)((const char*)kv + boff);
        acc[nt] = __builtin_amdgcn_mfma_f32_16x16x32_bf16(pa, vb, acc[nt], 0, 0, 0);
      }
    }
  }

#pragma unroll
  for (int nt = 0; nt < 16; ++nt)
#pragma unroll
    for (int e = 0; e < 4; ++e) {
      const int tok = bT + t0 + wid*16 + g*4 + e;
      y[(size_t)tok * 1024 + h*256 + nt*16 + lc] = f2b(acc[nt][e]);
    }
}

// ---------------- host orchestration ----------------
extern "C" void kernel_launch(void* const* d_in, const int* in_sizes, int n_in,
                              void* d_out, int out_size, void* d_ws, size_t ws_size,
                              hipStream_t stream) {
  const float* x_in      = (const float*)d_in[0];
  const float* ln1_s     = (const float*)d_in[1];
  const float* ln1_b     = (const float*)d_in[2];
  const float* ln2_s     = (const float*)d_in[3];
  const float* ln2_b     = (const float*)d_in[4];
  const float* ln3_s     = (const float*)d_in[5];
  const float* ln3_b     = (const float*)d_in[6];
  const float* rg_in_w   = (const float*)d_in[7];
  const float* rg_in_b   = (const float*)d_in[8];
  const float* rg_gate_w = (const float*)d_in[9];
  const float* rg_gate_b = (const float*)d_in[10];
  const float* rg_out_w  = (const float*)d_in[11];
  const float* rg_out_b  = (const float*)d_in[12];
  const float* qkv_w     = (const float*)d_in[13];
  const float* qkv_b     = (const float*)d_in[14];
  const float* attn_out_w= (const float*)d_in[15];
  const float* attn_out_b= (const float*)d_in[16];
  const float* mlp_w1    = (const float*)d_in[17];
  const float* mlp_b1    = (const float*)d_in[18];
  const float* mlp_w2    = (const float*)d_in[19];
  const float* mlp_b2    = (const float*)d_in[20];

  float* x = (float*)d_out;
  char* ws = (char*)d_ws;
  u16*  wt     = (u16*)ws;                          // 62,914,560 B (bf16 transposed weights)
  u16*  xn     = (u16*)(ws + 62914560);             // 16,777,216 B
  char* bigS   = ws + 62914560 + 16777216;          // 67,108,864 B
  char* smallS = bigS + 67108864;                   // 16,777,216 B
  float* aggA  = (float*)(smallS + 16777216);
  float* aggB  = aggA + (size_t)BB * NCHUNK * DD;
  float* carry = aggB + (size_t)BB * NCHUNK * DD;

  u16* ubuf = (u16*)bigS;                           // RG phase (bf16 now)
  u16* zbuf = (u16*)(bigS + 33554432);              // pre-sigmoid gate, bf16
  u16* qkb  = (u16*)bigS;                           // attn phase: [8192][2048] QK
  u16* vtb  = (u16*)(bigS + 33554432);              // attn phase: V transposed, 16MB
  u16* hid  = (u16*)bigS;                           // MLP phase
  u16* hbuf = (u16*)smallS;
  u16* ybuf = (u16*)smallS;

  hipMemcpyAsync(x, x_in, (size_t)MM * DD * sizeof(float), hipMemcpyDeviceToDevice, stream);

  const size_t LW = 15728640;
  const dim3 tb(32, 8);
  for (int l = 0; l < NLAYER; ++l) {
    u16* base = wt + (size_t)l * LW;
    transpose_cvt<<<dim3(32, 32),  tb, 0, stream>>>(rg_in_w   + (size_t)l*DD*DD,   base + 0,        DD, DD);
    transpose_cvt<<<dim3(32, 32),  tb, 0, stream>>>(rg_gate_w + (size_t)l*DD*DD,   base + 1048576,  DD, DD);
    transpose_cvt<<<dim3(32, 32),  tb, 0, stream>>>(rg_out_w  + (size_t)l*DD*DD,   base + 2097152,  DD, DD);
    transpose_cvt<<<dim3(96, 32),  tb, 0, stream>>>(qkv_w     + (size_t)l*DD*3072, base + 3145728,  DD, 3072);
    transpose_cvt<<<dim3(32, 32),  tb, 0, stream>>>(attn_out_w+ (size_t)l*DD*DD,   base + 6291456,  DD, DD);
    transpose_cvt<<<dim3(128, 32), tb, 0, stream>>>(mlp_w1    + (size_t)l*DD*4096, base + 7340032,  DD, 4096);
    transpose_cvt<<<dim3(32, 128), tb, 0, stream>>>(mlp_w2    + (size_t)l*4096*DD, base + 11534336, 4096, DD);
  }

  for (int l = 0; l < NLAYER; ++l) {
    u16* base = wt + (size_t)l * LW;
    // ---- RG-LRU block (rg_in + rg_gate fused; u and pre-sigmoid z stored bf16)
    ln_k<<<MM, 256, 0, stream>>>(x, ln1_s + l*DD, ln1_b + l*DD, xn);
    gemm_k<5><<<dim3(16, 64), 256, 0, stream>>>(xn, base + 0, rg_in_b + l*DD, rg_gate_b + l*DD,
                                                (float*)ubuf, (float*)zbuf, nullptr, DD, 2048);
    scan1_k<<<dim3(4, NCHUNK, BB), 256, 0, stream>>>(zbuf, ubuf, aggA, aggB);
    scan2_k<<<16, 256, 0, stream>>>(aggA, aggB, carry);
    scan3_k<<<dim3(4, NCHUNK, BB), 256, 0, stream>>>(zbuf, ubuf, carry, hbuf);
    gemm_k<3><<<dim3(8, 64), 256, 0, stream>>>(hbuf, base + 2097152, rg_out_b + l*DD, nullptr,
                                               x, nullptr, nullptr, DD, DD);
    // ---- local attention block
    ln_k<<<MM, 256, 0, stream>>>(x, ln2_s + l*DD, ln2_b + l*DD, xn);
    gemm_k<4><<<dim3(24, 64), 256, 0, stream>>>(xn, base + 3145728, qkv_b + l*3072, nullptr,
                                                (float*)vtb, nullptr, qkb, DD, 3072);
    attn_mfma<<<dim3(TT/64, BB*HH), 256, 0, stream>>>(qkb, vtb, ybuf);
    gemm_k<3><<<dim3(8, 64), 256, 0, stream>>>(ybuf, base + 6291456, attn_out_b + l*DD, nullptr,
                                               x, nullptr, nullptr, DD, DD);
    // ---- MLP block
    ln_k<<<MM, 256, 0, stream>>>(x, ln3_s + l*DD, ln3_b + l*DD, xn);
    gemm_k<2><<<dim3(32, 64), 256, 0, stream>>>(xn, base + 7340032, mlp_b1 + l*4096, nullptr,
                                                nullptr, nullptr, hid, DD, 4096);
    gemm_k<3><<<dim3(8, 64), 256, 0, stream>>>(hid, base + 11534336, mlp_b2 + l*DD, nullptr,
                                               x, nullptr, nullptr, 4096, DD);
  }
}

// Round 5
// 920.346 us; speedup vs baseline: 1.9949x; 1.0272x over previous
//
#include <hip/hip_runtime.h>
#include <math.h>

#define DD 1024
#define TT 2048
#define BB 4
#define HH 4
#define HDIM 256
#define NLAYER 2
#define MM (BB*TT)          // 8192 rows
#define NCHUNK 32
#define CHUNK (TT/NCHUNK)   // 64

typedef unsigned short u16;
typedef __bf16 bf16x8 __attribute__((ext_vector_type(8)));
typedef float f32x4 __attribute__((ext_vector_type(4)));

__device__ __forceinline__ float b2f(u16 h) {
  unsigned u = ((unsigned)h) << 16;
  return __builtin_bit_cast(float, u);
}
__device__ __forceinline__ u16 f2b(float f) {
  unsigned u = __builtin_bit_cast(unsigned, f);
  u += 0x7fffu + ((u >> 16) & 1u);
  return (u16)(u >> 16);
}
__device__ __forceinline__ float blo(unsigned u) { return __builtin_bit_cast(float, u << 16); }
__device__ __forceinline__ float bhi(unsigned u) { return __builtin_bit_cast(float, u & 0xffff0000u); }

#define GLD16(g, l) __builtin_amdgcn_global_load_lds( \
    (__attribute__((address_space(1))) void*)(void*)(g), \
    (__attribute__((address_space(3))) void*)(l), 16, 0, 0)

__device__ __forceinline__ void wg_barrier() {
  asm volatile("" ::: "memory");
  __builtin_amdgcn_s_barrier();
  asm volatile("" ::: "memory");
}

// ---------------- weight fp32 -> bf16 transpose: Wt[N][K] = W[K][N] ----------------
__global__ __launch_bounds__(256)
void transpose_cvt(const float* __restrict__ W, u16* __restrict__ Wt, int K, int N) {
  __shared__ float tile[32][33];
  const int n0 = blockIdx.x << 5, k0 = blockIdx.y << 5;
  const int tx = threadIdx.x, ty = threadIdx.y;
#pragma unroll
  for (int i = 0; i < 4; ++i)
    tile[ty + i*8][tx] = W[(size_t)(k0 + ty + i*8) * N + n0 + tx];
  __syncthreads();
#pragma unroll
  for (int i = 0; i < 4; ++i)
    Wt[(size_t)(n0 + ty + i*8) * K + k0 + tx] = f2b(tile[tx][ty + i*8]);
}

// ---------------- LayerNorm (fp32 in, bf16 out) ----------------
__global__ __launch_bounds__(256)
void ln_k(const float* __restrict__ x, const float* __restrict__ sc,
          const float* __restrict__ bi, u16* __restrict__ xn) {
  const int row = blockIdx.x;
  const int tid = threadIdx.x;
  const float4 xv = ((const float4*)(x + (size_t)row * DD))[tid];
  float s = xv.x + xv.y + xv.z + xv.w;
  float q = xv.x*xv.x + xv.y*xv.y + xv.z*xv.z + xv.w*xv.w;
#pragma unroll
  for (int o = 1; o < 64; o <<= 1) { s += __shfl_xor(s, o); q += __shfl_xor(q, o); }
  __shared__ float rs[4], rq[4];
  if ((tid & 63) == 0) { rs[tid >> 6] = s; rq[tid >> 6] = q; }
  __syncthreads();
  s = rs[0] + rs[1] + rs[2] + rs[3];
  q = rq[0] + rq[1] + rq[2] + rq[3];
  const float mean = s * (1.f / DD);
  const float var = q * (1.f / DD) - mean * mean;
  const float rstd = rsqrtf(var + 1e-5f);
  const float4 sv = ((const float4*)sc)[tid];
  const float4 bv = ((const float4*)bi)[tid];
  const u16 o0 = f2b((xv.x - mean) * rstd * sv.x + bv.x);
  const u16 o1 = f2b((xv.y - mean) * rstd * sv.y + bv.y);
  const u16 o2 = f2b((xv.z - mean) * rstd * sv.z + bv.z);
  const u16 o3 = f2b((xv.w - mean) * rstd * sv.w + bv.w);
  uint2 pk;
  pk.x = (unsigned)o0 | ((unsigned)o1 << 16);
  pk.y = (unsigned)o2 | ((unsigned)o3 << 16);
  *(uint2*)(xn + (size_t)row * DD + (tid << 2)) = pk;
}

// ============ 256x256 8-wave phase-interleaved GEMM (T2+T3+T4+T5) ============
// C[M,N] = A[M,K]*Wt[N,K]^T + bias.  512 threads, dynamic LDS 128KB.
// EPI: 2 = bf16 gelu store, 4 = qkv split (QK rowmajor + V transposed),
//      5 = dual bf16 store (n<1024 -> u, else pre-sigmoid z)
template<int EPI>
__global__ __launch_bounds__(512, 2)
void gemm256_k(const u16* __restrict__ A, const u16* __restrict__ Wt,
               const float* __restrict__ bias, const float* __restrict__ bias2,
               float* __restrict__ outf, u16* __restrict__ outb, int K, int N) {
  extern __shared__ u16 lds[];
  u16* Al = lds;            // [2][256][64]
  u16* Bl = lds + 32768;    // [2][256][64]
  const int tid = threadIdx.x;
  const int gx = gridDim.x;
  const int nwg = gx * (int)gridDim.y;
  int lid = (int)blockIdx.y * gx + (int)blockIdx.x;
  lid = (lid & 7) * (nwg >> 3) + (lid >> 3);     // XCD-chunked (nwg % 8 == 0)
  const int m0 = (lid / gx) << 8;
  const int n0 = (lid % gx) << 8;
  const int lane = tid & 63;
  const int wid = tid >> 6;
  const int wm = wid >> 2;        // 0..1 -> m-half (128 rows)
  const int wn = wid & 3;         // 0..3 -> n-quarter (64 cols)
  const int g = lane >> 4;
  const int lc = lane & 15;

  // staging geometry: 512 threads, sweep = 64 rows x 64 cols (8KB)
  const int srow = tid >> 3;      // 0..63
  const int sslot = tid & 7;

  auto stage_part = [&](int kt, int c, int p) {
    if (p < 2) {
#pragma unroll
      for (int i = p*2; i < p*2 + 2; ++i) {
        const int row = i*64 + srow;
        GLD16(A + (size_t)(m0 + row) * K + kt*64 + ((sslot ^ (row & 7)) << 3),
              Al + c*16384 + row*64 + sslot*8);
      }
    } else {
#pragma unroll
      for (int i = (p-2)*2; i < (p-2)*2 + 2; ++i) {
        const int row = i*64 + srow;
        GLD16(Wt + (size_t)(n0 + row) * K + kt*64 + ((sslot ^ (row & 7)) << 3),
              Bl + c*16384 + row*64 + sslot*8);
      }
    }
  };

  f32x4 acc[8][4];
#pragma unroll
  for (int i = 0; i < 8; ++i)
#pragma unroll
    for (int j = 0; j < 4; ++j)
#pragma unroll
      for (int e = 0; e < 4; ++e) acc[i][j][e] = 0.f;

  const int KT = K >> 6;
  // prologue: stage tile 0 -> buf 0
#pragma unroll
  for (int p = 0; p < 4; ++p) stage_part(0, 0, p);

  for (int kt = 0; kt < KT; ++kt) {
    const int cur = kt & 1;
    asm volatile("s_waitcnt vmcnt(0)" ::: "memory");
    wg_barrier();                 // buf[cur] fully staged; buf[cur^1] free
    bf16x8 bfr[4];
#pragma unroll
    for (int p = 0; p < 4; ++p) {
      const int kk = p >> 1, mh = p & 1;
      const int c16 = ((kk*4 + g) ^ (lc & 7)) << 3;
      bf16x8 af[4];
#pragma unroll
      for (int i = 0; i < 4; ++i) {
        const int row = wm*128 + (mh*4 + i)*16 + lc;
        af[i] = *(const bf16x8*)(Al + cur*16384 + row*64 + c16);
      }
      if (mh == 0) {
#pragma unroll
        for (int ni = 0; ni < 4; ++ni) {
          const int row = wn*64 + ni*16 + lc;
          bfr[ni] = *(const bf16x8*)(Bl + cur*16384 + row*64 + c16);
        }
      }
      if (kt + 1 < KT) stage_part(kt + 1, cur ^ 1, p);
      wg_barrier();
      __builtin_amdgcn_s_setprio(1);
#pragma unroll
      for (int i = 0; i < 4; ++i)
#pragma unroll
        for (int ni = 0; ni < 4; ++ni)
          acc[mh*4 + i][ni] = __builtin_amdgcn_mfma_f32_16x16x32_bf16(af[i], bfr[ni], acc[mh*4 + i][ni], 0, 0, 0);
      __builtin_amdgcn_s_setprio(0);
      wg_barrier();
    }
  }

#pragma unroll
  for (int mi = 0; mi < 8; ++mi) {
#pragma unroll
    for (int ni = 0; ni < 4; ++ni) {
      const int n = n0 + wn*64 + ni*16 + lc;
      const int mbase = m0 + wm*128 + mi*16 + (g << 2);
      if (EPI == 4) {
        const float bia = bias[n];
        if (n < 2048) {
#pragma unroll
          for (int e = 0; e < 4; ++e)
            outb[(size_t)(mbase + e) * 2048 + n] = f2b(acc[mi][ni][e] + bia);
        } else {
          const int hh = (n - 2048) >> 8, dim = (n - 2048) & 255;
          const int bidx = mbase >> 11, t = mbase & 2047;
          const u16 a0 = f2b(acc[mi][ni][0] + bia);
          const u16 a1 = f2b(acc[mi][ni][1] + bia);
          const u16 a2 = f2b(acc[mi][ni][2] + bia);
          const u16 a3 = f2b(acc[mi][ni][3] + bia);
          uint2 pk;
          pk.x = (unsigned)a0 | ((unsigned)a1 << 16);
          pk.y = (unsigned)a2 | ((unsigned)a3 << 16);
          u16* vtp = (u16*)outf;
          *(uint2*)(vtp + ((size_t)((bidx*4 + hh)*256 + dim)) * 2048 + t) = pk;
        }
      } else if (EPI == 5) {
        const float bia = (n < 1024) ? bias[n] : bias2[n - 1024];
        u16* dst = (n < 1024) ? outb : (u16*)outf;
        const int nn = n & 1023;
#pragma unroll
        for (int e = 0; e < 4; ++e)
          dst[(size_t)(mbase + e) * 1024 + nn] = f2b(acc[mi][ni][e] + bia);
      } else {  // EPI == 2
        const float bia = bias[n];
#pragma unroll
        for (int e = 0; e < 4; ++e) {
          const float v = acc[mi][ni][e] + bia;
          const float zc = fminf(fmaxf(1.5957691216f * (v + 0.044715f*v*v*v), -30.f), 30.f);
          outb[(size_t)(mbase + e) * N + n] = f2b(v / (1.f + __expf(-zc)));
        }
      }
    }
  }
}

// ---------------- 128x128 bf16 MFMA GEMM (N=1024 cases), 2-phase, proven ----------
// EPI: 3 = f32 residual add
template<int EPI>
__global__ __launch_bounds__(256)
void gemm_k(const u16* __restrict__ A, const u16* __restrict__ Wt,
            const float* __restrict__ bias, float* __restrict__ outf, int K, int N) {
  __shared__ u16 As[2][8192];   // [128][64] per buffer
  __shared__ u16 Bs[2][8192];
  const int tid = threadIdx.x;
  const int gx = gridDim.x;
  const int nwg = gx * (int)gridDim.y;
  int lid = (int)blockIdx.y * gx + (int)blockIdx.x;
  lid = (lid & 7) * (nwg >> 3) + (lid >> 3);
  const int m0 = (lid / gx) << 7;
  const int n0 = (lid % gx) << 7;
  const int lane = tid & 63;
  const int wm = (tid >> 7) & 1;
  const int wn = (tid >> 6) & 1;
  const int g = lane >> 4;
  const int lc = lane & 15;
  const int sw = lc & 7;
  const int rowst = tid >> 3;
  const int aslot = (tid & 7) ^ (rowst & 7);

  const u16* Abase = A  + (size_t)m0 * K;
  const u16* Bbase = Wt + (size_t)n0 * K;

  auto stage = [&](int kt, int buf) {
    const int ko = (kt << 6) + (aslot << 3);
#pragma unroll
    for (int i = 0; i < 4; ++i) {
      GLD16(Abase + (size_t)(i*32 + rowst) * K + ko, As[buf] + (i*256 + tid)*8);
      GLD16(Bbase + (size_t)(i*32 + rowst) * K + ko, Bs[buf] + (i*256 + tid)*8);
    }
  };

  f32x4 acc[4][4];
#pragma unroll
  for (int i = 0; i < 4; ++i)
#pragma unroll
    for (int j = 0; j < 4; ++j)
#pragma unroll
      for (int e = 0; e < 4; ++e) acc[i][j][e] = 0.f;

  const int KT = K >> 6;
  stage(0, 0);
  stage(1, 1);
  for (int kt = 0; kt < KT; ++kt) {
    const int cur = kt & 1;
    if (kt + 1 < KT) asm volatile("s_waitcnt vmcnt(8)" ::: "memory");
    else             asm volatile("s_waitcnt vmcnt(0)" ::: "memory");
    __builtin_amdgcn_s_barrier();
    asm volatile("" ::: "memory");
    const u16* Ac = As[cur];
    const u16* Bc = Bs[cur];
#pragma unroll
    for (int kk = 0; kk < 2; ++kk) {
      const int ko = ((kk*4 + g) ^ sw) << 3;
      bf16x8 af[4], bfr[4];
#pragma unroll
      for (int mi = 0; mi < 4; ++mi)
        af[mi] = *(const bf16x8*)(Ac + ((wm*64 + mi*16 + lc) << 6) + ko);
#pragma unroll
      for (int ni = 0; ni < 4; ++ni)
        bfr[ni] = *(const bf16x8*)(Bc + ((wn*64 + ni*16 + lc) << 6) + ko);
      __builtin_amdgcn_s_setprio(1);
#pragma unroll
      for (int mi = 0; mi < 4; ++mi)
#pragma unroll
        for (int ni = 0; ni < 4; ++ni)
          acc[mi][ni] = __builtin_amdgcn_mfma_f32_16x16x32_bf16(af[mi], bfr[ni], acc[mi][ni], 0, 0, 0);
      __builtin_amdgcn_s_setprio(0);
    }
    wg_barrier();
    if (kt + 2 < KT) stage(kt + 2, cur);
  }

#pragma unroll
  for (int mi = 0; mi < 4; ++mi) {
#pragma unroll
    for (int ni = 0; ni < 4; ++ni) {
      const int n = n0 + (wn << 6) + ni*16 + lc;
      const int mbase = m0 + (wm << 6) + mi*16 + (g << 2);
      const float bia = bias[n];
#pragma unroll
      for (int e = 0; e < 4; ++e)
        outf[(size_t)(mbase + e) * N + n] += acc[mi][ni][e] + bia;
    }
  }
}

// ---------------- RG-LRU chunked scan (bf16 z,u inputs): h_t = g*h_{t-1} + (1-g)*u ----
__global__ __launch_bounds__(256)
void scan1_k(const u16* __restrict__ zpre, const u16* __restrict__ u,
             float* __restrict__ aggA, float* __restrict__ aggB) {
  const int d = blockIdx.x * 256 + threadIdx.x;
  const int c = blockIdx.y, b = blockIdx.z;
  const size_t base = ((size_t)b * TT + (size_t)c * CHUNK) * DD + d;
  float a = 1.f, acc = 0.f;
  for (int t = 0; t < CHUNK; ++t) {
    const float gl = 1.f / (1.f + __expf(-b2f(zpre[base + (size_t)t * DD])));
    const float ul = b2f(u[base + (size_t)t * DD]);
    acc = gl * acc + (1.f - gl) * ul;
    a *= gl;
  }
  const size_t o = ((size_t)b * NCHUNK + c) * DD + d;
  aggA[o] = a; aggB[o] = acc;
}

__global__ __launch_bounds__(256)
void scan2_k(const float* __restrict__ aggA, const float* __restrict__ aggB,
             float* __restrict__ carry) {
  const int idx = blockIdx.x * 256 + threadIdx.x;  // b*DD + d
  const int b = idx >> 10, d = idx & 1023;
  float h = 0.f;
  for (int c = 0; c < NCHUNK; ++c) {
    const size_t o = ((size_t)b * NCHUNK + c) * DD + d;
    carry[o] = h;
    h = aggA[o] * h + aggB[o];
  }
}

__global__ __launch_bounds__(256)
void scan3_k(const u16* __restrict__ zpre, const u16* __restrict__ u,
             const float* __restrict__ carry, u16* __restrict__ hout) {
  const int d = blockIdx.x * 256 + threadIdx.x;
  const int c = blockIdx.y, b = blockIdx.z;
  const size_t base = ((size_t)b * TT + (size_t)c * CHUNK) * DD + d;
  float h = carry[((size_t)b * NCHUNK + c) * DD + d];
  for (int t = 0; t < CHUNK; ++t) {
    const float gl = 1.f / (1.f + __expf(-b2f(zpre[base + (size_t)t * DD])));
    const float ul = b2f(u[base + (size_t)t * DD]);
    h = gl * h + (1.f - gl) * ul;
    hout[base + (size_t)t * DD] = f2b(h);
  }
}

// ---------------- MFMA local-window attention ----------------
__global__ __launch_bounds__(256)
void attn_mfma(const u16* __restrict__ qkb, const u16* __restrict__ vt,
               u16* __restrict__ y) {
  __shared__ u16 kv[16384];
  __shared__ u16 pb[4][16][200];
  const int tid = threadIdx.x;
  const int lane = tid & 63;
  const int wid = tid >> 6;
  const int g = lane >> 4;
  const int lc = lane & 15;
  const int t0 = blockIdx.x << 6;
  const int bh = blockIdx.y;
  const int bT = (bh >> 2) * TT;
  const int h = bh & 3;

  bf16x8 afq[8];
  {
    const u16* qg = qkb + (size_t)(bT + t0 + wid*16 + lc) * 2048 + h*256 + g*8;
#pragma unroll
    for (int ks = 0; ks < 8; ++ks)
      afq[ks] = __builtin_bit_cast(bf16x8, *(const uint4*)(qg + ks*32));
  }

  f32x4 sc[12];
#pragma unroll
  for (int f = 0; f < 12; ++f)
#pragma unroll
    for (int e = 0; e < 4; ++e) sc[f][e] = 0.f;

  const int koff = 1024 + h*256;
#pragma unroll
  for (int c = 0; c < 3; ++c) {
    const int j0 = t0 + (c - 2) * 64;
    if (j0 < 0) {
#pragma unroll
      for (int nt = 0; nt < 4; ++nt)
#pragma unroll
        for (int e = 0; e < 4; ++e) sc[c*4+nt][e] = -1e30f;
      continue;
    }
    __syncthreads();
    {
      const u16* kg = qkb + (size_t)(bT + j0) * 2048 + koff;
#pragma unroll
      for (int i = 0; i < 8; ++i) {
        const int o16 = i*256 + tid;
        const int slab = o16 >> 8, key = (o16 >> 2) & 63, ds = o16 & 3;
        GLD16(kg + (size_t)key*2048 + slab*32 + ds*8, kv + o16*8);
      }
    }
    __syncthreads();
#pragma unroll
    for (int nt = 0; nt < 4; ++nt) {
      f32x4 s = sc[c*4+nt];
#pragma unroll
      for (int ks = 0; ks < 8; ++ks) {
        const bf16x8 kb = *(const bf16x8*)(kv + ks*2048 + (nt*16 + lc)*32 + g*8);
        s = __builtin_amdgcn_mfma_f32_16x16x32_bf16(afq[ks], kb, s, 0, 0, 0);
      }
      sc[c*4+nt] = s;
    }
#pragma unroll
    for (int nt = 0; nt < 4; ++nt)
#pragma unroll
      for (int e = 0; e < 4; ++e) {
        const int tl = wid*16 + g*4 + e;
        const int jl = nt*16 + lc;
        const bool ok = (c == 1) || (c == 2 ? (jl <= tl) : (jl >= tl + 1));
        sc[c*4+nt][e] = ok ? sc[c*4+nt][e] * 0.0625f : -1e30f;
      }
  }

#pragma unroll
  for (int e = 0; e < 4; ++e) {
    float m = -1e30f;
#pragma unroll
    for (int f = 0; f < 12; ++f) m = fmaxf(m, sc[f][e]);
    m = fmaxf(m, __shfl_xor(m, 1)); m = fmaxf(m, __shfl_xor(m, 2));
    m = fmaxf(m, __shfl_xor(m, 4)); m = fmaxf(m, __shfl_xor(m, 8));
    float s = 0.f;
#pragma unroll
    for (int f = 0; f < 12; ++f) { const float p = __expf(sc[f][e] - m); sc[f][e] = p; s += p; }
    s += __shfl_xor(s, 1); s += __shfl_xor(s, 2);
    s += __shfl_xor(s, 4); s += __shfl_xor(s, 8);
    const float is = 1.f / s;
#pragma unroll
    for (int f = 0; f < 12; ++f) sc[f][e] *= is;
  }
#pragma unroll
  for (int c = 0; c < 3; ++c)
#pragma unroll
    for (int nt = 0; nt < 4; ++nt)
#pragma unroll
      for (int e = 0; e < 4; ++e)
        pb[wid][g*4 + e][c*64 + nt*16 + lc] = f2b(sc[c*4+nt][e]);

  f32x4 acc[16];
#pragma unroll
  for (int nt = 0; nt < 16; ++nt)
#pragma unroll
    for (int e = 0; e < 4; ++e) acc[nt][e] = 0.f;

  const u16* vg = vt + (size_t)bh * 256 * 2048;
#pragma unroll
  for (int c = 0; c < 3; ++c) {
    const int j0 = t0 + (c - 2) * 64;
    if (j0 < 0) continue;
    __syncthreads();
#pragma unroll
    for (int i = 0; i < 8; ++i) {
      const int o16 = i*256 + tid;
      const int dim = o16 >> 3, slot = o16 & 7;
      const int ss = slot ^ (dim & 7);
      GLD16(vg + (size_t)dim*2048 + j0 + ss*8, kv + o16*8);
    }
    __syncthreads();
#pragma unroll
    for (int ks = 0; ks < 2; ++ks) {
      const bf16x8 pa = *(const bf16x8*)&pb[wid][lc][(c*2 + ks)*32 + g*8];
#pragma unroll
      for (int nt = 0; nt < 16; ++nt) {
        const int dim = nt*16 + lc;
        int boff = dim*128 + ks*64 + g*16;
        boff ^= (dim & 7) << 4;
        const bf16x8 vb = *(const bf16x8*)((const char*)kv + boff);
        acc[nt] = __builtin_amdgcn_mfma_f32_16x16x32_bf16(pa, vb, acc[nt], 0, 0, 0);
      }
    }
  }

#pragma unroll
  for (int nt = 0; nt < 16; ++nt)
#pragma unroll
    for (int e = 0; e < 4; ++e) {
      const int tok = bT + t0 + wid*16 + g*4 + e;
      y[(size_t)tok * 1024 + h*256 + nt*16 + lc] = f2b(acc[nt][e]);
    }
}

// ---------------- host orchestration ----------------
extern "C" void kernel_launch(void* const* d_in, const int* in_sizes, int n_in,
                              void* d_out, int out_size, void* d_ws, size_t ws_size,
                              hipStream_t stream) {
  const float* x_in      = (const float*)d_in[0];
  const float* ln1_s     = (const float*)d_in[1];
  const float* ln1_b     = (const float*)d_in[2];
  const float* ln2_s     = (const float*)d_in[3];
  const float* ln2_b     = (const float*)d_in[4];
  const float* ln3_s     = (const float*)d_in[5];
  const float* ln3_b     = (const float*)d_in[6];
  const float* rg_in_w   = (const float*)d_in[7];
  const float* rg_in_b   = (const float*)d_in[8];
  const float* rg_gate_w = (const float*)d_in[9];
  const float* rg_gate_b = (const float*)d_in[10];
  const float* rg_out_w  = (const float*)d_in[11];
  const float* rg_out_b  = (const float*)d_in[12];
  const float* qkv_w     = (const float*)d_in[13];
  const float* qkv_b     = (const float*)d_in[14];
  const float* attn_out_w= (const float*)d_in[15];
  const float* attn_out_b= (const float*)d_in[16];
  const float* mlp_w1    = (const float*)d_in[17];
  const float* mlp_b1    = (const float*)d_in[18];
  const float* mlp_w2    = (const float*)d_in[19];
  const float* mlp_b2    = (const float*)d_in[20];

  hipFuncSetAttribute((const void*)&gemm256_k<5>, hipFuncAttributeMaxDynamicSharedMemorySize, 131072);
  hipFuncSetAttribute((const void*)&gemm256_k<4>, hipFuncAttributeMaxDynamicSharedMemorySize, 131072);
  hipFuncSetAttribute((const void*)&gemm256_k<2>, hipFuncAttributeMaxDynamicSharedMemorySize, 131072);

  float* x = (float*)d_out;
  char* ws = (char*)d_ws;
  u16*  wt     = (u16*)ws;                          // 62,914,560 B (bf16 transposed weights)
  u16*  xn     = (u16*)(ws + 62914560);             // 16,777,216 B
  char* bigS   = ws + 62914560 + 16777216;          // 67,108,864 B
  char* smallS = bigS + 67108864;                   // 16,777,216 B
  float* aggA  = (float*)(smallS + 16777216);
  float* aggB  = aggA + (size_t)BB * NCHUNK * DD;
  float* carry = aggB + (size_t)BB * NCHUNK * DD;

  u16* ubuf = (u16*)bigS;                           // RG phase (bf16)
  u16* zbuf = (u16*)(bigS + 33554432);              // pre-sigmoid gate, bf16
  u16* qkb  = (u16*)bigS;                           // attn phase: [8192][2048] QK
  u16* vtb  = (u16*)(bigS + 33554432);              // attn phase: V transposed, 16MB
  u16* hid  = (u16*)bigS;                           // MLP phase
  u16* hbuf = (u16*)smallS;
  u16* ybuf = (u16*)smallS;

  hipMemcpyAsync(x, x_in, (size_t)MM * DD * sizeof(float), hipMemcpyDeviceToDevice, stream);

  const size_t LW = 15728640;
  const dim3 tb(32, 8);
  for (int l = 0; l < NLAYER; ++l) {
    u16* base = wt + (size_t)l * LW;
    transpose_cvt<<<dim3(32, 32),  tb, 0, stream>>>(rg_in_w   + (size_t)l*DD*DD,   base + 0,        DD, DD);
    transpose_cvt<<<dim3(32, 32),  tb, 0, stream>>>(rg_gate_w + (size_t)l*DD*DD,   base + 1048576,  DD, DD);
    transpose_cvt<<<dim3(32, 32),  tb, 0, stream>>>(rg_out_w  + (size_t)l*DD*DD,   base + 2097152,  DD, DD);
    transpose_cvt<<<dim3(96, 32),  tb, 0, stream>>>(qkv_w     + (size_t)l*DD*3072, base + 3145728,  DD, 3072);
    transpose_cvt<<<dim3(32, 32),  tb, 0, stream>>>(attn_out_w+ (size_t)l*DD*DD,   base + 6291456,  DD, DD);
    transpose_cvt<<<dim3(128, 32), tb, 0, stream>>>(mlp_w1    + (size_t)l*DD*4096, base + 7340032,  DD, 4096);
    transpose_cvt<<<dim3(32, 128), tb, 0, stream>>>(mlp_w2    + (size_t)l*4096*DD, base + 11534336, 4096, DD);
  }

  for (int l = 0; l < NLAYER; ++l) {
    u16* base = wt + (size_t)l * LW;
    // ---- RG-LRU block (rg_in + rg_gate fused; u and pre-sigmoid z stored bf16)
    ln_k<<<MM, 256, 0, stream>>>(x, ln1_s + l*DD, ln1_b + l*DD, xn);
    gemm256_k<5><<<dim3(8, 32), 512, 131072, stream>>>(xn, base + 0, rg_in_b + l*DD, rg_gate_b + l*DD,
                                                       (float*)zbuf, ubuf, DD, 2048);
    scan1_k<<<dim3(4, NCHUNK, BB), 256, 0, stream>>>(zbuf, ubuf, aggA, aggB);
    scan2_k<<<16, 256, 0, stream>>>(aggA, aggB, carry);
    scan3_k<<<dim3(4, NCHUNK, BB), 256, 0, stream>>>(zbuf, ubuf, carry, hbuf);
    gemm_k<3><<<dim3(8, 64), 256, 0, stream>>>(hbuf, base + 2097152, rg_out_b + l*DD, x, DD, DD);
    // ---- local attention block
    ln_k<<<MM, 256, 0, stream>>>(x, ln2_s + l*DD, ln2_b + l*DD, xn);
    gemm256_k<4><<<dim3(12, 32), 512, 131072, stream>>>(xn, base + 3145728, qkv_b + l*3072, nullptr,
                                                        (float*)vtb, qkb, DD, 3072);
    attn_mfma<<<dim3(TT/64, BB*HH), 256, 0, stream>>>(qkb, vtb, ybuf);
    gemm_k<3><<<dim3(8, 64), 256, 0, stream>>>(ybuf, base + 6291456, attn_out_b + l*DD, x, DD, DD);
    // ---- MLP block
    ln_k<<<MM, 256, 0, stream>>>(x, ln3_s + l*DD, ln3_b + l*DD, xn);
    gemm256_k<2><<<dim3(16, 32), 512, 131072, stream>>>(xn, base + 7340032, mlp_b1 + l*4096, nullptr,
                                                        nullptr, hid, DD, 4096);
    gemm_k<3><<<dim3(8, 64), 256, 0, stream>>>(hid, base + 11534336, mlp_b2 + l*DD, x, 4096, DD);
  }
}

// Round 7
// 910.519 us; speedup vs baseline: 2.0165x; 1.0108x over previous
//
#include <hip/hip_runtime.h>
#include <math.h>

#define DD 1024
#define TT 2048
#define BB 4
#define HH 4
#define HDIM 256
#define NLAYER 2
#define MM (BB*TT)          // 8192 rows
#define NCHUNK 32
#define CHUNK (TT/NCHUNK)   // 64

typedef unsigned short u16;
typedef __bf16 bf16x8 __attribute__((ext_vector_type(8)));
typedef float f32x4 __attribute__((ext_vector_type(4)));

__device__ __forceinline__ float b2f(u16 h) {
  unsigned u = ((unsigned)h) << 16;
  return __builtin_bit_cast(float, u);
}
__device__ __forceinline__ u16 f2b(float f) {
  unsigned u = __builtin_bit_cast(unsigned, f);
  u += 0x7fffu + ((u >> 16) & 1u);
  return (u16)(u >> 16);
}

#define GLD16(g, l) __builtin_amdgcn_global_load_lds( \
    (__attribute__((address_space(1))) void*)(void*)(g), \
    (__attribute__((address_space(3))) void*)(l), 16, 0, 0)

__device__ __forceinline__ void wg_barrier() {
  asm volatile("" ::: "memory");
  __builtin_amdgcn_s_barrier();
  asm volatile("" ::: "memory");
}
template<int N> __device__ __forceinline__ void wait_vmcnt() {
  asm volatile("s_waitcnt vmcnt(%0)" :: "i"(N) : "memory");
}

// ---------------- weight fp32 -> bf16 transpose: Wt[N][K] = W[K][N] ----------------
__global__ __launch_bounds__(256)
void transpose_cvt(const float* __restrict__ W, u16* __restrict__ Wt, int K, int N) {
  __shared__ float tile[32][33];
  const int n0 = blockIdx.x << 5, k0 = blockIdx.y << 5;
  const int tx = threadIdx.x, ty = threadIdx.y;
#pragma unroll
  for (int i = 0; i < 4; ++i)
    tile[ty + i*8][tx] = W[(size_t)(k0 + ty + i*8) * N + n0 + tx];
  __syncthreads();
#pragma unroll
  for (int i = 0; i < 4; ++i)
    Wt[(size_t)(n0 + ty + i*8) * K + k0 + tx] = f2b(tile[tx][ty + i*8]);
}

// ---------------- LayerNorm (fp32 in, bf16 out) ----------------
__global__ __launch_bounds__(256)
void ln_k(const float* __restrict__ x, const float* __restrict__ sc,
          const float* __restrict__ bi, u16* __restrict__ xn) {
  const int row = blockIdx.x;
  const int tid = threadIdx.x;
  const float4 xv = ((const float4*)(x + (size_t)row * DD))[tid];
  float s = xv.x + xv.y + xv.z + xv.w;
  float q = xv.x*xv.x + xv.y*xv.y + xv.z*xv.z + xv.w*xv.w;
#pragma unroll
  for (int o = 1; o < 64; o <<= 1) { s += __shfl_xor(s, o); q += __shfl_xor(q, o); }
  __shared__ float rs[4], rq[4];
  if ((tid & 63) == 0) { rs[tid >> 6] = s; rq[tid >> 6] = q; }
  __syncthreads();
  s = rs[0] + rs[1] + rs[2] + rs[3];
  q = rq[0] + rq[1] + rq[2] + rq[3];
  const float mean = s * (1.f / DD);
  const float var = q * (1.f / DD) - mean * mean;
  const float rstd = rsqrtf(var + 1e-5f);
  const float4 sv = ((const float4*)sc)[tid];
  const float4 bv = ((const float4*)bi)[tid];
  const u16 o0 = f2b((xv.x - mean) * rstd * sv.x + bv.x);
  const u16 o1 = f2b((xv.y - mean) * rstd * sv.y + bv.y);
  const u16 o2 = f2b((xv.z - mean) * rstd * sv.z + bv.z);
  const u16 o3 = f2b((xv.w - mean) * rstd * sv.w + bv.w);
  uint2 pk;
  pk.x = (unsigned)o0 | ((unsigned)o1 << 16);
  pk.y = (unsigned)o2 | ((unsigned)o3 << 16);
  *(uint2*)(xn + (size_t)row * DD + (tid << 2)) = pk;
}

// ======== 256xBN 8-wave GEMM, counted-vmcnt pipeline, column-half parts ========
// C[M,N] = A[M,K]*Wt[N,K]^T + bias.  512 threads, dynamic LDS (128KB / 96KB).
// LDS layout per buffer: [2 col-halves][rows][32 cols]; swizzle slot' = chunk ^ ((row>>1)&3).
// Per K-tile: kk=0: wait vmcnt(PAIR), barrier, frags, stage next c0, MFMA mh0, MFMA mh1;
//             kk=1: wait vmcnt(PAIR | 0-last), barrier, ..., stage next c1, MFMA; end barrier.
// EPI: 2 = bf16 gelu store, 3 = f32 residual add, 4 = qkv split (QK rowmajor + V^T),
//      5 = dual bf16 store (n<1024 -> outb, else outf)
template<int EPI, int BN>
__global__ __launch_bounds__(512)
void gemm256t(const u16* __restrict__ A, const u16* __restrict__ Wt,
              const float* __restrict__ bias, const float* __restrict__ bias2,
              float* __restrict__ outf, u16* __restrict__ outb, int K, int N) {
  constexpr int NI = BN / 64;               // n-frags per wave (4 or 2)
  constexpr int PAIR = 2 + BN / 128;        // GLD16 insts per column-half pair (A + B)
  extern __shared__ u16 lds[];
  u16* Al = lds;                            // [2 buf][2 ch][256][32]
  u16* Bl = lds + 32768;                    // [2 buf][2 ch][BN][32]
  const int tid = threadIdx.x;
  const int gx = gridDim.x;
  const int nwg = gx * (int)gridDim.y;
  int lid = (int)blockIdx.y * gx + (int)blockIdx.x;
  lid = (lid & 7) * (nwg >> 3) + (lid >> 3);     // XCD-chunked (nwg % 8 == 0)
  const int m0 = (lid / gx) << 8;
  const int n0 = (lid % gx) * BN;
  const int lane = tid & 63;
  const int wid = tid >> 6;
  const int wm = wid >> 2;          // m-half (128 rows)
  const int wn = wid & 3;           // n-quarter (NI*16 cols)
  const int g = lane >> 4;
  const int lc = lane & 15;
  const int rkey = (lc >> 1) & 3;   // read-side swizzle key ((row>>1)&3, row base mult of 16)
  const int q = tid >> 2;           // staging row 0..127
  const int sslot = tid & 3;
  const int skey = (q >> 1) & 3;
  const int scs = (sslot ^ skey) << 3;   // inverse-swizzled source chunk (bf16 elems)

  // stage one column-half pair (A rows 0..255, B rows 0..BN) of tile kt into buf
  auto stage_pair = [&](int kt, int buf, int ch) {
    const int kbase = (kt << 6) + (ch << 5);
#pragma unroll
    for (int i = 0; i < 2; ++i) {
      const int row = i*128 + q;
      GLD16(A + (size_t)(m0 + row) * K + kbase + scs,
            Al + buf*16384 + ch*8192 + i*4096 + tid*8);
    }
#pragma unroll
    for (int i = 0; i < BN/128; ++i) {
      const int row = i*128 + q;
      GLD16(Wt + (size_t)(n0 + row) * K + kbase + scs,
            Bl + buf*(BN*64) + ch*(BN*32) + i*4096 + tid*8);
    }
  };

  f32x4 acc[8][NI];
#pragma unroll
  for (int i = 0; i < 8; ++i)
#pragma unroll
    for (int j = 0; j < NI; ++j)
#pragma unroll
      for (int e = 0; e < 4; ++e) acc[i][j][e] = 0.f;

  const int KT = K >> 6;
  stage_pair(0, 0, 0);
  stage_pair(0, 0, 1);

  for (int kt = 0; kt < KT; ++kt) {
    const int cur = kt & 1;
    const bool more = (kt + 1 < KT);
#pragma unroll
    for (int kk = 0; kk < 2; ++kk) {
      if (kk == 0) wait_vmcnt<PAIR>();
      else if (more) wait_vmcnt<PAIR>();
      else wait_vmcnt<0>();
      wg_barrier();
      const int so = (g ^ rkey) << 3;     // swizzled 16B slot within 32-col half
      const u16* Ab = Al + cur*16384 + kk*8192;
      const u16* Bb = Bl + cur*(BN*64) + kk*(BN*32);
      bf16x8 bfr[NI];
#pragma unroll
      for (int ni = 0; ni < NI; ++ni)
        bfr[ni] = *(const bf16x8*)(Bb + (wn*(NI*16) + ni*16 + lc)*32 + so);
      bf16x8 af0[4];
#pragma unroll
      for (int i = 0; i < 4; ++i)
        af0[i] = *(const bf16x8*)(Ab + (wm*128 + i*16 + lc)*32 + so);
      if (more) stage_pair(kt + 1, cur ^ 1, kk);
      __builtin_amdgcn_s_setprio(1);
#pragma unroll
      for (int i = 0; i < 4; ++i)
#pragma unroll
        for (int ni = 0; ni < NI; ++ni)
          acc[i][ni] = __builtin_amdgcn_mfma_f32_16x16x32_bf16(af0[i], bfr[ni], acc[i][ni], 0, 0, 0);
      __builtin_amdgcn_s_setprio(0);
      bf16x8 af1[4];
#pragma unroll
      for (int i = 0; i < 4; ++i)
        af1[i] = *(const bf16x8*)(Ab + (wm*128 + 64 + i*16 + lc)*32 + so);
      __builtin_amdgcn_s_setprio(1);
#pragma unroll
      for (int i = 0; i < 4; ++i)
#pragma unroll
        for (int ni = 0; ni < NI; ++ni)
          acc[4 + i][ni] = __builtin_amdgcn_mfma_f32_16x16x32_bf16(af1[i], bfr[ni], acc[4 + i][ni], 0, 0, 0);
      __builtin_amdgcn_s_setprio(0);
    }
    wg_barrier();   // end-of-tile isolation
  }

#pragma unroll
  for (int mi = 0; mi < 8; ++mi) {
#pragma unroll
    for (int ni = 0; ni < NI; ++ni) {
      const int n = n0 + wn*(NI*16) + ni*16 + lc;
      // acc rows: mi<4 -> wm*128 + mi*16 sub-block 0; mi>=4 -> +64
      const int mbase = m0 + wm*128 + (mi & 3)*16 + (mi >> 2)*64 + (g << 2);
      if (EPI == 4) {
        const float bia = bias[n];
        if (n < 2048) {
#pragma unroll
          for (int e = 0; e < 4; ++e)
            outb[(size_t)(mbase + e) * 2048 + n] = f2b(acc[mi][ni][e] + bia);
        } else {
          const int hh = (n - 2048) >> 8, dim = (n - 2048) & 255;
          const int bidx = mbase >> 11, t = mbase & 2047;
          const u16 a0 = f2b(acc[mi][ni][0] + bia);
          const u16 a1 = f2b(acc[mi][ni][1] + bia);
          const u16 a2 = f2b(acc[mi][ni][2] + bia);
          const u16 a3 = f2b(acc[mi][ni][3] + bia);
          uint2 pk;
          pk.x = (unsigned)a0 | ((unsigned)a1 << 16);
          pk.y = (unsigned)a2 | ((unsigned)a3 << 16);
          u16* vtp = (u16*)outf;
          *(uint2*)(vtp + ((size_t)((bidx*4 + hh)*256 + dim)) * 2048 + t) = pk;
        }
      } else if (EPI == 5) {
        const float bia = (n < 1024) ? bias[n] : bias2[n - 1024];
        u16* dst = (n < 1024) ? outb : (u16*)outf;
        const int nn = n & 1023;
#pragma unroll
        for (int e = 0; e < 4; ++e)
          dst[(size_t)(mbase + e) * 1024 + nn] = f2b(acc[mi][ni][e] + bia);
      } else if (EPI == 2) {
        const float bia = bias[n];
#pragma unroll
        for (int e = 0; e < 4; ++e) {
          const float v = acc[mi][ni][e] + bia;
          const float zc = fminf(fmaxf(1.5957691216f * (v + 0.044715f*v*v*v), -30.f), 30.f);
          outb[(size_t)(mbase + e) * N + n] = f2b(v / (1.f + __expf(-zc)));
        }
      } else {  // EPI == 3: f32 residual add
        const float bia = bias[n];
#pragma unroll
        for (int e = 0; e < 4; ++e)
          outf[(size_t)(mbase + e) * N + n] += acc[mi][ni][e] + bia;
      }
    }
  }
}

// ---------------- RG-LRU chunked scan (bf16 z,u inputs): h_t = g*h_{t-1} + (1-g)*u ----
__global__ __launch_bounds__(256)
void scan1_k(const u16* __restrict__ zpre, const u16* __restrict__ u,
             float* __restrict__ aggA, float* __restrict__ aggB) {
  const int d = blockIdx.x * 256 + threadIdx.x;
  const int c = blockIdx.y, b = blockIdx.z;
  const size_t base = ((size_t)b * TT + (size_t)c * CHUNK) * DD + d;
  float a = 1.f, acc = 0.f;
  for (int t = 0; t < CHUNK; ++t) {
    const float gl = 1.f / (1.f + __expf(-b2f(zpre[base + (size_t)t * DD])));
    const float ul = b2f(u[base + (size_t)t * DD]);
    acc = gl * acc + (1.f - gl) * ul;
    a *= gl;
  }
  const size_t o = ((size_t)b * NCHUNK + c) * DD + d;
  aggA[o] = a; aggB[o] = acc;
}

__global__ __launch_bounds__(256)
void scan2_k(const float* __restrict__ aggA, const float* __restrict__ aggB,
             float* __restrict__ carry) {
  const int idx = blockIdx.x * 256 + threadIdx.x;  // b*DD + d
  const int b = idx >> 10, d = idx & 1023;
  float h = 0.f;
  for (int c = 0; c < NCHUNK; ++c) {
    const size_t o = ((size_t)b * NCHUNK + c) * DD + d;
    carry[o] = h;
    h = aggA[o] * h + aggB[o];
  }
}

__global__ __launch_bounds__(256)
void scan3_k(const u16* __restrict__ zpre, const u16* __restrict__ u,
             const float* __restrict__ carry, u16* __restrict__ hout) {
  const int d = blockIdx.x * 256 + threadIdx.x;
  const int c = blockIdx.y, b = blockIdx.z;
  const size_t base = ((size_t)b * TT + (size_t)c * CHUNK) * DD + d;
  float h = carry[((size_t)b * NCHUNK + c) * DD + d];
  for (int t = 0; t < CHUNK; ++t) {
    const float gl = 1.f / (1.f + __expf(-b2f(zpre[base + (size_t)t * DD])));
    const float ul = b2f(u[base + (size_t)t * DD]);
    h = gl * h + (1.f - gl) * ul;
    hout[base + (size_t)t * DD] = f2b(h);
  }
}

// ---------------- MFMA local-window attention ----------------
__global__ __launch_bounds__(256)
void attn_mfma(const u16* __restrict__ qkb, const u16* __restrict__ vt,
               u16* __restrict__ y) {
  __shared__ u16 kv[16384];
  __shared__ u16 pb[4][16][200];
  const int tid = threadIdx.x;
  const int lane = tid & 63;
  const int wid = tid >> 6;
  const int g = lane >> 4;
  const int lc = lane & 15;
  const int t0 = blockIdx.x << 6;
  const int bh = blockIdx.y;
  const int bT = (bh >> 2) * TT;
  const int h = bh & 3;

  bf16x8 afq[8];
  {
    const u16* qg = qkb + (size_t)(bT + t0 + wid*16 + lc) * 2048 + h*256 + g*8;
#pragma unroll
    for (int ks = 0; ks < 8; ++ks)
      afq[ks] = __builtin_bit_cast(bf16x8, *(const uint4*)(qg + ks*32));
  }

  f32x4 sc[12];
#pragma unroll
  for (int f = 0; f < 12; ++f)
#pragma unroll
    for (int e = 0; e < 4; ++e) sc[f][e] = 0.f;

  const int koff = 1024 + h*256;
#pragma unroll
  for (int c = 0; c < 3; ++c) {
    const int j0 = t0 + (c - 2) * 64;
    if (j0 < 0) {
#pragma unroll
      for (int nt = 0; nt < 4; ++nt)
#pragma unroll
        for (int e = 0; e < 4; ++e) sc[c*4+nt][e] = -1e30f;
      continue;
    }
    __syncthreads();
    {
      const u16* kg = qkb + (size_t)(bT + j0) * 2048 + koff;
#pragma unroll
      for (int i = 0; i < 8; ++i) {
        const int o16 = i*256 + tid;
        const int slab = o16 >> 8, key = (o16 >> 2) & 63, ds = o16 & 3;
        GLD16(kg + (size_t)key*2048 + slab*32 + ds*8, kv + o16*8);
      }
    }
    __syncthreads();
#pragma unroll
    for (int nt = 0; nt < 4; ++nt) {
      f32x4 s = sc[c*4+nt];
#pragma unroll
      for (int ks = 0; ks < 8; ++ks) {
        const bf16x8 kb = *(const bf16x8*)(kv + ks*2048 + (nt*16 + lc)*32 + g*8);
        s = __builtin_amdgcn_mfma_f32_16x16x32_bf16(afq[ks], kb, s, 0, 0, 0);
      }
      sc[c*4+nt] = s;
    }
#pragma unroll
    for (int nt = 0; nt < 4; ++nt)
#pragma unroll
      for (int e = 0; e < 4; ++e) {
        const int tl = wid*16 + g*4 + e;
        const int jl = nt*16 + lc;
        const bool ok = (c == 1) || (c == 2 ? (jl <= tl) : (jl >= tl + 1));
        sc[c*4+nt][e] = ok ? sc[c*4+nt][e] * 0.0625f : -1e30f;
      }
  }

#pragma unroll
  for (int e = 0; e < 4; ++e) {
    float m = -1e30f;
#pragma unroll
    for (int f = 0; f < 12; ++f) m = fmaxf(m, sc[f][e]);
    m = fmaxf(m, __shfl_xor(m, 1)); m = fmaxf(m, __shfl_xor(m, 2));
    m = fmaxf(m, __shfl_xor(m, 4)); m = fmaxf(m, __shfl_xor(m, 8));
    float s = 0.f;
#pragma unroll
    for (int f = 0; f < 12; ++f) { const float p = __expf(sc[f][e] - m); sc[f][e] = p; s += p; }
    s += __shfl_xor(s, 1); s += __shfl_xor(s, 2);
    s += __shfl_xor(s, 4); s += __shfl_xor(s, 8);
    const float is = 1.f / s;
#pragma unroll
    for (int f = 0; f < 12; ++f) sc[f][e] *= is;
  }
#pragma unroll
  for (int c = 0; c < 3; ++c)
#pragma unroll
    for (int nt = 0; nt < 4; ++nt)
#pragma unroll
      for (int e = 0; e < 4; ++e)
        pb[wid][g*4 + e][c*64 + nt*16 + lc] = f2b(sc[c*4+nt][e]);

  f32x4 acc[16];
#pragma unroll
  for (int nt = 0; nt < 16; ++nt)
#pragma unroll
    for (int e = 0; e < 4; ++e) acc[nt][e] = 0.f;

  const u16* vg = vt + (size_t)bh * 256 * 2048;
#pragma unroll
  for (int c = 0; c < 3; ++c) {
    const int j0 = t0 + (c - 2) * 64;
    if (j0 < 0) continue;
    __syncthreads();
#pragma unroll
    for (int i = 0; i < 8; ++i) {
      const int o16 = i*256 + tid;
      const int dim = o16 >> 3, slot = o16 & 7;
      const int ss = slot ^ (dim & 7);
      GLD16(vg + (size_t)dim*2048 + j0 + ss*8, kv + o16*8);
    }
    __syncthreads();
#pragma unroll
    for (int ks = 0; ks < 2; ++ks) {
      const bf16x8 pa = *(const bf16x8*)&pb[wid][lc][(c*2 + ks)*32 + g*8];
#pragma unroll
      for (int nt = 0; nt < 16; ++nt) {
        const int dim = nt*16 + lc;
        int boff = dim*128 + ks*64 + g*16;
        boff ^= (dim & 7) << 4;
        const bf16x8 vb = *(const bf16x8*)((const char*)kv + boff);
        acc[nt] = __builtin_amdgcn_mfma_f32_16x16x32_bf16(pa, vb, acc[nt], 0, 0, 0);
      }
    }
  }

#pragma unroll
  for (int nt = 0; nt < 16; ++nt)
#pragma unroll
    for (int e = 0; e < 4; ++e) {
      const int tok = bT + t0 + wid*16 + g*4 + e;
      y[(size_t)tok * 1024 + h*256 + nt*16 + lc] = f2b(acc[nt][e]);
    }
}

// ---------------- host orchestration ----------------
extern "C" void kernel_launch(void* const* d_in, const int* in_sizes, int n_in,
                              void* d_out, int out_size, void* d_ws, size_t ws_size,
                              hipStream_t stream) {
  const float* x_in      = (const float*)d_in[0];
  const float* ln1_s     = (const float*)d_in[1];
  const float* ln1_b     = (const float*)d_in[2];
  const float* ln2_s     = (const float*)d_in[3];
  const float* ln2_b     = (const float*)d_in[4];
  const float* ln3_s     = (const float*)d_in[5];
  const float* ln3_b     = (const float*)d_in[6];
  const float* rg_in_w   = (const float*)d_in[7];
  const float* rg_in_b   = (const float*)d_in[8];
  const float* rg_gate_w = (const float*)d_in[9];
  const float* rg_gate_b = (const float*)d_in[10];
  const float* rg_out_w  = (const float*)d_in[11];
  const float* rg_out_b  = (const float*)d_in[12];
  const float* qkv_w     = (const float*)d_in[13];
  const float* qkv_b     = (const float*)d_in[14];
  const float* attn_out_w= (const float*)d_in[15];
  const float* attn_out_b= (const float*)d_in[16];
  const float* mlp_w1    = (const float*)d_in[17];
  const float* mlp_b1    = (const float*)d_in[18];
  const float* mlp_w2    = (const float*)d_in[19];
  const float* mlp_b2    = (const float*)d_in[20];

  hipFuncSetAttribute((const void*)&gemm256t<5,256>, hipFuncAttributeMaxDynamicSharedMemorySize, 131072);
  hipFuncSetAttribute((const void*)&gemm256t<4,256>, hipFuncAttributeMaxDynamicSharedMemorySize, 131072);
  hipFuncSetAttribute((const void*)&gemm256t<2,256>, hipFuncAttributeMaxDynamicSharedMemorySize, 131072);
  hipFuncSetAttribute((const void*)&gemm256t<3,128>, hipFuncAttributeMaxDynamicSharedMemorySize, 98304);

  float* x = (float*)d_out;
  char* ws = (char*)d_ws;
  u16*  wt     = (u16*)ws;                          // 62,914,560 B (bf16 transposed weights)
  u16*  xn     = (u16*)(ws + 62914560);             // 16,777,216 B
  char* bigS   = ws + 62914560 + 16777216;          // 67,108,864 B
  char* smallS = bigS + 67108864;                   // 16,777,216 B
  float* aggA  = (float*)(smallS + 16777216);
  float* aggB  = aggA + (size_t)BB * NCHUNK * DD;
  float* carry = aggB + (size_t)BB * NCHUNK * DD;

  u16* ubuf = (u16*)bigS;                           // RG phase (bf16)
  u16* zbuf = (u16*)(bigS + 33554432);              // pre-sigmoid gate, bf16
  u16* qkb  = (u16*)bigS;                           // attn phase: [8192][2048] QK
  u16* vtb  = (u16*)(bigS + 33554432);              // attn phase: V transposed, 16MB
  u16* hid  = (u16*)bigS;                           // MLP phase
  u16* hbuf = (u16*)smallS;
  u16* ybuf = (u16*)smallS;

  hipMemcpyAsync(x, x_in, (size_t)MM * DD * sizeof(float), hipMemcpyDeviceToDevice, stream);

  const size_t LW = 15728640;
  const dim3 tb(32, 8);
  for (int l = 0; l < NLAYER; ++l) {
    u16* base = wt + (size_t)l * LW;
    transpose_cvt<<<dim3(32, 32),  tb, 0, stream>>>(rg_in_w   + (size_t)l*DD*DD,   base + 0,        DD, DD);
    transpose_cvt<<<dim3(32, 32),  tb, 0, stream>>>(rg_gate_w + (size_t)l*DD*DD,   base + 1048576,  DD, DD);
    transpose_cvt<<<dim3(32, 32),  tb, 0, stream>>>(rg_out_w  + (size_t)l*DD*DD,   base + 2097152,  DD, DD);
    transpose_cvt<<<dim3(96, 32),  tb, 0, stream>>>(qkv_w     + (size_t)l*DD*3072, base + 3145728,  DD, 3072);
    transpose_cvt<<<dim3(32, 32),  tb, 0, stream>>>(attn_out_w+ (size_t)l*DD*DD,   base + 6291456,  DD, DD);
    transpose_cvt<<<dim3(128, 32), tb, 0, stream>>>(mlp_w1    + (size_t)l*DD*4096, base + 7340032,  DD, 4096);
    transpose_cvt<<<dim3(32, 128), tb, 0, stream>>>(mlp_w2    + (size_t)l*4096*DD, base + 11534336, 4096, DD);
  }

  for (int l = 0; l < NLAYER; ++l) {
    u16* base = wt + (size_t)l * LW;
    // ---- RG-LRU block (rg_in + rg_gate fused; u and pre-sigmoid z stored bf16)
    ln_k<<<MM, 256, 0, stream>>>(x, ln1_s + l*DD, ln1_b + l*DD, xn);
    gemm256t<5,256><<<dim3(8, 32), 512, 131072, stream>>>(xn, base + 0, rg_in_b + l*DD, rg_gate_b + l*DD,
                                                          (float*)zbuf, ubuf, DD, 2048);
    scan1_k<<<dim3(4, NCHUNK, BB), 256, 0, stream>>>(zbuf, ubuf, aggA, aggB);
    scan2_k<<<16, 256, 0, stream>>>(aggA, aggB, carry);
    scan3_k<<<dim3(4, NCHUNK, BB), 256, 0, stream>>>(zbuf, ubuf, carry, hbuf);
    gemm256t<3,128><<<dim3(8, 32), 512, 98304, stream>>>(hbuf, base + 2097152, rg_out_b + l*DD, nullptr,
                                                         x, nullptr, DD, 1024);
    // ---- local attention block
    ln_k<<<MM, 256, 0, stream>>>(x, ln2_s + l*DD, ln2_b + l*DD, xn);
    gemm256t<4,256><<<dim3(12, 32), 512, 131072, stream>>>(xn, base + 3145728, qkv_b + l*3072, nullptr,
                                                           (float*)vtb, qkb, DD, 3072);
    attn_mfma<<<dim3(TT/64, BB*HH), 256, 0, stream>>>(qkb, vtb, ybuf);
    gemm256t<3,128><<<dim3(8, 32), 512, 98304, stream>>>(ybuf, base + 6291456, attn_out_b + l*DD, nullptr,
                                                         x, nullptr, DD, 1024);
    // ---- MLP block
    ln_k<<<MM, 256, 0, stream>>>(x, ln3_s + l*DD, ln3_b + l*DD, xn);
    gemm256t<2,256><<<dim3(16, 32), 512, 131072, stream>>>(xn, base + 7340032, mlp_b1 + l*4096, nullptr,
                                                           nullptr, hid, DD, 4096);
    gemm256t<3,128><<<dim3(8, 32), 512, 98304, stream>>>(hid, base + 11534336, mlp_b2 + l*DD, nullptr,
                                                         x, nullptr, 4096, 1024);
  }
}

// Round 8
// 910.345 us; speedup vs baseline: 2.0168x; 1.0002x over previous
//
#include <hip/hip_runtime.h>
#include <math.h>

#define DD 1024
#define TT 2048
#define BB 4
#define HH 4
#define HDIM 256
#define NLAYER 2
#define MM (BB*TT)          // 8192 rows
#define NCHUNK 32
#define CHUNK (TT/NCHUNK)   // 64

typedef unsigned short u16;
typedef __bf16 bf16x8 __attribute__((ext_vector_type(8)));
typedef float f32x4 __attribute__((ext_vector_type(4)));

__device__ __forceinline__ float b2f(u16 h) {
  unsigned u = ((unsigned)h) << 16;
  return __builtin_bit_cast(float, u);
}
__device__ __forceinline__ u16 f2b(float f) {
  unsigned u = __builtin_bit_cast(unsigned, f);
  u += 0x7fffu + ((u >> 16) & 1u);
  return (u16)(u >> 16);
}

#define GLD16(g, l) __builtin_amdgcn_global_load_lds( \
    (__attribute__((address_space(1))) void*)(void*)(g), \
    (__attribute__((address_space(3))) void*)(l), 16, 0, 0)

__device__ __forceinline__ void wg_barrier() {
  asm volatile("" ::: "memory");
  __builtin_amdgcn_s_barrier();
  asm volatile("" ::: "memory");
}
template<int N> __device__ __forceinline__ void wait_vmcnt() {
  asm volatile("s_waitcnt vmcnt(%0)" :: "i"(N) : "memory");
}

// ---------------- weight fp32 -> bf16 transpose: Wt[N][K] = W[K][N] ----------------
__global__ __launch_bounds__(256)
void transpose_cvt(const float* __restrict__ W, u16* __restrict__ Wt, int K, int N) {
  __shared__ float tile[32][33];
  const int n0 = blockIdx.x << 5, k0 = blockIdx.y << 5;
  const int tx = threadIdx.x, ty = threadIdx.y;
#pragma unroll
  for (int i = 0; i < 4; ++i)
    tile[ty + i*8][tx] = W[(size_t)(k0 + ty + i*8) * N + n0 + tx];
  __syncthreads();
#pragma unroll
  for (int i = 0; i < 4; ++i)
    Wt[(size_t)(n0 + ty + i*8) * K + k0 + tx] = f2b(tile[tx][ty + i*8]);
}

// ---------------- LayerNorm (fp32 in, bf16 out) ----------------
__global__ __launch_bounds__(256)
void ln_k(const float* __restrict__ x, const float* __restrict__ sc,
          const float* __restrict__ bi, u16* __restrict__ xn) {
  const int row = blockIdx.x;
  const int tid = threadIdx.x;
  const float4 xv = ((const float4*)(x + (size_t)row * DD))[tid];
  float s = xv.x + xv.y + xv.z + xv.w;
  float q = xv.x*xv.x + xv.y*xv.y + xv.z*xv.z + xv.w*xv.w;
#pragma unroll
  for (int o = 1; o < 64; o <<= 1) { s += __shfl_xor(s, o); q += __shfl_xor(q, o); }
  __shared__ float rs[4], rq[4];
  if ((tid & 63) == 0) { rs[tid >> 6] = s; rq[tid >> 6] = q; }
  __syncthreads();
  s = rs[0] + rs[1] + rs[2] + rs[3];
  q = rq[0] + rq[1] + rq[2] + rq[3];
  const float mean = s * (1.f / DD);
  const float var = q * (1.f / DD) - mean * mean;
  const float rstd = rsqrtf(var + 1e-5f);
  const float4 sv = ((const float4*)sc)[tid];
  const float4 bv = ((const float4*)bi)[tid];
  const u16 o0 = f2b((xv.x - mean) * rstd * sv.x + bv.x);
  const u16 o1 = f2b((xv.y - mean) * rstd * sv.y + bv.y);
  const u16 o2 = f2b((xv.z - mean) * rstd * sv.z + bv.z);
  const u16 o3 = f2b((xv.w - mean) * rstd * sv.w + bv.w);
  uint2 pk;
  pk.x = (unsigned)o0 | ((unsigned)o1 << 16);
  pk.y = (unsigned)o2 | ((unsigned)o3 << 16);
  *(uint2*)(xn + (size_t)row * DD + (tid << 2)) = pk;
}

// ======== 256xBN 8-wave GEMM, counted-vmcnt + register-prefetch pipeline ========
// C[M,N] = A[M,K]*Wt[N,K]^T + bias.  512 threads, dynamic LDS (128KB / 96KB).
// Pipeline: phase P consumes frags prefetched at P-1; pair P+3 staged at P (3 in flight).
// EPI: 2 = bf16 gelu store, 3 = f32 residual add, 4 = qkv split (QK rowmajor + V^T),
//      5 = dual bf16 store (n<1024 -> outb, else outf)
template<int EPI, int BN>
__global__ __launch_bounds__(512)
void gemm256t(const u16* __restrict__ A, const u16* __restrict__ Wt,
              const float* __restrict__ bias, const float* __restrict__ bias2,
              float* __restrict__ outf, u16* __restrict__ outb, int K, int N) {
  constexpr int NI = BN / 64;               // n-frags per wave (4 or 2)
  constexpr int PAIR = 2 + BN / 128;        // GLD16 insts per column-half pair (A + B)
  extern __shared__ u16 lds[];
  u16* Al = lds;                            // [2 buf][2 ch][256][32]
  u16* Bl = lds + 32768;                    // [2 buf][2 ch][BN][32]
  const int tid = threadIdx.x;
  const int gx = gridDim.x;
  const int nwg = gx * (int)gridDim.y;
  int lid = (int)blockIdx.y * gx + (int)blockIdx.x;
  lid = (lid & 7) * (nwg >> 3) + (lid >> 3);     // XCD-chunked (nwg % 8 == 0)
  const int m0 = (lid / gx) << 8;
  const int n0 = (lid % gx) * BN;
  const int lane = tid & 63;
  const int wid = tid >> 6;
  const int wm = wid >> 2;          // m-half (128 rows)
  const int wn = wid & 3;           // n-quarter (NI*16 cols)
  const int g = lane >> 4;
  const int lc = lane & 15;
  const int rkey = (lc >> 1) & 3;   // read-side swizzle key
  const int q = tid >> 2;           // staging row 0..127
  const int sslot = tid & 3;
  const int skey = (q >> 1) & 3;
  const int scs = (sslot ^ skey) << 3;   // inverse-swizzled source chunk (bf16 elems)
  const int so = (g ^ rkey) << 3;        // swizzled 16B slot for frag reads

  // stage one column-half pair p (buf = (p>>1)&1, ch = p&1)
  auto stage_pairP = [&](int p) {
    const int kt = p >> 1, buf = kt & 1, ch = p & 1;
    const int kbase = (kt << 6) + (ch << 5);
#pragma unroll
    for (int i = 0; i < 2; ++i) {
      const int row = i*128 + q;
      GLD16(A + (size_t)(m0 + row) * K + kbase + scs,
            Al + buf*16384 + ch*8192 + i*4096 + tid*8);
    }
#pragma unroll
    for (int i = 0; i < BN/128; ++i) {
      const int row = i*128 + q;
      GLD16(Wt + (size_t)(n0 + row) * K + kbase + scs,
            Bl + buf*(BN*64) + ch*(BN*32) + i*4096 + tid*8);
    }
  };
  auto read_b = [&](int p, bf16x8* bf) {
    const u16* Bb = Bl + ((p >> 1) & 1)*(BN*64) + (p & 1)*(BN*32);
#pragma unroll
    for (int ni = 0; ni < NI; ++ni)
      bf[ni] = *(const bf16x8*)(Bb + (wn*(NI*16) + ni*16 + lc)*32 + so);
  };
  auto read_a0 = [&](int p, bf16x8* af) {
    const u16* Ab = Al + ((p >> 1) & 1)*16384 + (p & 1)*8192;
#pragma unroll
    for (int i = 0; i < 4; ++i)
      af[i] = *(const bf16x8*)(Ab + (wm*128 + i*16 + lc)*32 + so);
  };
  auto read_a1 = [&](int p, bf16x8* af) {
    const u16* Ab = Al + ((p >> 1) & 1)*16384 + (p & 1)*8192;
#pragma unroll
    for (int i = 0; i < 4; ++i)
      af[i] = *(const bf16x8*)(Ab + (wm*128 + 64 + i*16 + lc)*32 + so);
  };

  f32x4 acc[8][NI];
#pragma unroll
  for (int i = 0; i < 8; ++i)
#pragma unroll
    for (int j = 0; j < NI; ++j)
#pragma unroll
      for (int e = 0; e < 4; ++e) acc[i][j][e] = 0.f;

  const int KT = K >> 6;
  const int NP = KT << 1;
  stage_pairP(0); stage_pairP(1); stage_pairP(2);
  wait_vmcnt<2*PAIR>();
  wg_barrier();
  bf16x8 afX[4], bfX[NI], afY[4], bfY[NI], af1[4];
  read_a0(0, afX); read_b(0, bfX);

  for (int P = 0; P < NP; P += 2) {
    // ---- even phase: consume X, prefetch P+1 -> Y
    {
      if (P + 2 < NP) wait_vmcnt<PAIR>(); else wait_vmcnt<0>();
      wg_barrier();
      read_a0(P + 1, afY); read_b(P + 1, bfY);
      if (P + 3 < NP) stage_pairP(P + 3);
      __builtin_amdgcn_s_setprio(1);
#pragma unroll
      for (int i = 0; i < 4; ++i)
#pragma unroll
        for (int ni = 0; ni < NI; ++ni)
          acc[i][ni] = __builtin_amdgcn_mfma_f32_16x16x32_bf16(afX[i], bfX[ni], acc[i][ni], 0, 0, 0);
      __builtin_amdgcn_s_setprio(0);
      read_a1(P, af1);
      __builtin_amdgcn_s_setprio(1);
#pragma unroll
      for (int i = 0; i < 4; ++i)
#pragma unroll
        for (int ni = 0; ni < NI; ++ni)
          acc[4 + i][ni] = __builtin_amdgcn_mfma_f32_16x16x32_bf16(af1[i], bfX[ni], acc[4 + i][ni], 0, 0, 0);
      __builtin_amdgcn_s_setprio(0);
    }
    // ---- odd phase: consume Y, prefetch P+2 -> X
    {
      if (P + 2 < NP) {
        if (P + 3 < NP) wait_vmcnt<PAIR>(); else wait_vmcnt<0>();
        wg_barrier();
        read_a0(P + 2, afX); read_b(P + 2, bfX);
        if (P + 4 < NP) stage_pairP(P + 4);
      }
      __builtin_amdgcn_s_setprio(1);
#pragma unroll
      for (int i = 0; i < 4; ++i)
#pragma unroll
        for (int ni = 0; ni < NI; ++ni)
          acc[i][ni] = __builtin_amdgcn_mfma_f32_16x16x32_bf16(afY[i], bfY[ni], acc[i][ni], 0, 0, 0);
      __builtin_amdgcn_s_setprio(0);
      read_a1(P + 1, af1);
      __builtin_amdgcn_s_setprio(1);
#pragma unroll
      for (int i = 0; i < 4; ++i)
#pragma unroll
        for (int ni = 0; ni < NI; ++ni)
          acc[4 + i][ni] = __builtin_amdgcn_mfma_f32_16x16x32_bf16(af1[i], bfY[ni], acc[4 + i][ni], 0, 0, 0);
      __builtin_amdgcn_s_setprio(0);
    }
  }

#pragma unroll
  for (int mi = 0; mi < 8; ++mi) {
#pragma unroll
    for (int ni = 0; ni < NI; ++ni) {
      const int n = n0 + wn*(NI*16) + ni*16 + lc;
      const int mbase = m0 + wm*128 + (mi & 3)*16 + (mi >> 2)*64 + (g << 2);
      if (EPI == 4) {
        const float bia = bias[n];
        if (n < 2048) {
#pragma unroll
          for (int e = 0; e < 4; ++e)
            outb[(size_t)(mbase + e) * 2048 + n] = f2b(acc[mi][ni][e] + bia);
        } else {
          const int hh = (n - 2048) >> 8, dim = (n - 2048) & 255;
          const int bidx = mbase >> 11, t = mbase & 2047;
          const u16 a0 = f2b(acc[mi][ni][0] + bia);
          const u16 a1 = f2b(acc[mi][ni][1] + bia);
          const u16 a2 = f2b(acc[mi][ni][2] + bia);
          const u16 a3 = f2b(acc[mi][ni][3] + bia);
          uint2 pk;
          pk.x = (unsigned)a0 | ((unsigned)a1 << 16);
          pk.y = (unsigned)a2 | ((unsigned)a3 << 16);
          u16* vtp = (u16*)outf;
          *(uint2*)(vtp + ((size_t)((bidx*4 + hh)*256 + dim)) * 2048 + t) = pk;
        }
      } else if (EPI == 5) {
        const float bia = (n < 1024) ? bias[n] : bias2[n - 1024];
        u16* dst = (n < 1024) ? outb : (u16*)outf;
        const int nn = n & 1023;
#pragma unroll
        for (int e = 0; e < 4; ++e)
          dst[(size_t)(mbase + e) * 1024 + nn] = f2b(acc[mi][ni][e] + bia);
      } else if (EPI == 2) {
        const float bia = bias[n];
#pragma unroll
        for (int e = 0; e < 4; ++e) {
          const float v = acc[mi][ni][e] + bia;
          const float zc = fminf(fmaxf(1.5957691216f * (v + 0.044715f*v*v*v), -30.f), 30.f);
          outb[(size_t)(mbase + e) * N + n] = f2b(v / (1.f + __expf(-zc)));
        }
      } else {  // EPI == 3: f32 residual add
        const float bia = bias[n];
#pragma unroll
        for (int e = 0; e < 4; ++e)
          outf[(size_t)(mbase + e) * N + n] += acc[mi][ni][e] + bia;
      }
    }
  }
}

// ---------------- RG-LRU chunked scan (bf16 z,u inputs): h_t = g*h_{t-1} + (1-g)*u ----
__global__ __launch_bounds__(256)
void scan1_k(const u16* __restrict__ zpre, const u16* __restrict__ u,
             float* __restrict__ aggA, float* __restrict__ aggB) {
  const int d = blockIdx.x * 256 + threadIdx.x;
  const int c = blockIdx.y, b = blockIdx.z;
  const size_t base = ((size_t)b * TT + (size_t)c * CHUNK) * DD + d;
  float a = 1.f, acc = 0.f;
  for (int t = 0; t < CHUNK; ++t) {
    const float gl = 1.f / (1.f + __expf(-b2f(zpre[base + (size_t)t * DD])));
    const float ul = b2f(u[base + (size_t)t * DD]);
    acc = gl * acc + (1.f - gl) * ul;
    a *= gl;
  }
  const size_t o = ((size_t)b * NCHUNK + c) * DD + d;
  aggA[o] = a; aggB[o] = acc;
}

__global__ __launch_bounds__(256)
void scan2_k(const float* __restrict__ aggA, const float* __restrict__ aggB,
             float* __restrict__ carry) {
  const int idx = blockIdx.x * 256 + threadIdx.x;  // b*DD + d
  const int b = idx >> 10, d = idx & 1023;
  float h = 0.f;
  for (int c = 0; c < NCHUNK; ++c) {
    const size_t o = ((size_t)b * NCHUNK + c) * DD + d;
    carry[o] = h;
    h = aggA[o] * h + aggB[o];
  }
}

__global__ __launch_bounds__(256)
void scan3_k(const u16* __restrict__ zpre, const u16* __restrict__ u,
             const float* __restrict__ carry, u16* __restrict__ hout) {
  const int d = blockIdx.x * 256 + threadIdx.x;
  const int c = blockIdx.y, b = blockIdx.z;
  const size_t base = ((size_t)b * TT + (size_t)c * CHUNK) * DD + d;
  float h = carry[((size_t)b * NCHUNK + c) * DD + d];
  for (int t = 0; t < CHUNK; ++t) {
    const float gl = 1.f / (1.f + __expf(-b2f(zpre[base + (size_t)t * DD])));
    const float ul = b2f(u[base + (size_t)t * DD]);
    h = gl * h + (1.f - gl) * ul;
    hout[base + (size_t)t * DD] = f2b(h);
  }
}

// ---------------- MFMA local-window attention ----------------
__global__ __launch_bounds__(256)
void attn_mfma(const u16* __restrict__ qkb, const u16* __restrict__ vt,
               u16* __restrict__ y) {
  __shared__ u16 kv[16384];
  __shared__ u16 pb[4][16][200];
  const int tid = threadIdx.x;
  const int lane = tid & 63;
  const int wid = tid >> 6;
  const int g = lane >> 4;
  const int lc = lane & 15;
  const int t0 = blockIdx.x << 6;
  const int bh = blockIdx.y;
  const int bT = (bh >> 2) * TT;
  const int h = bh & 3;

  bf16x8 afq[8];
  {
    const u16* qg = qkb + (size_t)(bT + t0 + wid*16 + lc) * 2048 + h*256 + g*8;
#pragma unroll
    for (int ks = 0; ks < 8; ++ks)
      afq[ks] = __builtin_bit_cast(bf16x8, *(const uint4*)(qg + ks*32));
  }

  f32x4 sc[12];
#pragma unroll
  for (int f = 0; f < 12; ++f)
#pragma unroll
    for (int e = 0; e < 4; ++e) sc[f][e] = 0.f;

  const int koff = 1024 + h*256;
#pragma unroll
  for (int c = 0; c < 3; ++c) {
    const int j0 = t0 + (c - 2) * 64;
    if (j0 < 0) {
#pragma unroll
      for (int nt = 0; nt < 4; ++nt)
#pragma unroll
        for (int e = 0; e < 4; ++e) sc[c*4+nt][e] = -1e30f;
      continue;
    }
    __syncthreads();
    {
      const u16* kg = qkb + (size_t)(bT + j0) * 2048 + koff;
#pragma unroll
      for (int i = 0; i < 8; ++i) {
        const int o16 = i*256 + tid;
        const int slab = o16 >> 8, key = (o16 >> 2) & 63, ds = o16 & 3;
        GLD16(kg + (size_t)key*2048 + slab*32 + ds*8, kv + o16*8);
      }
    }
    __syncthreads();
#pragma unroll
    for (int nt = 0; nt < 4; ++nt) {
      f32x4 s = sc[c*4+nt];
#pragma unroll
      for (int ks = 0; ks < 8; ++ks) {
        const bf16x8 kb = *(const bf16x8*)(kv + ks*2048 + (nt*16 + lc)*32 + g*8);
        s = __builtin_amdgcn_mfma_f32_16x16x32_bf16(afq[ks], kb, s, 0, 0, 0);
      }
      sc[c*4+nt] = s;
    }
#pragma unroll
    for (int nt = 0; nt < 4; ++nt)
#pragma unroll
      for (int e = 0; e < 4; ++e) {
        const int tl = wid*16 + g*4 + e;
        const int jl = nt*16 + lc;
        const bool ok = (c == 1) || (c == 2 ? (jl <= tl) : (jl >= tl + 1));
        sc[c*4+nt][e] = ok ? sc[c*4+nt][e] * 0.0625f : -1e30f;
      }
  }

#pragma unroll
  for (int e = 0; e < 4; ++e) {
    float m = -1e30f;
#pragma unroll
    for (int f = 0; f < 12; ++f) m = fmaxf(m, sc[f][e]);
    m = fmaxf(m, __shfl_xor(m, 1)); m = fmaxf(m, __shfl_xor(m, 2));
    m = fmaxf(m, __shfl_xor(m, 4)); m = fmaxf(m, __shfl_xor(m, 8));
    float s = 0.f;
#pragma unroll
    for (int f = 0; f < 12; ++f) { const float p = __expf(sc[f][e] - m); sc[f][e] = p; s += p; }
    s += __shfl_xor(s, 1); s += __shfl_xor(s, 2);
    s += __shfl_xor(s, 4); s += __shfl_xor(s, 8);
    const float is = 1.f / s;
#pragma unroll
    for (int f = 0; f < 12; ++f) sc[f][e] *= is;
  }
#pragma unroll
  for (int c = 0; c < 3; ++c)
#pragma unroll
    for (int nt = 0; nt < 4; ++nt)
#pragma unroll
      for (int e = 0; e < 4; ++e)
        pb[wid][g*4 + e][c*64 + nt*16 + lc] = f2b(sc[c*4+nt][e]);

  f32x4 acc[16];
#pragma unroll
  for (int nt = 0; nt < 16; ++nt)
#pragma unroll
    for (int e = 0; e < 4; ++e) acc[nt][e] = 0.f;

  const u16* vg = vt + (size_t)bh * 256 * 2048;
#pragma unroll
  for (int c = 0; c < 3; ++c) {
    const int j0 = t0 + (c - 2) * 64;
    if (j0 < 0) continue;
    __syncthreads();
#pragma unroll
    for (int i = 0; i < 8; ++i) {
      const int o16 = i*256 + tid;
      const int dim = o16 >> 3, slot = o16 & 7;
      const int ss = slot ^ (dim & 7);
      GLD16(vg + (size_t)dim*2048 + j0 + ss*8, kv + o16*8);
    }
    __syncthreads();
#pragma unroll
    for (int ks = 0; ks < 2; ++ks) {
      const bf16x8 pa = *(const bf16x8*)&pb[wid][lc][(c*2 + ks)*32 + g*8];
#pragma unroll
      for (int nt = 0; nt < 16; ++nt) {
        const int dim = nt*16 + lc;
        int boff = dim*128 + ks*64 + g*16;
        boff ^= (dim & 7) << 4;
        const bf16x8 vb = *(const bf16x8*)((const char*)kv + boff);
        acc[nt] = __builtin_amdgcn_mfma_f32_16x16x32_bf16(pa, vb, acc[nt], 0, 0, 0);
      }
    }
  }

#pragma unroll
  for (int nt = 0; nt < 16; ++nt)
#pragma unroll
    for (int e = 0; e < 4; ++e) {
      const int tok = bT + t0 + wid*16 + g*4 + e;
      y[(size_t)tok * 1024 + h*256 + nt*16 + lc] = f2b(acc[nt][e]);
    }
}

// ---------------- host orchestration ----------------
extern "C" void kernel_launch(void* const* d_in, const int* in_sizes, int n_in,
                              void* d_out, int out_size, void* d_ws, size_t ws_size,
                              hipStream_t stream) {
  const float* x_in      = (const float*)d_in[0];
  const float* ln1_s     = (const float*)d_in[1];
  const float* ln1_b     = (const float*)d_in[2];
  const float* ln2_s     = (const float*)d_in[3];
  const float* ln2_b     = (const float*)d_in[4];
  const float* ln3_s     = (const float*)d_in[5];
  const float* ln3_b     = (const float*)d_in[6];
  const float* rg_in_w   = (const float*)d_in[7];
  const float* rg_in_b   = (const float*)d_in[8];
  const float* rg_gate_w = (const float*)d_in[9];
  const float* rg_gate_b = (const float*)d_in[10];
  const float* rg_out_w  = (const float*)d_in[11];
  const float* rg_out_b  = (const float*)d_in[12];
  const float* qkv_w     = (const float*)d_in[13];
  const float* qkv_b     = (const float*)d_in[14];
  const float* attn_out_w= (const float*)d_in[15];
  const float* attn_out_b= (const float*)d_in[16];
  const float* mlp_w1    = (const float*)d_in[17];
  const float* mlp_b1    = (const float*)d_in[18];
  const float* mlp_w2    = (const float*)d_in[19];
  const float* mlp_b2    = (const float*)d_in[20];

  hipFuncSetAttribute((const void*)&gemm256t<5,256>, hipFuncAttributeMaxDynamicSharedMemorySize, 131072);
  hipFuncSetAttribute((const void*)&gemm256t<4,256>, hipFuncAttributeMaxDynamicSharedMemorySize, 131072);
  hipFuncSetAttribute((const void*)&gemm256t<2,256>, hipFuncAttributeMaxDynamicSharedMemorySize, 131072);
  hipFuncSetAttribute((const void*)&gemm256t<3,128>, hipFuncAttributeMaxDynamicSharedMemorySize, 98304);

  float* x = (float*)d_out;
  char* ws = (char*)d_ws;
  u16*  wt     = (u16*)ws;                          // 62,914,560 B (bf16 transposed weights)
  u16*  xn     = (u16*)(ws + 62914560);             // 16,777,216 B
  char* bigS   = ws + 62914560 + 16777216;          // 67,108,864 B
  char* smallS = bigS + 67108864;                   // 16,777,216 B
  float* aggA  = (float*)(smallS + 16777216);
  float* aggB  = aggA + (size_t)BB * NCHUNK * DD;
  float* carry = aggB + (size_t)BB * NCHUNK * DD;

  u16* ubuf = (u16*)bigS;                           // RG phase (bf16)
  u16* zbuf = (u16*)(bigS + 33554432);              // pre-sigmoid gate, bf16
  u16* qkb  = (u16*)bigS;                           // attn phase: [8192][2048] QK
  u16* vtb  = (u16*)(bigS + 33554432);              // attn phase: V transposed, 16MB
  u16* hid  = (u16*)bigS;                           // MLP phase
  u16* hbuf = (u16*)smallS;
  u16* ybuf = (u16*)smallS;

  hipMemcpyAsync(x, x_in, (size_t)MM * DD * sizeof(float), hipMemcpyDeviceToDevice, stream);

  const size_t LW = 15728640;
  const dim3 tb(32, 8);
  for (int l = 0; l < NLAYER; ++l) {
    u16* base = wt + (size_t)l * LW;
    transpose_cvt<<<dim3(32, 32),  tb, 0, stream>>>(rg_in_w   + (size_t)l*DD*DD,   base + 0,        DD, DD);
    transpose_cvt<<<dim3(32, 32),  tb, 0, stream>>>(rg_gate_w + (size_t)l*DD*DD,   base + 1048576,  DD, DD);
    transpose_cvt<<<dim3(32, 32),  tb, 0, stream>>>(rg_out_w  + (size_t)l*DD*DD,   base + 2097152,  DD, DD);
    transpose_cvt<<<dim3(96, 32),  tb, 0, stream>>>(qkv_w     + (size_t)l*DD*3072, base + 3145728,  DD, 3072);
    transpose_cvt<<<dim3(32, 32),  tb, 0, stream>>>(attn_out_w+ (size_t)l*DD*DD,   base + 6291456,  DD, DD);
    transpose_cvt<<<dim3(128, 32), tb, 0, stream>>>(mlp_w1    + (size_t)l*DD*4096, base + 7340032,  DD, 4096);
    transpose_cvt<<<dim3(32, 128), tb, 0, stream>>>(mlp_w2    + (size_t)l*4096*DD, base + 11534336, 4096, DD);
  }

  for (int l = 0; l < NLAYER; ++l) {
    u16* base = wt + (size_t)l * LW;
    // ---- RG-LRU block (rg_in + rg_gate fused; u and pre-sigmoid z stored bf16)
    ln_k<<<MM, 256, 0, stream>>>(x, ln1_s + l*DD, ln1_b + l*DD, xn);
    gemm256t<5,256><<<dim3(8, 32), 512, 131072, stream>>>(xn, base + 0, rg_in_b + l*DD, rg_gate_b + l*DD,
                                                          (float*)zbuf, ubuf, DD, 2048);
    scan1_k<<<dim3(4, NCHUNK, BB), 256, 0, stream>>>(zbuf, ubuf, aggA, aggB);
    scan2_k<<<16, 256, 0, stream>>>(aggA, aggB, carry);
    scan3_k<<<dim3(4, NCHUNK, BB), 256, 0, stream>>>(zbuf, ubuf, carry, hbuf);
    gemm256t<3,128><<<dim3(8, 32), 512, 98304, stream>>>(hbuf, base + 2097152, rg_out_b + l*DD, nullptr,
                                                         x, nullptr, DD, 1024);
    // ---- local attention block
    ln_k<<<MM, 256, 0, stream>>>(x, ln2_s + l*DD, ln2_b + l*DD, xn);
    gemm256t<4,256><<<dim3(12, 32), 512, 131072, stream>>>(xn, base + 3145728, qkv_b + l*3072, nullptr,
                                                           (float*)vtb, qkb, DD, 3072);
    attn_mfma<<<dim3(TT/64, BB*HH), 256, 0, stream>>>(qkb, vtb, ybuf);
    gemm256t<3,128><<<dim3(8, 32), 512, 98304, stream>>>(ybuf, base + 6291456, attn_out_b + l*DD, nullptr,
                                                         x, nullptr, DD, 1024);
    // ---- MLP block
    ln_k<<<MM, 256, 0, stream>>>(x, ln3_s + l*DD, ln3_b + l*DD, xn);
    gemm256t<2,256><<<dim3(16, 32), 512, 131072, stream>>>(xn, base + 7340032, mlp_b1 + l*4096, nullptr,
                                                           nullptr, hid, DD, 4096);
    gemm256t<3,128><<<dim3(8, 32), 512, 98304, stream>>>(hid, base + 11534336, mlp_b2 + l*DD, nullptr,
                                                         x, nullptr, 4096, 1024);
  }
}

// Round 9
// 900.467 us; speedup vs baseline: 2.0390x; 1.0110x over previous
//
#include <hip/hip_runtime.h>
#include <math.h>

#define DD 1024
#define TT 2048
#define BB 4
#define HH 4
#define HDIM 256
#define NLAYER 2
#define MM (BB*TT)          // 8192 rows
#define NCHUNK 32
#define CHUNK (TT/NCHUNK)   // 64

typedef unsigned short u16;
typedef __bf16 bf16x8 __attribute__((ext_vector_type(8)));
typedef float f32x4 __attribute__((ext_vector_type(4)));

__device__ __forceinline__ float b2f(u16 h) {
  unsigned u = ((unsigned)h) << 16;
  return __builtin_bit_cast(float, u);
}
__device__ __forceinline__ u16 f2b(float f) {
  unsigned u = __builtin_bit_cast(unsigned, f);
  u += 0x7fffu + ((u >> 16) & 1u);
  return (u16)(u >> 16);
}

#define GLD16(g, l) __builtin_amdgcn_global_load_lds( \
    (__attribute__((address_space(1))) void*)(void*)(g), \
    (__attribute__((address_space(3))) void*)(l), 16, 0, 0)

__device__ __forceinline__ void wg_barrier() {
  asm volatile("" ::: "memory");
  __builtin_amdgcn_s_barrier();
  asm volatile("" ::: "memory");
}
template<int N> __device__ __forceinline__ void wait_vmcnt() {
  asm volatile("s_waitcnt vmcnt(%0)" :: "i"(N) : "memory");
}

// ------- weight fp32 -> bf16 transpose: Wt[N][K] = W[K][N], batched over layers -------
__global__ __launch_bounds__(256)
void transpose_cvt(const float* __restrict__ W, u16* __restrict__ Wt, int K, int N,
                   size_t lsrc, size_t ldst) {
  __shared__ float tile[32][33];
  const float* Wl = W + (size_t)blockIdx.z * lsrc;
  u16* Wtl = Wt + (size_t)blockIdx.z * ldst;
  const int n0 = blockIdx.x << 5, k0 = blockIdx.y << 5;
  const int tx = threadIdx.x, ty = threadIdx.y;
#pragma unroll
  for (int i = 0; i < 4; ++i)
    tile[ty + i*8][tx] = Wl[(size_t)(k0 + ty + i*8) * N + n0 + tx];
  __syncthreads();
#pragma unroll
  for (int i = 0; i < 4; ++i)
    Wtl[(size_t)(n0 + ty + i*8) * K + k0 + tx] = f2b(tile[tx][ty + i*8]);
}

// ---------------- LayerNorm (fp32 in, bf16 out) ----------------
__global__ __launch_bounds__(256)
void ln_k(const float* __restrict__ x, const float* __restrict__ sc,
          const float* __restrict__ bi, u16* __restrict__ xn) {
  const int row = blockIdx.x;
  const int tid = threadIdx.x;
  const float4 xv = ((const float4*)(x + (size_t)row * DD))[tid];
  float s = xv.x + xv.y + xv.z + xv.w;
  float q = xv.x*xv.x + xv.y*xv.y + xv.z*xv.z + xv.w*xv.w;
#pragma unroll
  for (int o = 1; o < 64; o <<= 1) { s += __shfl_xor(s, o); q += __shfl_xor(q, o); }
  __shared__ float rs[4], rq[4];
  if ((tid & 63) == 0) { rs[tid >> 6] = s; rq[tid >> 6] = q; }
  __syncthreads();
  s = rs[0] + rs[1] + rs[2] + rs[3];
  q = rq[0] + rq[1] + rq[2] + rq[3];
  const float mean = s * (1.f / DD);
  const float var = q * (1.f / DD) - mean * mean;
  const float rstd = rsqrtf(var + 1e-5f);
  const float4 sv = ((const float4*)sc)[tid];
  const float4 bv = ((const float4*)bi)[tid];
  const u16 o0 = f2b((xv.x - mean) * rstd * sv.x + bv.x);
  const u16 o1 = f2b((xv.y - mean) * rstd * sv.y + bv.y);
  const u16 o2 = f2b((xv.z - mean) * rstd * sv.z + bv.z);
  const u16 o3 = f2b((xv.w - mean) * rstd * sv.w + bv.w);
  uint2 pk;
  pk.x = (unsigned)o0 | ((unsigned)o1 << 16);
  pk.y = (unsigned)o2 | ((unsigned)o3 << 16);
  *(uint2*)(xn + (size_t)row * DD + (tid << 2)) = pk;
}

// ======== 256xBN 8-wave GEMM: counted-vmcnt + FULL register double-buffer ========
// C[M,N] = A[M,K]*Wt[N,K]^T + bias.  512 threads, dynamic LDS (128KB / 96KB).
// Phase P: wait vmcnt(PAIR) [pair P+1 landed] -> barrier -> prefetch ALL frags of set
// P+1 (12 ds_reads, consumed next phase) -> stage pair P+3 -> 32 MFMA on set P
// (zero LDS dependency). One barrier per phase; 3 pairs in flight; never vmcnt(0) mid-loop.
// EPI: 2 = bf16 gelu store, 3 = f32 residual add, 4 = qkv split (QK rowmajor + V^T),
//      5 = dual bf16 store (n<1024 -> outb, else outf)
template<int EPI, int BN>
__global__ __launch_bounds__(512)
void gemm256t(const u16* __restrict__ A, const u16* __restrict__ Wt,
              const float* __restrict__ bias, const float* __restrict__ bias2,
              float* __restrict__ outf, u16* __restrict__ outb, int K, int N) {
  constexpr int NI = BN / 64;               // n-frags per wave (4 or 2)
  constexpr int PAIR = 2 + BN / 128;        // GLD16 insts per column-half pair (A + B)
  extern __shared__ u16 lds[];
  u16* Al = lds;                            // [2 buf][2 ch][256][32]
  u16* Bl = lds + 32768;                    // [2 buf][2 ch][BN][32]
  const int tid = threadIdx.x;
  const int gx = gridDim.x;
  const int nwg = gx * (int)gridDim.y;
  int lid = (int)blockIdx.y * gx + (int)blockIdx.x;
  lid = (lid & 7) * (nwg >> 3) + (lid >> 3);     // XCD-chunked (nwg % 8 == 0)
  const int m0 = (lid / gx) << 8;
  const int n0 = (lid % gx) * BN;
  const int lane = tid & 63;
  const int wid = tid >> 6;
  const int wm = wid >> 2;          // m-half (128 rows)
  const int wn = wid & 3;           // n-quarter (NI*16 cols)
  const int g = lane >> 4;
  const int lc = lane & 15;
  const int rkey = (lc >> 1) & 3;   // read-side swizzle key
  const int q = tid >> 2;           // staging row 0..127
  const int sslot = tid & 3;
  const int skey = (q >> 1) & 3;
  const int scs = (sslot ^ skey) << 3;   // inverse-swizzled source chunk (bf16 elems)
  const int so = (g ^ rkey) << 3;        // swizzled 16B slot for frag reads

  // stage column-half pair p into LDS slot p&3 (buf=(p>>1)&1, ch=p&1)
  auto stage_pairP = [&](int p) {
    const int kt = p >> 1, buf = kt & 1, ch = p & 1;
    const int kbase = (kt << 6) + (ch << 5);
#pragma unroll
    for (int i = 0; i < 2; ++i) {
      const int row = i*128 + q;
      GLD16(A + (size_t)(m0 + row) * K + kbase + scs,
            Al + buf*16384 + ch*8192 + i*4096 + tid*8);
    }
#pragma unroll
    for (int i = 0; i < BN/128; ++i) {
      const int row = i*128 + q;
      GLD16(Wt + (size_t)(n0 + row) * K + kbase + scs,
            Bl + buf*(BN*64) + ch*(BN*32) + i*4096 + tid*8);
    }
  };
  // prefetch full fragment set of pair p: bfr[NI] + af[8]
  auto read_set = [&](int p, bf16x8* af, bf16x8* bf) {
    const u16* Ab = Al + ((p >> 1) & 1)*16384 + (p & 1)*8192;
    const u16* Bb = Bl + ((p >> 1) & 1)*(BN*64) + (p & 1)*(BN*32);
#pragma unroll
    for (int ni = 0; ni < NI; ++ni)
      bf[ni] = *(const bf16x8*)(Bb + (wn*(NI*16) + ni*16 + lc)*32 + so);
#pragma unroll
    for (int i = 0; i < 4; ++i)
      af[i] = *(const bf16x8*)(Ab + (wm*128 + i*16 + lc)*32 + so);
#pragma unroll
    for (int i = 0; i < 4; ++i)
      af[4 + i] = *(const bf16x8*)(Ab + (wm*128 + 64 + i*16 + lc)*32 + so);
  };

  f32x4 acc[8][NI];
#pragma unroll
  for (int i = 0; i < 8; ++i)
#pragma unroll
    for (int j = 0; j < NI; ++j)
#pragma unroll
      for (int e = 0; e < 4; ++e) acc[i][j][e] = 0.f;

  const int KT = K >> 6;
  const int NP = KT << 1;           // phases (>= 4 always here)
  stage_pairP(0); stage_pairP(1); stage_pairP(2);
  wait_vmcnt<2*PAIR>();             // pair 0 landed (1,2 may be in flight)
  wg_barrier();
  bf16x8 afX[8], bfX[NI], afY[8], bfY[NI];
  read_set(0, afX, bfX);

#define GPHASE(PP, CURA, CURB, NXTA, NXTB)                                          \
  {                                                                                 \
    const int P_ = (PP);                                                            \
    if (P_ + 1 < NP) {                                                              \
      if (P_ + 2 < NP) wait_vmcnt<PAIR>(); else wait_vmcnt<0>();                    \
      wg_barrier();                                                                 \
      read_set(P_ + 1, NXTA, NXTB);                                                 \
      if (P_ + 3 < NP) stage_pairP(P_ + 3);                                         \
    }                                                                               \
    __builtin_amdgcn_s_setprio(1);                                                  \
    _Pragma("unroll")                                                               \
    for (int i = 0; i < 8; ++i)                                                     \
      _Pragma("unroll")                                                             \
      for (int ni = 0; ni < NI; ++ni)                                               \
        acc[i][ni] = __builtin_amdgcn_mfma_f32_16x16x32_bf16(CURA[i], CURB[ni],     \
                                                             acc[i][ni], 0, 0, 0); \
    __builtin_amdgcn_s_setprio(0);                                                  \
  }

  for (int P = 0; P < NP; P += 2) {
    GPHASE(P,     afX, bfX, afY, bfY)
    GPHASE(P + 1, afY, bfY, afX, bfX)
  }
#undef GPHASE

#pragma unroll
  for (int mi = 0; mi < 8; ++mi) {
#pragma unroll
    for (int ni = 0; ni < NI; ++ni) {
      const int n = n0 + wn*(NI*16) + ni*16 + lc;
      const int mbase = m0 + wm*128 + (mi & 3)*16 + (mi >> 2)*64 + (g << 2);
      if (EPI == 4) {
        const float bia = bias[n];
        if (n < 2048) {
#pragma unroll
          for (int e = 0; e < 4; ++e)
            outb[(size_t)(mbase + e) * 2048 + n] = f2b(acc[mi][ni][e] + bia);
        } else {
          const int hh = (n - 2048) >> 8, dim = (n - 2048) & 255;
          const int bidx = mbase >> 11, t = mbase & 2047;
          const u16 a0 = f2b(acc[mi][ni][0] + bia);
          const u16 a1 = f2b(acc[mi][ni][1] + bia);
          const u16 a2 = f2b(acc[mi][ni][2] + bia);
          const u16 a3 = f2b(acc[mi][ni][3] + bia);
          uint2 pk;
          pk.x = (unsigned)a0 | ((unsigned)a1 << 16);
          pk.y = (unsigned)a2 | ((unsigned)a3 << 16);
          u16* vtp = (u16*)outf;
          *(uint2*)(vtp + ((size_t)((bidx*4 + hh)*256 + dim)) * 2048 + t) = pk;
        }
      } else if (EPI == 5) {
        const float bia = (n < 1024) ? bias[n] : bias2[n - 1024];
        u16* dst = (n < 1024) ? outb : (u16*)outf;
        const int nn = n & 1023;
#pragma unroll
        for (int e = 0; e < 4; ++e)
          dst[(size_t)(mbase + e) * 1024 + nn] = f2b(acc[mi][ni][e] + bia);
      } else if (EPI == 2) {
        const float bia = bias[n];
#pragma unroll
        for (int e = 0; e < 4; ++e) {
          const float v = acc[mi][ni][e] + bia;
          const float zc = fminf(fmaxf(1.5957691216f * (v + 0.044715f*v*v*v), -30.f), 30.f);
          outb[(size_t)(mbase + e) * N + n] = f2b(v / (1.f + __expf(-zc)));
        }
      } else {  // EPI == 3: f32 residual add
        const float bia = bias[n];
#pragma unroll
        for (int e = 0; e < 4; ++e)
          outf[(size_t)(mbase + e) * N + n] += acc[mi][ni][e] + bia;
      }
    }
  }
}

// ---------------- RG-LRU chunked scan (bf16 z,u inputs): h_t = g*h_{t-1} + (1-g)*u ----
__global__ __launch_bounds__(256)
void scan1_k(const u16* __restrict__ zpre, const u16* __restrict__ u,
             float* __restrict__ aggA, float* __restrict__ aggB) {
  const int d = blockIdx.x * 256 + threadIdx.x;
  const int c = blockIdx.y, b = blockIdx.z;
  const size_t base = ((size_t)b * TT + (size_t)c * CHUNK) * DD + d;
  float a = 1.f, acc = 0.f;
  for (int t = 0; t < CHUNK; ++t) {
    const float gl = 1.f / (1.f + __expf(-b2f(zpre[base + (size_t)t * DD])));
    const float ul = b2f(u[base + (size_t)t * DD]);
    acc = gl * acc + (1.f - gl) * ul;
    a *= gl;
  }
  const size_t o = ((size_t)b * NCHUNK + c) * DD + d;
  aggA[o] = a; aggB[o] = acc;
}

__global__ __launch_bounds__(256)
void scan2_k(const float* __restrict__ aggA, const float* __restrict__ aggB,
             float* __restrict__ carry) {
  const int idx = blockIdx.x * 256 + threadIdx.x;  // b*DD + d
  const int b = idx >> 10, d = idx & 1023;
  float h = 0.f;
  for (int c = 0; c < NCHUNK; ++c) {
    const size_t o = ((size_t)b * NCHUNK + c) * DD + d;
    carry[o] = h;
    h = aggA[o] * h + aggB[o];
  }
}

__global__ __launch_bounds__(256)
void scan3_k(const u16* __restrict__ zpre, const u16* __restrict__ u,
             const float* __restrict__ carry, u16* __restrict__ hout) {
  const int d = blockIdx.x * 256 + threadIdx.x;
  const int c = blockIdx.y, b = blockIdx.z;
  const size_t base = ((size_t)b * TT + (size_t)c * CHUNK) * DD + d;
  float h = carry[((size_t)b * NCHUNK + c) * DD + d];
  for (int t = 0; t < CHUNK; ++t) {
    const float gl = 1.f / (1.f + __expf(-b2f(zpre[base + (size_t)t * DD])));
    const float ul = b2f(u[base + (size_t)t * DD]);
    h = gl * h + (1.f - gl) * ul;
    hout[base + (size_t)t * DD] = f2b(h);
  }
}

// ---------------- MFMA local-window attention ----------------
__global__ __launch_bounds__(256)
void attn_mfma(const u16* __restrict__ qkb, const u16* __restrict__ vt,
               u16* __restrict__ y) {
  __shared__ u16 kv[16384];
  __shared__ u16 pb[4][16][200];
  const int tid = threadIdx.x;
  const int lane = tid & 63;
  const int wid = tid >> 6;
  const int g = lane >> 4;
  const int lc = lane & 15;
  const int t0 = blockIdx.x << 6;
  const int bh = blockIdx.y;
  const int bT = (bh >> 2) * TT;
  const int h = bh & 3;

  bf16x8 afq[8];
  {
    const u16* qg = qkb + (size_t)(bT + t0 + wid*16 + lc) * 2048 + h*256 + g*8;
#pragma unroll
    for (int ks = 0; ks < 8; ++ks)
      afq[ks] = __builtin_bit_cast(bf16x8, *(const uint4*)(qg + ks*32));
  }

  f32x4 sc[12];
#pragma unroll
  for (int f = 0; f < 12; ++f)
#pragma unroll
    for (int e = 0; e < 4; ++e) sc[f][e] = 0.f;

  const int koff = 1024 + h*256;
#pragma unroll
  for (int c = 0; c < 3; ++c) {
    const int j0 = t0 + (c - 2) * 64;
    if (j0 < 0) {
#pragma unroll
      for (int nt = 0; nt < 4; ++nt)
#pragma unroll
        for (int e = 0; e < 4; ++e) sc[c*4+nt][e] = -1e30f;
      continue;
    }
    __syncthreads();
    {
      const u16* kg = qkb + (size_t)(bT + j0) * 2048 + koff;
#pragma unroll
      for (int i = 0; i < 8; ++i) {
        const int o16 = i*256 + tid;
        const int slab = o16 >> 8, key = (o16 >> 2) & 63, ds = o16 & 3;
        GLD16(kg + (size_t)key*2048 + slab*32 + ds*8, kv + o16*8);
      }
    }
    __syncthreads();
#pragma unroll
    for (int nt = 0; nt < 4; ++nt) {
      f32x4 s = sc[c*4+nt];
#pragma unroll
      for (int ks = 0; ks < 8; ++ks) {
        const bf16x8 kb = *(const bf16x8*)(kv + ks*2048 + (nt*16 + lc)*32 + g*8);
        s = __builtin_amdgcn_mfma_f32_16x16x32_bf16(afq[ks], kb, s, 0, 0, 0);
      }
      sc[c*4+nt] = s;
    }
#pragma unroll
    for (int nt = 0; nt < 4; ++nt)
#pragma unroll
      for (int e = 0; e < 4; ++e) {
        const int tl = wid*16 + g*4 + e;
        const int jl = nt*16 + lc;
        const bool ok = (c == 1) || (c == 2 ? (jl <= tl) : (jl >= tl + 1));
        sc[c*4+nt][e] = ok ? sc[c*4+nt][e] * 0.0625f : -1e30f;
      }
  }

#pragma unroll
  for (int e = 0; e < 4; ++e) {
    float m = -1e30f;
#pragma unroll
    for (int f = 0; f < 12; ++f) m = fmaxf(m, sc[f][e]);
    m = fmaxf(m, __shfl_xor(m, 1)); m = fmaxf(m, __shfl_xor(m, 2));
    m = fmaxf(m, __shfl_xor(m, 4)); m = fmaxf(m, __shfl_xor(m, 8));
    float s = 0.f;
#pragma unroll
    for (int f = 0; f < 12; ++f) { const float p = __expf(sc[f][e] - m); sc[f][e] = p; s += p; }
    s += __shfl_xor(s, 1); s += __shfl_xor(s, 2);
    s += __shfl_xor(s, 4); s += __shfl_xor(s, 8);
    const float is = 1.f / s;
#pragma unroll
    for (int f = 0; f < 12; ++f) sc[f][e] *= is;
  }
#pragma unroll
  for (int c = 0; c < 3; ++c)
#pragma unroll
    for (int nt = 0; nt < 4; ++nt)
#pragma unroll
      for (int e = 0; e < 4; ++e)
        pb[wid][g*4 + e][c*64 + nt*16 + lc] = f2b(sc[c*4+nt][e]);

  f32x4 acc[16];
#pragma unroll
  for (int nt = 0; nt < 16; ++nt)
#pragma unroll
    for (int e = 0; e < 4; ++e) acc[nt][e] = 0.f;

  const u16* vg = vt + (size_t)bh * 256 * 2048;
#pragma unroll
  for (int c = 0; c < 3; ++c) {
    const int j0 = t0 + (c - 2) * 64;
    if (j0 < 0) continue;
    __syncthreads();
#pragma unroll
    for (int i = 0; i < 8; ++i) {
      const int o16 = i*256 + tid;
      const int dim = o16 >> 3, slot = o16 & 7;
      const int ss = slot ^ (dim & 7);
      GLD16(vg + (size_t)dim*2048 + j0 + ss*8, kv + o16*8);
    }
    __syncthreads();
#pragma unroll
    for (int ks = 0; ks < 2; ++ks) {
      const bf16x8 pa = *(const bf16x8*)&pb[wid][lc][(c*2 + ks)*32 + g*8];
#pragma unroll
      for (int nt = 0; nt < 16; ++nt) {
        const int dim = nt*16 + lc;
        int boff = dim*128 + ks*64 + g*16;
        boff ^= (dim & 7) << 4;
        const bf16x8 vb = *(const bf16x8*)((const char*)kv + boff);
        acc[nt] = __builtin_amdgcn_mfma_f32_16x16x32_bf16(pa, vb, acc[nt], 0, 0, 0);
      }
    }
  }

#pragma unroll
  for (int nt = 0; nt < 16; ++nt)
#pragma unroll
    for (int e = 0; e < 4; ++e) {
      const int tok = bT + t0 + wid*16 + g*4 + e;
      y[(size_t)tok * 1024 + h*256 + nt*16 + lc] = f2b(acc[nt][e]);
    }
}

// ---------------- host orchestration ----------------
extern "C" void kernel_launch(void* const* d_in, const int* in_sizes, int n_in,
                              void* d_out, int out_size, void* d_ws, size_t ws_size,
                              hipStream_t stream) {
  const float* x_in      = (const float*)d_in[0];
  const float* ln1_s     = (const float*)d_in[1];
  const float* ln1_b     = (const float*)d_in[2];
  const float* ln2_s     = (const float*)d_in[3];
  const float* ln2_b     = (const float*)d_in[4];
  const float* ln3_s     = (const float*)d_in[5];
  const float* ln3_b     = (const float*)d_in[6];
  const float* rg_in_w   = (const float*)d_in[7];
  const float* rg_in_b   = (const float*)d_in[8];
  const float* rg_gate_w = (const float*)d_in[9];
  const float* rg_gate_b = (const float*)d_in[10];
  const float* rg_out_w  = (const float*)d_in[11];
  const float* rg_out_b  = (const float*)d_in[12];
  const float* qkv_w     = (const float*)d_in[13];
  const float* qkv_b     = (const float*)d_in[14];
  const float* attn_out_w= (const float*)d_in[15];
  const float* attn_out_b= (const float*)d_in[16];
  const float* mlp_w1    = (const float*)d_in[17];
  const float* mlp_b1    = (const float*)d_in[18];
  const float* mlp_w2    = (const float*)d_in[19];
  const float* mlp_b2    = (const float*)d_in[20];

  hipFuncSetAttribute((const void*)&gemm256t<5,256>, hipFuncAttributeMaxDynamicSharedMemorySize, 131072);
  hipFuncSetAttribute((const void*)&gemm256t<4,256>, hipFuncAttributeMaxDynamicSharedMemorySize, 131072);
  hipFuncSetAttribute((const void*)&gemm256t<2,256>, hipFuncAttributeMaxDynamicSharedMemorySize, 131072);
  hipFuncSetAttribute((const void*)&gemm256t<3,128>, hipFuncAttributeMaxDynamicSharedMemorySize, 98304);

  float* x = (float*)d_out;
  char* ws = (char*)d_ws;
  u16*  wt     = (u16*)ws;                          // 62,914,560 B (bf16 transposed weights)
  u16*  xn     = (u16*)(ws + 62914560);             // 16,777,216 B
  char* bigS   = ws + 62914560 + 16777216;          // 67,108,864 B
  char* smallS = bigS + 67108864;                   // 16,777,216 B
  float* aggA  = (float*)(smallS + 16777216);
  float* aggB  = aggA + (size_t)BB * NCHUNK * DD;
  float* carry = aggB + (size_t)BB * NCHUNK * DD;

  u16* ubuf = (u16*)bigS;                           // RG phase (bf16)
  u16* zbuf = (u16*)(bigS + 33554432);              // pre-sigmoid gate, bf16
  u16* qkb  = (u16*)bigS;                           // attn phase: [8192][2048] QK
  u16* vtb  = (u16*)(bigS + 33554432);              // attn phase: V transposed, 16MB
  u16* hid  = (u16*)bigS;                           // MLP phase
  u16* hbuf = (u16*)smallS;
  u16* ybuf = (u16*)smallS;

  hipMemcpyAsync(x, x_in, (size_t)MM * DD * sizeof(float), hipMemcpyDeviceToDevice, stream);

  const size_t LW = 15728640;
  const dim3 tb(32, 8);
  // batched over both layers via blockIdx.z
  transpose_cvt<<<dim3(32, 32, 2),  tb, 0, stream>>>(rg_in_w,    wt + 0,        DD, DD,   DD*DD,   LW);
  transpose_cvt<<<dim3(32, 32, 2),  tb, 0, stream>>>(rg_gate_w,  wt + 1048576,  DD, DD,   DD*DD,   LW);
  transpose_cvt<<<dim3(32, 32, 2),  tb, 0, stream>>>(rg_out_w,   wt + 2097152,  DD, DD,   DD*DD,   LW);
  transpose_cvt<<<dim3(96, 32, 2),  tb, 0, stream>>>(qkv_w,      wt + 3145728,  DD, 3072, DD*3072, LW);
  transpose_cvt<<<dim3(32, 32, 2),  tb, 0, stream>>>(attn_out_w, wt + 6291456,  DD, DD,   DD*DD,   LW);
  transpose_cvt<<<dim3(128, 32, 2), tb, 0, stream>>>(mlp_w1,     wt + 7340032,  DD, 4096, DD*4096, LW);
  transpose_cvt<<<dim3(32, 128, 2), tb, 0, stream>>>(mlp_w2,     wt + 11534336, 4096, DD, 4096*DD, LW);

  for (int l = 0; l < NLAYER; ++l) {
    u16* base = wt + (size_t)l * LW;
    // ---- RG-LRU block (rg_in + rg_gate fused; u and pre-sigmoid z stored bf16)
    ln_k<<<MM, 256, 0, stream>>>(x, ln1_s + l*DD, ln1_b + l*DD, xn);
    gemm256t<5,256><<<dim3(8, 32), 512, 131072, stream>>>(xn, base + 0, rg_in_b + l*DD, rg_gate_b + l*DD,
                                                          (float*)zbuf, ubuf, DD, 2048);
    scan1_k<<<dim3(4, NCHUNK, BB), 256, 0, stream>>>(zbuf, ubuf, aggA, aggB);
    scan2_k<<<16, 256, 0, stream>>>(aggA, aggB, carry);
    scan3_k<<<dim3(4, NCHUNK, BB), 256, 0, stream>>>(zbuf, ubuf, carry, hbuf);
    gemm256t<3,128><<<dim3(8, 32), 512, 98304, stream>>>(hbuf, base + 2097152, rg_out_b + l*DD, nullptr,
                                                         x, nullptr, DD, 1024);
    // ---- local attention block
    ln_k<<<MM, 256, 0, stream>>>(x, ln2_s + l*DD, ln2_b + l*DD, xn);
    gemm256t<4,256><<<dim3(12, 32), 512, 131072, stream>>>(xn, base + 3145728, qkv_b + l*3072, nullptr,
                                                           (float*)vtb, qkb, DD, 3072);
    attn_mfma<<<dim3(TT/64, BB*HH), 256, 0, stream>>>(qkb, vtb, ybuf);
    gemm256t<3,128><<<dim3(8, 32), 512, 98304, stream>>>(ybuf, base + 6291456, attn_out_b + l*DD, nullptr,
                                                         x, nullptr, DD, 1024);
    // ---- MLP block
    ln_k<<<MM, 256, 0, stream>>>(x, ln3_s + l*DD, ln3_b + l*DD, xn);
    gemm256t<2,256><<<dim3(16, 32), 512, 131072, stream>>>(xn, base + 7340032, mlp_b1 + l*4096, nullptr,
                                                           nullptr, hid, DD, 4096);
    gemm256t<3,128><<<dim3(8, 32), 512, 98304, stream>>>(hid, base + 11534336, mlp_b2 + l*DD, nullptr,
                                                         x, nullptr, 4096, 1024);
  }
}

// Round 10
// 899.565 us; speedup vs baseline: 2.0410x; 1.0010x over previous
//
#include <hip/hip_runtime.h>
#include <math.h>

#define DD 1024
#define TT 2048
#define BB 4
#define HH 4
#define HDIM 256
#define NLAYER 2
#define MM (BB*TT)          // 8192 rows
#define NCHUNK 32
#define CHUNK (TT/NCHUNK)   // 64

typedef unsigned short u16;
typedef __bf16 bf16x8 __attribute__((ext_vector_type(8)));
typedef float f32x4 __attribute__((ext_vector_type(4)));

__device__ __forceinline__ float b2f(u16 h) {
  unsigned u = ((unsigned)h) << 16;
  return __builtin_bit_cast(float, u);
}
__device__ __forceinline__ u16 f2b(float f) {
  unsigned u = __builtin_bit_cast(unsigned, f);
  u += 0x7fffu + ((u >> 16) & 1u);
  return (u16)(u >> 16);
}

#define GLD16(g, l) __builtin_amdgcn_global_load_lds( \
    (__attribute__((address_space(1))) void*)(void*)(g), \
    (__attribute__((address_space(3))) void*)(l), 16, 0, 0)

__device__ __forceinline__ void wg_barrier() {
  asm volatile("" ::: "memory");
  __builtin_amdgcn_s_barrier();
  asm volatile("" ::: "memory");
}
template<int N> __device__ __forceinline__ void wait_vmcnt() {
  asm volatile("s_waitcnt vmcnt(%0)" :: "i"(N) : "memory");
}

// ------- weight fp32 -> bf16 transpose: Wt[N][K] = W[K][N], batched over layers -------
__global__ __launch_bounds__(256)
void transpose_cvt(const float* __restrict__ W, u16* __restrict__ Wt, int K, int N,
                   size_t lsrc, size_t ldst) {
  __shared__ float tile[32][33];
  const float* Wl = W + (size_t)blockIdx.z * lsrc;
  u16* Wtl = Wt + (size_t)blockIdx.z * ldst;
  const int n0 = blockIdx.x << 5, k0 = blockIdx.y << 5;
  const int tx = threadIdx.x, ty = threadIdx.y;
#pragma unroll
  for (int i = 0; i < 4; ++i)
    tile[ty + i*8][tx] = Wl[(size_t)(k0 + ty + i*8) * N + n0 + tx];
  __syncthreads();
#pragma unroll
  for (int i = 0; i < 4; ++i)
    Wtl[(size_t)(n0 + ty + i*8) * K + k0 + tx] = f2b(tile[tx][ty + i*8]);
}

// ---------------- LayerNorm (fp32 in, bf16 out) ----------------
__global__ __launch_bounds__(256)
void ln_k(const float* __restrict__ x, const float* __restrict__ sc,
          const float* __restrict__ bi, u16* __restrict__ xn) {
  const int row = blockIdx.x;
  const int tid = threadIdx.x;
  const float4 xv = ((const float4*)(x + (size_t)row * DD))[tid];
  float s = xv.x + xv.y + xv.z + xv.w;
  float q = xv.x*xv.x + xv.y*xv.y + xv.z*xv.z + xv.w*xv.w;
#pragma unroll
  for (int o = 1; o < 64; o <<= 1) { s += __shfl_xor(s, o); q += __shfl_xor(q, o); }
  __shared__ float rs[4], rq[4];
  if ((tid & 63) == 0) { rs[tid >> 6] = s; rq[tid >> 6] = q; }
  __syncthreads();
  s = rs[0] + rs[1] + rs[2] + rs[3];
  q = rq[0] + rq[1] + rq[2] + rq[3];
  const float mean = s * (1.f / DD);
  const float var = q * (1.f / DD) - mean * mean;
  const float rstd = rsqrtf(var + 1e-5f);
  const float4 sv = ((const float4*)sc)[tid];
  const float4 bv = ((const float4*)bi)[tid];
  const u16 o0 = f2b((xv.x - mean) * rstd * sv.x + bv.x);
  const u16 o1 = f2b((xv.y - mean) * rstd * sv.y + bv.y);
  const u16 o2 = f2b((xv.z - mean) * rstd * sv.z + bv.z);
  const u16 o3 = f2b((xv.w - mean) * rstd * sv.w + bv.w);
  uint2 pk;
  pk.x = (unsigned)o0 | ((unsigned)o1 << 16);
  pk.y = (unsigned)o2 | ((unsigned)o3 << 16);
  *(uint2*)(xn + (size_t)row * DD + (tid << 2)) = pk;
}

// ======== 256x128 8-wave GEMM, BK=32, 3-buffer LDS, 2 blocks/CU ========
// C[M,N] = A[M,K]*Wt[N,K]^T + bias.  512 threads, 72KB dynamic LDS.
// Per K-tile: wait vmcnt(3) [tile kt landed; kt+1 in flight] -> barrier ->
//   ds_read 10 frags (buf kt%3) -> stage tile kt+2 (buf (kt+2)%3, untouched) ->
//   16 MFMA. One barrier/K-tile; never vmcnt(0) mid-loop. Inter-block overlap
//   (2 blocks/CU) hides residual stalls.
// EPI: 2 = bf16 gelu store, 3 = f32 residual add, 4 = qkv split (QK rowmajor + V^T),
//      5 = dual bf16 store (n<1024 -> outb, else outf)
template<int EPI>
__global__ __launch_bounds__(512, 4)
void gemm256t(const u16* __restrict__ A, const u16* __restrict__ Wt,
              const float* __restrict__ bias, const float* __restrict__ bias2,
              float* __restrict__ outf, u16* __restrict__ outb, int K, int N) {
  extern __shared__ u16 lds[];
  const int tid = threadIdx.x;
  const int gx = gridDim.x;
  const int nwg = gx * (int)gridDim.y;
  int lid = (int)blockIdx.y * gx + (int)blockIdx.x;
  lid = (lid & 7) * (nwg >> 3) + (lid >> 3);     // XCD-chunked (nwg % 8 == 0)
  const int m0 = (lid / gx) << 8;
  const int n0 = (lid % gx) << 7;
  const int lane = tid & 63;
  const int wid = tid >> 6;
  const int wm = wid >> 2;          // m-half (128 rows)
  const int wn = wid & 3;           // n-quarter (32 cols)
  const int g = lane >> 4;
  const int lc = lane & 15;
  const int q = tid >> 2;           // staging row 0..127
  const int slot = tid & 3;
  const int scs = (slot ^ ((q >> 1) & 3)) << 3;  // inverse-swizzled source chunk
  const int so = (g ^ ((lc >> 1) & 3)) << 3;     // swizzled read slot

  u16* Ab = lds;            // 3 x [256][32]
  u16* Bbase = lds + 24576; // 3 x [128][32]
  u16 *Ac = Ab, *An = Ab + 8192, *Aw = Ab + 16384;
  u16 *Bc = Bbase, *Bn = Bbase + 4096, *Bw = Bbase + 8192;

  auto stage = [&](int kt, u16* At, u16* Bt) {
    const int kb = (kt << 5) + scs;
    GLD16(A + (size_t)(m0 + q) * K + kb,       At + q*32 + slot*8);
    GLD16(A + (size_t)(m0 + 128 + q) * K + kb, At + (128 + q)*32 + slot*8);
    GLD16(Wt + (size_t)(n0 + q) * K + kb,      Bt + q*32 + slot*8);
  };

  f32x4 acc[8][2];
#pragma unroll
  for (int i = 0; i < 8; ++i)
#pragma unroll
    for (int j = 0; j < 2; ++j)
#pragma unroll
      for (int e = 0; e < 4; ++e) acc[i][j][e] = 0.f;

  const int KT = K >> 5;
  stage(0, Ac, Bc);
  stage(1, An, Bn);

  for (int kt = 0; kt < KT; ++kt) {
    if (kt + 1 < KT) wait_vmcnt<3>();
    else             wait_vmcnt<0>();
    wg_barrier();
    bf16x8 bf0 = *(const bf16x8*)(Bc + (wn*32 + lc)*32 + so);
    bf16x8 bf1 = *(const bf16x8*)(Bc + (wn*32 + 16 + lc)*32 + so);
    bf16x8 af[8];
#pragma unroll
    for (int i = 0; i < 8; ++i)
      af[i] = *(const bf16x8*)(Ac + (wm*128 + i*16 + lc)*32 + so);
    if (kt + 2 < KT) stage(kt + 2, Aw, Bw);
    __builtin_amdgcn_s_setprio(1);
#pragma unroll
    for (int i = 0; i < 8; ++i) {
      acc[i][0] = __builtin_amdgcn_mfma_f32_16x16x32_bf16(af[i], bf0, acc[i][0], 0, 0, 0);
      acc[i][1] = __builtin_amdgcn_mfma_f32_16x16x32_bf16(af[i], bf1, acc[i][1], 0, 0, 0);
    }
    __builtin_amdgcn_s_setprio(0);
    u16* t;
    t = Ac; Ac = An; An = Aw; Aw = t;
    t = Bc; Bc = Bn; Bn = Bw; Bw = t;
  }

#pragma unroll
  for (int mi = 0; mi < 8; ++mi) {
#pragma unroll
    for (int ni = 0; ni < 2; ++ni) {
      const int n = n0 + wn*32 + ni*16 + lc;
      const int mbase = m0 + wm*128 + mi*16 + (g << 2);
      if (EPI == 4) {
        const float bia = bias[n];
        if (n < 2048) {
#pragma unroll
          for (int e = 0; e < 4; ++e)
            outb[(size_t)(mbase + e) * 2048 + n] = f2b(acc[mi][ni][e] + bia);
        } else {
          const int hh = (n - 2048) >> 8, dim = (n - 2048) & 255;
          const int bidx = mbase >> 11, t = mbase & 2047;
          const u16 a0 = f2b(acc[mi][ni][0] + bia);
          const u16 a1 = f2b(acc[mi][ni][1] + bia);
          const u16 a2 = f2b(acc[mi][ni][2] + bia);
          const u16 a3 = f2b(acc[mi][ni][3] + bia);
          uint2 pk;
          pk.x = (unsigned)a0 | ((unsigned)a1 << 16);
          pk.y = (unsigned)a2 | ((unsigned)a3 << 16);
          u16* vtp = (u16*)outf;
          *(uint2*)(vtp + ((size_t)((bidx*4 + hh)*256 + dim)) * 2048 + t) = pk;
        }
      } else if (EPI == 5) {
        const float bia = (n < 1024) ? bias[n] : bias2[n - 1024];
        u16* dst = (n < 1024) ? outb : (u16*)outf;
        const int nn = n & 1023;
#pragma unroll
        for (int e = 0; e < 4; ++e)
          dst[(size_t)(mbase + e) * 1024 + nn] = f2b(acc[mi][ni][e] + bia);
      } else if (EPI == 2) {
        const float bia = bias[n];
#pragma unroll
        for (int e = 0; e < 4; ++e) {
          const float v = acc[mi][ni][e] + bia;
          const float zc = fminf(fmaxf(1.5957691216f * (v + 0.044715f*v*v*v), -30.f), 30.f);
          outb[(size_t)(mbase + e) * N + n] = f2b(v / (1.f + __expf(-zc)));
        }
      } else {  // EPI == 3: f32 residual add
        const float bia = bias[n];
#pragma unroll
        for (int e = 0; e < 4; ++e)
          outf[(size_t)(mbase + e) * N + n] += acc[mi][ni][e] + bia;
      }
    }
  }
}

// ---------------- RG-LRU chunked scan (bf16 z,u inputs): h_t = g*h_{t-1} + (1-g)*u ----
__global__ __launch_bounds__(256)
void scan1_k(const u16* __restrict__ zpre, const u16* __restrict__ u,
             float* __restrict__ aggA, float* __restrict__ aggB) {
  const int d = blockIdx.x * 256 + threadIdx.x;
  const int c = blockIdx.y, b = blockIdx.z;
  const size_t base = ((size_t)b * TT + (size_t)c * CHUNK) * DD + d;
  float a = 1.f, acc = 0.f;
  for (int t = 0; t < CHUNK; ++t) {
    const float gl = 1.f / (1.f + __expf(-b2f(zpre[base + (size_t)t * DD])));
    const float ul = b2f(u[base + (size_t)t * DD]);
    acc = gl * acc + (1.f - gl) * ul;
    a *= gl;
  }
  const size_t o = ((size_t)b * NCHUNK + c) * DD + d;
  aggA[o] = a; aggB[o] = acc;
}

__global__ __launch_bounds__(256)
void scan2_k(const float* __restrict__ aggA, const float* __restrict__ aggB,
             float* __restrict__ carry) {
  const int idx = blockIdx.x * 256 + threadIdx.x;  // b*DD + d
  const int b = idx >> 10, d = idx & 1023;
  float h = 0.f;
  for (int c = 0; c < NCHUNK; ++c) {
    const size_t o = ((size_t)b * NCHUNK + c) * DD + d;
    carry[o] = h;
    h = aggA[o] * h + aggB[o];
  }
}

__global__ __launch_bounds__(256)
void scan3_k(const u16* __restrict__ zpre, const u16* __restrict__ u,
             const float* __restrict__ carry, u16* __restrict__ hout) {
  const int d = blockIdx.x * 256 + threadIdx.x;
  const int c = blockIdx.y, b = blockIdx.z;
  const size_t base = ((size_t)b * TT + (size_t)c * CHUNK) * DD + d;
  float h = carry[((size_t)b * NCHUNK + c) * DD + d];
  for (int t = 0; t < CHUNK; ++t) {
    const float gl = 1.f / (1.f + __expf(-b2f(zpre[base + (size_t)t * DD])));
    const float ul = b2f(u[base + (size_t)t * DD]);
    h = gl * h + (1.f - gl) * ul;
    hout[base + (size_t)t * DD] = f2b(h);
  }
}

// ---------------- MFMA local-window attention ----------------
__global__ __launch_bounds__(256)
void attn_mfma(const u16* __restrict__ qkb, const u16* __restrict__ vt,
               u16* __restrict__ y) {
  __shared__ u16 kv[16384];
  __shared__ u16 pb[4][16][200];
  const int tid = threadIdx.x;
  const int lane = tid & 63;
  const int wid = tid >> 6;
  const int g = lane >> 4;
  const int lc = lane & 15;
  const int t0 = blockIdx.x << 6;
  const int bh = blockIdx.y;
  const int bT = (bh >> 2) * TT;
  const int h = bh & 3;

  bf16x8 afq[8];
  {
    const u16* qg = qkb + (size_t)(bT + t0 + wid*16 + lc) * 2048 + h*256 + g*8;
#pragma unroll
    for (int ks = 0; ks < 8; ++ks)
      afq[ks] = __builtin_bit_cast(bf16x8, *(const uint4*)(qg + ks*32));
  }

  f32x4 sc[12];
#pragma unroll
  for (int f = 0; f < 12; ++f)
#pragma unroll
    for (int e = 0; e < 4; ++e) sc[f][e] = 0.f;

  const int koff = 1024 + h*256;
#pragma unroll
  for (int c = 0; c < 3; ++c) {
    const int j0 = t0 + (c - 2) * 64;
    if (j0 < 0) {
#pragma unroll
      for (int nt = 0; nt < 4; ++nt)
#pragma unroll
        for (int e = 0; e < 4; ++e) sc[c*4+nt][e] = -1e30f;
      continue;
    }
    __syncthreads();
    {
      const u16* kg = qkb + (size_t)(bT + j0) * 2048 + koff;
#pragma unroll
      for (int i = 0; i < 8; ++i) {
        const int o16 = i*256 + tid;
        const int slab = o16 >> 8, key = (o16 >> 2) & 63, ds = o16 & 3;
        GLD16(kg + (size_t)key*2048 + slab*32 + ds*8, kv + o16*8);
      }
    }
    __syncthreads();
#pragma unroll
    for (int nt = 0; nt < 4; ++nt) {
      f32x4 s = sc[c*4+nt];
#pragma unroll
      for (int ks = 0; ks < 8; ++ks) {
        const bf16x8 kb = *(const bf16x8*)(kv + ks*2048 + (nt*16 + lc)*32 + g*8);
        s = __builtin_amdgcn_mfma_f32_16x16x32_bf16(afq[ks], kb, s, 0, 0, 0);
      }
      sc[c*4+nt] = s;
    }
#pragma unroll
    for (int nt = 0; nt < 4; ++nt)
#pragma unroll
      for (int e = 0; e < 4; ++e) {
        const int tl = wid*16 + g*4 + e;
        const int jl = nt*16 + lc;
        const bool ok = (c == 1) || (c == 2 ? (jl <= tl) : (jl >= tl + 1));
        sc[c*4+nt][e] = ok ? sc[c*4+nt][e] * 0.0625f : -1e30f;
      }
  }

#pragma unroll
  for (int e = 0; e < 4; ++e) {
    float m = -1e30f;
#pragma unroll
    for (int f = 0; f < 12; ++f) m = fmaxf(m, sc[f][e]);
    m = fmaxf(m, __shfl_xor(m, 1)); m = fmaxf(m, __shfl_xor(m, 2));
    m = fmaxf(m, __shfl_xor(m, 4)); m = fmaxf(m, __shfl_xor(m, 8));
    float s = 0.f;
#pragma unroll
    for (int f = 0; f < 12; ++f) { const float p = __expf(sc[f][e] - m); sc[f][e] = p; s += p; }
    s += __shfl_xor(s, 1); s += __shfl_xor(s, 2);
    s += __shfl_xor(s, 4); s += __shfl_xor(s, 8);
    const float is = 1.f / s;
#pragma unroll
    for (int f = 0; f < 12; ++f) sc[f][e] *= is;
  }
#pragma unroll
  for (int c = 0; c < 3; ++c)
#pragma unroll
    for (int nt = 0; nt < 4; ++nt)
#pragma unroll
      for (int e = 0; e < 4; ++e)
        pb[wid][g*4 + e][c*64 + nt*16 + lc] = f2b(sc[c*4+nt][e]);

  f32x4 acc[16];
#pragma unroll
  for (int nt = 0; nt < 16; ++nt)
#pragma unroll
    for (int e = 0; e < 4; ++e) acc[nt][e] = 0.f;

  const u16* vg = vt + (size_t)bh * 256 * 2048;
#pragma unroll
  for (int c = 0; c < 3; ++c) {
    const int j0 = t0 + (c - 2) * 64;
    if (j0 < 0) continue;
    __syncthreads();
#pragma unroll
    for (int i = 0; i < 8; ++i) {
      const int o16 = i*256 + tid;
      const int dim = o16 >> 3, slot = o16 & 7;
      const int ss = slot ^ (dim & 7);
      GLD16(vg + (size_t)dim*2048 + j0 + ss*8, kv + o16*8);
    }
    __syncthreads();
#pragma unroll
    for (int ks = 0; ks < 2; ++ks) {
      const bf16x8 pa = *(const bf16x8*)&pb[wid][lc][(c*2 + ks)*32 + g*8];
#pragma unroll
      for (int nt = 0; nt < 16; ++nt) {
        const int dim = nt*16 + lc;
        int boff = dim*128 + ks*64 + g*16;
        boff ^= (dim & 7) << 4;
        const bf16x8 vb = *(const bf16x8*)((const char*)kv + boff);
        acc[nt] = __builtin_amdgcn_mfma_f32_16x16x32_bf16(pa, vb, acc[nt], 0, 0, 0);
      }
    }
  }

#pragma unroll
  for (int nt = 0; nt < 16; ++nt)
#pragma unroll
    for (int e = 0; e < 4; ++e) {
      const int tok = bT + t0 + wid*16 + g*4 + e;
      y[(size_t)tok * 1024 + h*256 + nt*16 + lc] = f2b(acc[nt][e]);
    }
}

// ---------------- host orchestration ----------------
extern "C" void kernel_launch(void* const* d_in, const int* in_sizes, int n_in,
                              void* d_out, int out_size, void* d_ws, size_t ws_size,
                              hipStream_t stream) {
  const float* x_in      = (const float*)d_in[0];
  const float* ln1_s     = (const float*)d_in[1];
  const float* ln1_b     = (const float*)d_in[2];
  const float* ln2_s     = (const float*)d_in[3];
  const float* ln2_b     = (const float*)d_in[4];
  const float* ln3_s     = (const float*)d_in[5];
  const float* ln3_b     = (const float*)d_in[6];
  const float* rg_in_w   = (const float*)d_in[7];
  const float* rg_in_b   = (const float*)d_in[8];
  const float* rg_gate_w = (const float*)d_in[9];
  const float* rg_gate_b = (const float*)d_in[10];
  const float* rg_out_w  = (const float*)d_in[11];
  const float* rg_out_b  = (const float*)d_in[12];
  const float* qkv_w     = (const float*)d_in[13];
  const float* qkv_b     = (const float*)d_in[14];
  const float* attn_out_w= (const float*)d_in[15];
  const float* attn_out_b= (const float*)d_in[16];
  const float* mlp_w1    = (const float*)d_in[17];
  const float* mlp_b1    = (const float*)d_in[18];
  const float* mlp_w2    = (const float*)d_in[19];
  const float* mlp_b2    = (const float*)d_in[20];

  hipFuncSetAttribute((const void*)&gemm256t<5>, hipFuncAttributeMaxDynamicSharedMemorySize, 73728);
  hipFuncSetAttribute((const void*)&gemm256t<4>, hipFuncAttributeMaxDynamicSharedMemorySize, 73728);
  hipFuncSetAttribute((const void*)&gemm256t<2>, hipFuncAttributeMaxDynamicSharedMemorySize, 73728);
  hipFuncSetAttribute((const void*)&gemm256t<3>, hipFuncAttributeMaxDynamicSharedMemorySize, 73728);

  float* x = (float*)d_out;
  char* ws = (char*)d_ws;
  u16*  wt     = (u16*)ws;                          // 62,914,560 B (bf16 transposed weights)
  u16*  xn     = (u16*)(ws + 62914560);             // 16,777,216 B
  char* bigS   = ws + 62914560 + 16777216;          // 67,108,864 B
  char* smallS = bigS + 67108864;                   // 16,777,216 B
  float* aggA  = (float*)(smallS + 16777216);
  float* aggB  = aggA + (size_t)BB * NCHUNK * DD;
  float* carry = aggB + (size_t)BB * NCHUNK * DD;

  u16* ubuf = (u16*)bigS;                           // RG phase (bf16)
  u16* zbuf = (u16*)(bigS + 33554432);              // pre-sigmoid gate, bf16
  u16* qkb  = (u16*)bigS;                           // attn phase: [8192][2048] QK
  u16* vtb  = (u16*)(bigS + 33554432);              // attn phase: V transposed, 16MB
  u16* hid  = (u16*)bigS;                           // MLP phase
  u16* hbuf = (u16*)smallS;
  u16* ybuf = (u16*)smallS;

  hipMemcpyAsync(x, x_in, (size_t)MM * DD * sizeof(float), hipMemcpyDeviceToDevice, stream);

  const size_t LW = 15728640;
  const dim3 tb(32, 8);
  // batched over both layers via blockIdx.z
  transpose_cvt<<<dim3(32, 32, 2),  tb, 0, stream>>>(rg_in_w,    wt + 0,        DD, DD,   DD*DD,   LW);
  transpose_cvt<<<dim3(32, 32, 2),  tb, 0, stream>>>(rg_gate_w,  wt + 1048576,  DD, DD,   DD*DD,   LW);
  transpose_cvt<<<dim3(32, 32, 2),  tb, 0, stream>>>(rg_out_w,   wt + 2097152,  DD, DD,   DD*DD,   LW);
  transpose_cvt<<<dim3(96, 32, 2),  tb, 0, stream>>>(qkv_w,      wt + 3145728,  DD, 3072, DD*3072, LW);
  transpose_cvt<<<dim3(32, 32, 2),  tb, 0, stream>>>(attn_out_w, wt + 6291456,  DD, DD,   DD*DD,   LW);
  transpose_cvt<<<dim3(128, 32, 2), tb, 0, stream>>>(mlp_w1,     wt + 7340032,  DD, 4096, DD*4096, LW);
  transpose_cvt<<<dim3(32, 128, 2), tb, 0, stream>>>(mlp_w2,     wt + 11534336, 4096, DD, 4096*DD, LW);

  for (int l = 0; l < NLAYER; ++l) {
    u16* base = wt + (size_t)l * LW;
    // ---- RG-LRU block (rg_in + rg_gate fused; u and pre-sigmoid z stored bf16)
    ln_k<<<MM, 256, 0, stream>>>(x, ln1_s + l*DD, ln1_b + l*DD, xn);
    gemm256t<5><<<dim3(16, 32), 512, 73728, stream>>>(xn, base + 0, rg_in_b + l*DD, rg_gate_b + l*DD,
                                                      (float*)zbuf, ubuf, DD, 2048);
    scan1_k<<<dim3(4, NCHUNK, BB), 256, 0, stream>>>(zbuf, ubuf, aggA, aggB);
    scan2_k<<<16, 256, 0, stream>>>(aggA, aggB, carry);
    scan3_k<<<dim3(4, NCHUNK, BB), 256, 0, stream>>>(zbuf, ubuf, carry, hbuf);
    gemm256t<3><<<dim3(8, 32), 512, 73728, stream>>>(hbuf, base + 2097152, rg_out_b + l*DD, nullptr,
                                                     x, nullptr, DD, 1024);
    // ---- local attention block
    ln_k<<<MM, 256, 0, stream>>>(x, ln2_s + l*DD, ln2_b + l*DD, xn);
    gemm256t<4><<<dim3(24, 32), 512, 73728, stream>>>(xn, base + 3145728, qkv_b + l*3072, nullptr,
                                                      (float*)vtb, qkb, DD, 3072);
    attn_mfma<<<dim3(TT/64, BB*HH), 256, 0, stream>>>(qkb, vtb, ybuf);
    gemm256t<3><<<dim3(8, 32), 512, 73728, stream>>>(ybuf, base + 6291456, attn_out_b + l*DD, nullptr,
                                                     x, nullptr, DD, 1024);
    // ---- MLP block
    ln_k<<<MM, 256, 0, stream>>>(x, ln3_s + l*DD, ln3_b + l*DD, xn);
    gemm256t<2><<<dim3(32, 32), 512, 73728, stream>>>(xn, base + 7340032, mlp_b1 + l*4096, nullptr,
                                                      nullptr, hid, DD, 4096);
    gemm256t<3><<<dim3(8, 32), 512, 73728, stream>>>(hid, base + 11534336, mlp_b2 + l*DD, nullptr,
                                                     x, nullptr, 4096, 1024);
  }
}

// Round 11
// 893.386 us; speedup vs baseline: 2.0551x; 1.0069x over previous
//
#include <hip/hip_runtime.h>
#include <math.h>

#define DD 1024
#define TT 2048
#define BB 4
#define HH 4
#define HDIM 256
#define NLAYER 2
#define MM (BB*TT)          // 8192 rows
#define NCHUNK 32
#define CHUNK (TT/NCHUNK)   // 64

typedef unsigned short u16;
typedef __bf16 bf16x8 __attribute__((ext_vector_type(8)));
typedef float f32x4 __attribute__((ext_vector_type(4)));
typedef float f32x16 __attribute__((ext_vector_type(16)));

__device__ __forceinline__ float b2f(u16 h) {
  unsigned u = ((unsigned)h) << 16;
  return __builtin_bit_cast(float, u);
}
__device__ __forceinline__ u16 f2b(float f) {
  unsigned u = __builtin_bit_cast(unsigned, f);
  u += 0x7fffu + ((u >> 16) & 1u);
  return (u16)(u >> 16);
}

#define GLD16(g, l) __builtin_amdgcn_global_load_lds( \
    (__attribute__((address_space(1))) void*)(void*)(g), \
    (__attribute__((address_space(3))) void*)(l), 16, 0, 0)

__device__ __forceinline__ void wg_barrier() {
  asm volatile("" ::: "memory");
  __builtin_amdgcn_s_barrier();
  asm volatile("" ::: "memory");
}
template<int N> __device__ __forceinline__ void wait_vmcnt() {
  asm volatile("s_waitcnt vmcnt(%0)" :: "i"(N) : "memory");
}

// ------- weight fp32 -> bf16 transpose: Wt[N][K] = W[K][N], batched over layers -------
__global__ __launch_bounds__(256)
void transpose_cvt(const float* __restrict__ W, u16* __restrict__ Wt, int K, int N,
                   size_t lsrc, size_t ldst) {
  __shared__ float tile[32][33];
  const float* Wl = W + (size_t)blockIdx.z * lsrc;
  u16* Wtl = Wt + (size_t)blockIdx.z * ldst;
  const int n0 = blockIdx.x << 5, k0 = blockIdx.y << 5;
  const int tx = threadIdx.x, ty = threadIdx.y;
#pragma unroll
  for (int i = 0; i < 4; ++i)
    tile[ty + i*8][tx] = Wl[(size_t)(k0 + ty + i*8) * N + n0 + tx];
  __syncthreads();
#pragma unroll
  for (int i = 0; i < 4; ++i)
    Wtl[(size_t)(n0 + ty + i*8) * K + k0 + tx] = f2b(tile[tx][ty + i*8]);
}

// ---------------- LayerNorm (fp32 in, bf16 out) ----------------
__global__ __launch_bounds__(256)
void ln_k(const float* __restrict__ x, const float* __restrict__ sc,
          const float* __restrict__ bi, u16* __restrict__ xn) {
  const int row = blockIdx.x;
  const int tid = threadIdx.x;
  const float4 xv = ((const float4*)(x + (size_t)row * DD))[tid];
  float s = xv.x + xv.y + xv.z + xv.w;
  float q = xv.x*xv.x + xv.y*xv.y + xv.z*xv.z + xv.w*xv.w;
#pragma unroll
  for (int o = 1; o < 64; o <<= 1) { s += __shfl_xor(s, o); q += __shfl_xor(q, o); }
  __shared__ float rs[4], rq[4];
  if ((tid & 63) == 0) { rs[tid >> 6] = s; rq[tid >> 6] = q; }
  __syncthreads();
  s = rs[0] + rs[1] + rs[2] + rs[3];
  q = rq[0] + rq[1] + rq[2] + rq[3];
  const float mean = s * (1.f / DD);
  const float var = q * (1.f / DD) - mean * mean;
  const float rstd = rsqrtf(var + 1e-5f);
  const float4 sv = ((const float4*)sc)[tid];
  const float4 bv = ((const float4*)bi)[tid];
  const u16 o0 = f2b((xv.x - mean) * rstd * sv.x + bv.x);
  const u16 o1 = f2b((xv.y - mean) * rstd * sv.y + bv.y);
  const u16 o2 = f2b((xv.z - mean) * rstd * sv.z + bv.z);
  const u16 o3 = f2b((xv.w - mean) * rstd * sv.w + bv.w);
  uint2 pk;
  pk.x = (unsigned)o0 | ((unsigned)o1 << 16);
  pk.y = (unsigned)o2 | ((unsigned)o3 << 16);
  *(uint2*)(xn + (size_t)row * DD + (tid << 2)) = pk;
}

// ======== 256x128 8-wave GEMM, 32x32x16 MFMA, BK=32, 3-buffer LDS, 2 blocks/CU ========
// C[M,N] = A[M,K]*Wt[N,K]^T + bias.  512 threads, 72KB dynamic LDS.
// Waves 4M x 2N, per-wave 64x64 output = 2x2 tiles of 32x32 (f32x16 acc each).
// A/B frag: lane l holds row l&31, k (l>>5)*8..+7 (b128 from LDS).
// C/D: col = lane&31, row = (reg&3) + 8*(reg>>2) + 4*(lane>>5).
// Swizzle key K(r) = ((r>>1)&3)^((r>>3)&1) applied to 16B slot, both sides.
// EPI: 2 = bf16 gelu store, 3 = f32 out = addf + gemm, 4 = qkv split, 5 = dual bf16
template<int EPI>
__global__ __launch_bounds__(512, 4)
void gemm256t(const u16* __restrict__ A, const u16* __restrict__ Wt,
              const float* __restrict__ bias, const float* __restrict__ bias2,
              const float* __restrict__ addf,
              float* __restrict__ outf, u16* __restrict__ outb, int K, int N) {
  extern __shared__ u16 lds[];
  const int tid = threadIdx.x;
  const int gx = gridDim.x;
  const int nwg = gx * (int)gridDim.y;
  int lid = (int)blockIdx.y * gx + (int)blockIdx.x;
  lid = (lid & 7) * (nwg >> 3) + (lid >> 3);     // XCD-chunked (nwg % 8 == 0)
  const int m0 = (lid / gx) << 8;
  const int n0 = (lid % gx) << 7;
  const int lane = tid & 63;
  const int wid = tid >> 6;
  const int wm = wid >> 1;          // 0..3 -> 64-row band
  const int wn = wid & 1;           // 0..1 -> 64-col band
  const int lr = lane & 31;
  const int lh = lane >> 5;
  const int Kl = ((lr >> 1) & 3) ^ ((lr >> 3) & 1);   // read-side swizzle key
  const int q = tid >> 2;           // staging row 0..127
  const int slot = tid & 3;
  const int Kq = ((q >> 1) & 3) ^ ((q >> 3) & 1);
  const int scs = (slot ^ Kq) << 3; // inverse-swizzled source chunk (bf16 elems)

  u16* Ab = lds;            // 3 x [256][32]
  u16* Bbase = lds + 24576; // 3 x [128][32]
  u16 *Ac = Ab, *An = Ab + 8192, *Aw = Ab + 16384;
  u16 *Bc = Bbase, *Bn = Bbase + 4096, *Bw = Bbase + 8192;

  auto stage = [&](int kt, u16* At, u16* Bt) {
    const int kb = (kt << 5) + scs;
    GLD16(A + (size_t)(m0 + q) * K + kb,       At + q*32 + slot*8);
    GLD16(A + (size_t)(m0 + 128 + q) * K + kb, At + (128 + q)*32 + slot*8);
    GLD16(Wt + (size_t)(n0 + q) * K + kb,      Bt + q*32 + slot*8);
  };

  f32x16 accA, accB, accC, accD;   // [mt][nt]: A=00 B=01 C=10 D=11 (static names, rule #20)
#pragma unroll
  for (int e = 0; e < 16; ++e) { accA[e] = 0.f; accB[e] = 0.f; accC[e] = 0.f; accD[e] = 0.f; }

  const int KT = K >> 5;
  stage(0, Ac, Bc);
  stage(1, An, Bn);

  for (int kt = 0; kt < KT; ++kt) {
    if (kt + 1 < KT) wait_vmcnt<3>();
    else             wait_vmcnt<0>();
    wg_barrier();
    bf16x8 af[2][2], bfr[2][2];
#pragma unroll
    for (int mt = 0; mt < 2; ++mt)
#pragma unroll
      for (int ks = 0; ks < 2; ++ks)
        af[mt][ks] = *(const bf16x8*)(Ac + (wm*64 + mt*32 + lr)*32 + (((ks*2 + lh) ^ Kl) << 3));
#pragma unroll
    for (int nt = 0; nt < 2; ++nt)
#pragma unroll
      for (int ks = 0; ks < 2; ++ks)
        bfr[nt][ks] = *(const bf16x8*)(Bc + (wn*64 + nt*32 + lr)*32 + (((ks*2 + lh) ^ Kl) << 3));
    if (kt + 2 < KT) stage(kt + 2, Aw, Bw);
    __builtin_amdgcn_s_setprio(1);
#pragma unroll
    for (int ks = 0; ks < 2; ++ks) {
      accA = __builtin_amdgcn_mfma_f32_32x32x16_bf16(af[0][ks], bfr[0][ks], accA, 0, 0, 0);
      accB = __builtin_amdgcn_mfma_f32_32x32x16_bf16(af[0][ks], bfr[1][ks], accB, 0, 0, 0);
      accC = __builtin_amdgcn_mfma_f32_32x32x16_bf16(af[1][ks], bfr[0][ks], accC, 0, 0, 0);
      accD = __builtin_amdgcn_mfma_f32_32x32x16_bf16(af[1][ks], bfr[1][ks], accD, 0, 0, 0);
    }
    __builtin_amdgcn_s_setprio(0);
    u16* t;
    t = Ac; Ac = An; An = Aw; Aw = t;
    t = Bc; Bc = Bn; Bn = Bw; Bw = t;
  }

  // epilogue over the 4 tiles (static unroll)
#pragma unroll
  for (int mt = 0; mt < 2; ++mt) {
#pragma unroll
    for (int nt = 0; nt < 2; ++nt) {
      const f32x16 acc = (mt == 0) ? (nt == 0 ? accA : accB) : (nt == 0 ? accC : accD);
      const int mrow0 = m0 + wm*64 + mt*32;
      const int n = n0 + wn*64 + nt*32 + lr;
      const float bia = (EPI == 5) ? ((n & 1024) ? bias2[n & 1023] : bias[n])
                                   : bias[n];
#pragma unroll
      for (int rq = 0; rq < 4; ++rq) {
        const int rl = 8*rq + 4*lh;      // local row of reg rq*4 (+e)
        if (EPI == 4) {
          if (n < 2048) {
#pragma unroll
            for (int e = 0; e < 4; ++e)
              outb[(size_t)(mrow0 + rl + e) * 2048 + n] = f2b(acc[rq*4 + e] + bia);
          } else {
            const int hh = (n - 2048) >> 8, dim = (n - 2048) & 255;
            const int grow = mrow0 + rl;
            const int bidx = grow >> 11, t0 = grow & 2047;
            const u16 a0 = f2b(acc[rq*4 + 0] + bia);
            const u16 a1 = f2b(acc[rq*4 + 1] + bia);
            const u16 a2 = f2b(acc[rq*4 + 2] + bia);
            const u16 a3 = f2b(acc[rq*4 + 3] + bia);
            uint2 pk;
            pk.x = (unsigned)a0 | ((unsigned)a1 << 16);
            pk.y = (unsigned)a2 | ((unsigned)a3 << 16);
            u16* vtp = (u16*)outf;
            *(uint2*)(vtp + ((size_t)((bidx*4 + hh)*256 + dim)) * 2048 + t0) = pk;
          }
        } else if (EPI == 5) {
          u16* dst = (n & 1024) ? (u16*)outf : outb;
          const int nn = n & 1023;
#pragma unroll
          for (int e = 0; e < 4; ++e)
            dst[(size_t)(mrow0 + rl + e) * 1024 + nn] = f2b(acc[rq*4 + e] + bia);
        } else if (EPI == 2) {
#pragma unroll
          for (int e = 0; e < 4; ++e) {
            const float v = acc[rq*4 + e] + bia;
            const float zc = fminf(fmaxf(1.5957691216f * (v + 0.044715f*v*v*v), -30.f), 30.f);
            outb[(size_t)(mrow0 + rl + e) * N + n] = f2b(v / (1.f + __expf(-zc)));
          }
        } else {  // EPI == 3: out = addf + gemm + bias
#pragma unroll
          for (int e = 0; e < 4; ++e) {
            const size_t idx = (size_t)(mrow0 + rl + e) * N + n;
            outf[idx] = addf[idx] + acc[rq*4 + e] + bia;
          }
        }
      }
    }
  }
}

// ---------------- RG-LRU chunked scan (bf16 z,u inputs): h_t = g*h_{t-1} + (1-g)*u ----
__global__ __launch_bounds__(256)
void scan1_k(const u16* __restrict__ zpre, const u16* __restrict__ u,
             float* __restrict__ aggA, float* __restrict__ aggB) {
  const int d = blockIdx.x * 256 + threadIdx.x;
  const int c = blockIdx.y, b = blockIdx.z;
  const size_t base = ((size_t)b * TT + (size_t)c * CHUNK) * DD + d;
  float a = 1.f, acc = 0.f;
  for (int t = 0; t < CHUNK; ++t) {
    const float gl = 1.f / (1.f + __expf(-b2f(zpre[base + (size_t)t * DD])));
    const float ul = b2f(u[base + (size_t)t * DD]);
    acc = gl * acc + (1.f - gl) * ul;
    a *= gl;
  }
  const size_t o = ((size_t)b * NCHUNK + c) * DD + d;
  aggA[o] = a; aggB[o] = acc;
}

__global__ __launch_bounds__(256)
void scan2_k(const float* __restrict__ aggA, const float* __restrict__ aggB,
             float* __restrict__ carry) {
  const int idx = blockIdx.x * 256 + threadIdx.x;  // b*DD + d
  const int b = idx >> 10, d = idx & 1023;
  float h = 0.f;
  for (int c = 0; c < NCHUNK; ++c) {
    const size_t o = ((size_t)b * NCHUNK + c) * DD + d;
    carry[o] = h;
    h = aggA[o] * h + aggB[o];
  }
}

__global__ __launch_bounds__(256)
void scan3_k(const u16* __restrict__ zpre, const u16* __restrict__ u,
             const float* __restrict__ carry, u16* __restrict__ hout) {
  const int d = blockIdx.x * 256 + threadIdx.x;
  const int c = blockIdx.y, b = blockIdx.z;
  const size_t base = ((size_t)b * TT + (size_t)c * CHUNK) * DD + d;
  float h = carry[((size_t)b * NCHUNK + c) * DD + d];
  for (int t = 0; t < CHUNK; ++t) {
    const float gl = 1.f / (1.f + __expf(-b2f(zpre[base + (size_t)t * DD])));
    const float ul = b2f(u[base + (size_t)t * DD]);
    h = gl * h + (1.f - gl) * ul;
    hout[base + (size_t)t * DD] = f2b(h);
  }
}

// ---------------- MFMA local-window attention ----------------
__global__ __launch_bounds__(256)
void attn_mfma(const u16* __restrict__ qkb, const u16* __restrict__ vt,
               u16* __restrict__ y) {
  __shared__ u16 kv[16384];
  __shared__ u16 pb[4][16][200];
  const int tid = threadIdx.x;
  const int lane = tid & 63;
  const int wid = tid >> 6;
  const int g = lane >> 4;
  const int lc = lane & 15;
  const int t0 = blockIdx.x << 6;
  const int bh = blockIdx.y;
  const int bT = (bh >> 2) * TT;
  const int h = bh & 3;

  bf16x8 afq[8];
  {
    const u16* qg = qkb + (size_t)(bT + t0 + wid*16 + lc) * 2048 + h*256 + g*8;
#pragma unroll
    for (int ks = 0; ks < 8; ++ks)
      afq[ks] = __builtin_bit_cast(bf16x8, *(const uint4*)(qg + ks*32));
  }

  f32x4 sc[12];
#pragma unroll
  for (int f = 0; f < 12; ++f)
#pragma unroll
    for (int e = 0; e < 4; ++e) sc[f][e] = 0.f;

  const int koff = 1024 + h*256;
#pragma unroll
  for (int c = 0; c < 3; ++c) {
    const int j0 = t0 + (c - 2) * 64;
    if (j0 < 0) {
#pragma unroll
      for (int nt = 0; nt < 4; ++nt)
#pragma unroll
        for (int e = 0; e < 4; ++e) sc[c*4+nt][e] = -1e30f;
      continue;
    }
    __syncthreads();
    {
      const u16* kg = qkb + (size_t)(bT + j0) * 2048 + koff;
#pragma unroll
      for (int i = 0; i < 8; ++i) {
        const int o16 = i*256 + tid;
        const int slab = o16 >> 8, key = (o16 >> 2) & 63, ds = o16 & 3;
        GLD16(kg + (size_t)key*2048 + slab*32 + ds*8, kv + o16*8);
      }
    }
    __syncthreads();
#pragma unroll
    for (int nt = 0; nt < 4; ++nt) {
      f32x4 s = sc[c*4+nt];
#pragma unroll
      for (int ks = 0; ks < 8; ++ks) {
        const bf16x8 kb = *(const bf16x8*)(kv + ks*2048 + (nt*16 + lc)*32 + g*8);
        s = __builtin_amdgcn_mfma_f32_16x16x32_bf16(afq[ks], kb, s, 0, 0, 0);
      }
      sc[c*4+nt] = s;
    }
#pragma unroll
    for (int nt = 0; nt < 4; ++nt)
#pragma unroll
      for (int e = 0; e < 4; ++e) {
        const int tl = wid*16 + g*4 + e;
        const int jl = nt*16 + lc;
        const bool ok = (c == 1) || (c == 2 ? (jl <= tl) : (jl >= tl + 1));
        sc[c*4+nt][e] = ok ? sc[c*4+nt][e] * 0.0625f : -1e30f;
      }
  }

#pragma unroll
  for (int e = 0; e < 4; ++e) {
    float m = -1e30f;
#pragma unroll
    for (int f = 0; f < 12; ++f) m = fmaxf(m, sc[f][e]);
    m = fmaxf(m, __shfl_xor(m, 1)); m = fmaxf(m, __shfl_xor(m, 2));
    m = fmaxf(m, __shfl_xor(m, 4)); m = fmaxf(m, __shfl_xor(m, 8));
    float s = 0.f;
#pragma unroll
    for (int f = 0; f < 12; ++f) { const float p = __expf(sc[f][e] - m); sc[f][e] = p; s += p; }
    s += __shfl_xor(s, 1); s += __shfl_xor(s, 2);
    s += __shfl_xor(s, 4); s += __shfl_xor(s, 8);
    const float is = 1.f / s;
#pragma unroll
    for (int f = 0; f < 12; ++f) sc[f][e] *= is;
  }
#pragma unroll
  for (int c = 0; c < 3; ++c)
#pragma unroll
    for (int nt = 0; nt < 4; ++nt)
#pragma unroll
      for (int e = 0; e < 4; ++e)
        pb[wid][g*4 + e][c*64 + nt*16 + lc] = f2b(sc[c*4+nt][e]);

  f32x4 acc[16];
#pragma unroll
  for (int nt = 0; nt < 16; ++nt)
#pragma unroll
    for (int e = 0; e < 4; ++e) acc[nt][e] = 0.f;

  const u16* vg = vt + (size_t)bh * 256 * 2048;
#pragma unroll
  for (int c = 0; c < 3; ++c) {
    const int j0 = t0 + (c - 2) * 64;
    if (j0 < 0) continue;
    __syncthreads();
#pragma unroll
    for (int i = 0; i < 8; ++i) {
      const int o16 = i*256 + tid;
      const int dim = o16 >> 3, slot = o16 & 7;
      const int ss = slot ^ (dim & 7);
      GLD16(vg + (size_t)dim*2048 + j0 + ss*8, kv + o16*8);
    }
    __syncthreads();
#pragma unroll
    for (int ks = 0; ks < 2; ++ks) {
      const bf16x8 pa = *(const bf16x8*)&pb[wid][lc][(c*2 + ks)*32 + g*8];
#pragma unroll
      for (int nt = 0; nt < 16; ++nt) {
        const int dim = nt*16 + lc;
        int boff = dim*128 + ks*64 + g*16;
        boff ^= (dim & 7) << 4;
        const bf16x8 vb = *(const bf16x8*)((const char*)kv + boff);
        acc[nt] = __builtin_amdgcn_mfma_f32_16x16x32_bf16(pa, vb, acc[nt], 0, 0, 0);
      }
    }
  }

#pragma unroll
  for (int nt = 0; nt < 16; ++nt)
#pragma unroll
    for (int e = 0; e < 4; ++e) {
      const int tok = bT + t0 + wid*16 + g*4 + e;
      y[(size_t)tok * 1024 + h*256 + nt*16 + lc] = f2b(acc[nt][e]);
    }
}

// ---------------- host orchestration ----------------
extern "C" void kernel_launch(void* const* d_in, const int* in_sizes, int n_in,
                              void* d_out, int out_size, void* d_ws, size_t ws_size,
                              hipStream_t stream) {
  const float* x_in      = (const float*)d_in[0];
  const float* ln1_s     = (const float*)d_in[1];
  const float* ln1_b     = (const float*)d_in[2];
  const float* ln2_s     = (const float*)d_in[3];
  const float* ln2_b     = (const float*)d_in[4];
  const float* ln3_s     = (const float*)d_in[5];
  const float* ln3_b     = (const float*)d_in[6];
  const float* rg_in_w   = (const float*)d_in[7];
  const float* rg_in_b   = (const float*)d_in[8];
  const float* rg_gate_w = (const float*)d_in[9];
  const float* rg_gate_b = (const float*)d_in[10];
  const float* rg_out_w  = (const float*)d_in[11];
  const float* rg_out_b  = (const float*)d_in[12];
  const float* qkv_w     = (const float*)d_in[13];
  const float* qkv_b     = (const float*)d_in[14];
  const float* attn_out_w= (const float*)d_in[15];
  const float* attn_out_b= (const float*)d_in[16];
  const float* mlp_w1    = (const float*)d_in[17];
  const float* mlp_b1    = (const float*)d_in[18];
  const float* mlp_w2    = (const float*)d_in[19];
  const float* mlp_b2    = (const float*)d_in[20];

  hipFuncSetAttribute((const void*)&gemm256t<5>, hipFuncAttributeMaxDynamicSharedMemorySize, 73728);
  hipFuncSetAttribute((const void*)&gemm256t<4>, hipFuncAttributeMaxDynamicSharedMemorySize, 73728);
  hipFuncSetAttribute((const void*)&gemm256t<2>, hipFuncAttributeMaxDynamicSharedMemorySize, 73728);
  hipFuncSetAttribute((const void*)&gemm256t<3>, hipFuncAttributeMaxDynamicSharedMemorySize, 73728);

  float* x = (float*)d_out;
  char* ws = (char*)d_ws;
  u16*  wt     = (u16*)ws;                          // 62,914,560 B (bf16 transposed weights)
  u16*  xn     = (u16*)(ws + 62914560);             // 16,777,216 B
  char* bigS   = ws + 62914560 + 16777216;          // 67,108,864 B
  char* smallS = bigS + 67108864;                   // 16,777,216 B
  float* aggA  = (float*)(smallS + 16777216);
  float* aggB  = aggA + (size_t)BB * NCHUNK * DD;
  float* carry = aggB + (size_t)BB * NCHUNK * DD;

  u16* ubuf = (u16*)bigS;                           // RG phase (bf16)
  u16* zbuf = (u16*)(bigS + 33554432);              // pre-sigmoid gate, bf16
  u16* qkb  = (u16*)bigS;                           // attn phase: [8192][2048] QK
  u16* vtb  = (u16*)(bigS + 33554432);              // attn phase: V transposed, 16MB
  u16* hid  = (u16*)bigS;                           // MLP phase
  u16* hbuf = (u16*)smallS;
  u16* ybuf = (u16*)smallS;

  const size_t LW = 15728640;
  const dim3 tb(32, 8);
  // batched over both layers via blockIdx.z
  transpose_cvt<<<dim3(32, 32, 2),  tb, 0, stream>>>(rg_in_w,    wt + 0,        DD, DD,   DD*DD,   LW);
  transpose_cvt<<<dim3(32, 32, 2),  tb, 0, stream>>>(rg_gate_w,  wt + 1048576,  DD, DD,   DD*DD,   LW);
  transpose_cvt<<<dim3(32, 32, 2),  tb, 0, stream>>>(rg_out_w,   wt + 2097152,  DD, DD,   DD*DD,   LW);
  transpose_cvt<<<dim3(96, 32, 2),  tb, 0, stream>>>(qkv_w,      wt + 3145728,  DD, 3072, DD*3072, LW);
  transpose_cvt<<<dim3(32, 32, 2),  tb, 0, stream>>>(attn_out_w, wt + 6291456,  DD, DD,   DD*DD,   LW);
  transpose_cvt<<<dim3(128, 32, 2), tb, 0, stream>>>(mlp_w1,     wt + 7340032,  DD, 4096, DD*4096, LW);
  transpose_cvt<<<dim3(32, 128, 2), tb, 0, stream>>>(mlp_w2,     wt + 11534336, 4096, DD, 4096*DD, LW);

  for (int l = 0; l < NLAYER; ++l) {
    u16* base = wt + (size_t)l * LW;
    const float* xsrc = (l == 0) ? x_in : x;   // residual source before rg_out writes x
    // ---- RG-LRU block (rg_in + rg_gate fused; u and pre-sigmoid z stored bf16)
    ln_k<<<MM, 256, 0, stream>>>(xsrc, ln1_s + l*DD, ln1_b + l*DD, xn);
    gemm256t<5><<<dim3(16, 32), 512, 73728, stream>>>(xn, base + 0, rg_in_b + l*DD, rg_gate_b + l*DD,
                                                      nullptr, (float*)zbuf, ubuf, DD, 2048);
    scan1_k<<<dim3(4, NCHUNK, BB), 256, 0, stream>>>(zbuf, ubuf, aggA, aggB);
    scan2_k<<<16, 256, 0, stream>>>(aggA, aggB, carry);
    scan3_k<<<dim3(4, NCHUNK, BB), 256, 0, stream>>>(zbuf, ubuf, carry, hbuf);
    gemm256t<3><<<dim3(8, 32), 512, 73728, stream>>>(hbuf, base + 2097152, rg_out_b + l*DD, nullptr,
                                                     xsrc, x, nullptr, DD, 1024);
    // ---- local attention block
    ln_k<<<MM, 256, 0, stream>>>(x, ln2_s + l*DD, ln2_b + l*DD, xn);
    gemm256t<4><<<dim3(24, 32), 512, 73728, stream>>>(xn, base + 3145728, qkv_b + l*3072, nullptr,
                                                      nullptr, (float*)vtb, qkb, DD, 3072);
    attn_mfma<<<dim3(TT/64, BB*HH), 256, 0, stream>>>(qkb, vtb, ybuf);
    gemm256t<3><<<dim3(8, 32), 512, 73728, stream>>>(ybuf, base + 6291456, attn_out_b + l*DD, nullptr,
                                                     x, x, nullptr, DD, 1024);
    // ---- MLP block
    ln_k<<<MM, 256, 0, stream>>>(x, ln3_s + l*DD, ln3_b + l*DD, xn);
    gemm256t<2><<<dim3(32, 32), 512, 73728, stream>>>(xn, base + 7340032, mlp_b1 + l*4096, nullptr,
                                                      nullptr, nullptr, hid, DD, 4096);
    gemm256t<3><<<dim3(8, 32), 512, 73728, stream>>>(hid, base + 11534336, mlp_b2 + l*DD, nullptr,
                                                     x, x, nullptr, 4096, 1024);
  }
}

// Round 12
// 848.214 us; speedup vs baseline: 2.1646x; 1.0533x over previous
//
#include <hip/hip_runtime.h>
#include <math.h>

#define DD 1024
#define TT 2048
#define BB 4
#define HH 4
#define HDIM 256
#define NLAYER 2
#define MM (BB*TT)          // 8192 rows
#define NCHUNK 32
#define CHUNK (TT/NCHUNK)   // 64

typedef unsigned short u16;
typedef __bf16 bf16x8 __attribute__((ext_vector_type(8)));
typedef float f32x4 __attribute__((ext_vector_type(4)));

__device__ __forceinline__ float b2f(u16 h) {
  unsigned u = ((unsigned)h) << 16;
  return __builtin_bit_cast(float, u);
}
__device__ __forceinline__ u16 f2b(float f) {
  unsigned u = __builtin_bit_cast(unsigned, f);
  u += 0x7fffu + ((u >> 16) & 1u);
  return (u16)(u >> 16);
}

#define GLD16(g, l) __builtin_amdgcn_global_load_lds( \
    (__attribute__((address_space(1))) void*)(void*)(g), \
    (__attribute__((address_space(3))) void*)(l), 16, 0, 0)

__device__ __forceinline__ void wg_barrier() {
  asm volatile("" ::: "memory");
  __builtin_amdgcn_s_barrier();
  asm volatile("" ::: "memory");
}
template<int N> __device__ __forceinline__ void wait_vmcnt() {
  asm volatile("s_waitcnt vmcnt(%0)" :: "i"(N) : "memory");
}

// ------- weight fp32 -> bf16 transpose: Wt[N][K] = W[K][N], batched over layers -------
__global__ __launch_bounds__(256)
void transpose_cvt(const float* __restrict__ W, u16* __restrict__ Wt, int K, int N,
                   size_t lsrc, size_t ldst) {
  __shared__ float tile[32][33];
  const float* Wl = W + (size_t)blockIdx.z * lsrc;
  u16* Wtl = Wt + (size_t)blockIdx.z * ldst;
  const int n0 = blockIdx.x << 5, k0 = blockIdx.y << 5;
  const int tx = threadIdx.x, ty = threadIdx.y;
#pragma unroll
  for (int i = 0; i < 4; ++i)
    tile[ty + i*8][tx] = Wl[(size_t)(k0 + ty + i*8) * N + n0 + tx];
  __syncthreads();
#pragma unroll
  for (int i = 0; i < 4; ++i)
    Wtl[(size_t)(n0 + ty + i*8) * K + k0 + tx] = f2b(tile[tx][ty + i*8]);
}

// ---------------- LayerNorm (fp32 in, bf16 out) ----------------
__global__ __launch_bounds__(256)
void ln_k(const float* __restrict__ x, const float* __restrict__ sc,
          const float* __restrict__ bi, u16* __restrict__ xn) {
  const int row = blockIdx.x;
  const int tid = threadIdx.x;
  const float4 xv = ((const float4*)(x + (size_t)row * DD))[tid];
  float s = xv.x + xv.y + xv.z + xv.w;
  float q = xv.x*xv.x + xv.y*xv.y + xv.z*xv.z + xv.w*xv.w;
#pragma unroll
  for (int o = 1; o < 64; o <<= 1) { s += __shfl_xor(s, o); q += __shfl_xor(q, o); }
  __shared__ float rs[4], rq[4];
  if ((tid & 63) == 0) { rs[tid >> 6] = s; rq[tid >> 6] = q; }
  __syncthreads();
  s = rs[0] + rs[1] + rs[2] + rs[3];
  q = rq[0] + rq[1] + rq[2] + rq[3];
  const float mean = s * (1.f / DD);
  const float var = q * (1.f / DD) - mean * mean;
  const float rstd = rsqrtf(var + 1e-5f);
  const float4 sv = ((const float4*)sc)[tid];
  const float4 bv = ((const float4*)bi)[tid];
  const u16 o0 = f2b((xv.x - mean) * rstd * sv.x + bv.x);
  const u16 o1 = f2b((xv.y - mean) * rstd * sv.y + bv.y);
  const u16 o2 = f2b((xv.z - mean) * rstd * sv.z + bv.z);
  const u16 o3 = f2b((xv.w - mean) * rstd * sv.w + bv.w);
  uint2 pk;
  pk.x = (unsigned)o0 | ((unsigned)o1 << 16);
  pk.y = (unsigned)o2 | ((unsigned)o3 << 16);
  *(uint2*)(xn + (size_t)row * DD + (tid << 2)) = pk;
}

// ======== 256x128 8-wave GEMM, 16x16x32 MFMA, BK=32, 3-buffer LDS, 2 blocks/CU ========
// (R9 structure - best measured.)  512 threads, 72KB dynamic LDS.
// EPI: 2 = bf16 gelu store, 4 = qkv split (QK rowmajor + V^T), 5 = dual bf16 store
template<int EPI>
__global__ __launch_bounds__(512, 4)
void gemm256t(const u16* __restrict__ A, const u16* __restrict__ Wt,
              const float* __restrict__ bias, const float* __restrict__ bias2,
              float* __restrict__ outf, u16* __restrict__ outb, int K, int N) {
  extern __shared__ u16 lds[];
  const int tid = threadIdx.x;
  const int gx = gridDim.x;
  const int nwg = gx * (int)gridDim.y;
  int lid = (int)blockIdx.y * gx + (int)blockIdx.x;
  lid = (lid & 7) * (nwg >> 3) + (lid >> 3);     // XCD-chunked (nwg % 8 == 0)
  const int m0 = (lid / gx) << 8;
  const int n0 = (lid % gx) << 7;
  const int lane = tid & 63;
  const int wid = tid >> 6;
  const int wm = wid >> 2;          // m-half (128 rows)
  const int wn = wid & 3;           // n-quarter (32 cols)
  const int g = lane >> 4;
  const int lc = lane & 15;
  const int q = tid >> 2;           // staging row 0..127
  const int slot = tid & 3;
  const int scs = (slot ^ ((q >> 1) & 3)) << 3;  // inverse-swizzled source chunk
  const int so = (g ^ ((lc >> 1) & 3)) << 3;     // swizzled read slot

  u16* Ab = lds;            // 3 x [256][32]
  u16* Bbase = lds + 24576; // 3 x [128][32]
  u16 *Ac = Ab, *An = Ab + 8192, *Aw = Ab + 16384;
  u16 *Bc = Bbase, *Bn = Bbase + 4096, *Bw = Bbase + 8192;

  auto stage = [&](int kt, u16* At, u16* Bt) {
    const int kb = (kt << 5) + scs;
    GLD16(A + (size_t)(m0 + q) * K + kb,       At + q*32 + slot*8);
    GLD16(A + (size_t)(m0 + 128 + q) * K + kb, At + (128 + q)*32 + slot*8);
    GLD16(Wt + (size_t)(n0 + q) * K + kb,      Bt + q*32 + slot*8);
  };

  f32x4 acc[8][2];
#pragma unroll
  for (int i = 0; i < 8; ++i)
#pragma unroll
    for (int j = 0; j < 2; ++j)
#pragma unroll
      for (int e = 0; e < 4; ++e) acc[i][j][e] = 0.f;

  const int KT = K >> 5;
  stage(0, Ac, Bc);
  stage(1, An, Bn);

  for (int kt = 0; kt < KT; ++kt) {
    if (kt + 1 < KT) wait_vmcnt<3>();
    else             wait_vmcnt<0>();
    wg_barrier();
    bf16x8 bf0 = *(const bf16x8*)(Bc + (wn*32 + lc)*32 + so);
    bf16x8 bf1 = *(const bf16x8*)(Bc + (wn*32 + 16 + lc)*32 + so);
    bf16x8 af[8];
#pragma unroll
    for (int i = 0; i < 8; ++i)
      af[i] = *(const bf16x8*)(Ac + (wm*128 + i*16 + lc)*32 + so);
    if (kt + 2 < KT) stage(kt + 2, Aw, Bw);
    __builtin_amdgcn_s_setprio(1);
#pragma unroll
    for (int i = 0; i < 8; ++i) {
      acc[i][0] = __builtin_amdgcn_mfma_f32_16x16x32_bf16(af[i], bf0, acc[i][0], 0, 0, 0);
      acc[i][1] = __builtin_amdgcn_mfma_f32_16x16x32_bf16(af[i], bf1, acc[i][1], 0, 0, 0);
    }
    __builtin_amdgcn_s_setprio(0);
    u16* t;
    t = Ac; Ac = An; An = Aw; Aw = t;
    t = Bc; Bc = Bn; Bn = Bw; Bw = t;
  }

#pragma unroll
  for (int mi = 0; mi < 8; ++mi) {
#pragma unroll
    for (int ni = 0; ni < 2; ++ni) {
      const int n = n0 + wn*32 + ni*16 + lc;
      const int mbase = m0 + wm*128 + mi*16 + (g << 2);
      if (EPI == 4) {
        const float bia = bias[n];
        if (n < 2048) {
#pragma unroll
          for (int e = 0; e < 4; ++e)
            outb[(size_t)(mbase + e) * 2048 + n] = f2b(acc[mi][ni][e] + bia);
        } else {
          const int hh = (n - 2048) >> 8, dim = (n - 2048) & 255;
          const int bidx = mbase >> 11, t = mbase & 2047;
          const u16 a0 = f2b(acc[mi][ni][0] + bia);
          const u16 a1 = f2b(acc[mi][ni][1] + bia);
          const u16 a2 = f2b(acc[mi][ni][2] + bia);
          const u16 a3 = f2b(acc[mi][ni][3] + bia);
          uint2 pk;
          pk.x = (unsigned)a0 | ((unsigned)a1 << 16);
          pk.y = (unsigned)a2 | ((unsigned)a3 << 16);
          u16* vtp = (u16*)outf;
          *(uint2*)(vtp + ((size_t)((bidx*4 + hh)*256 + dim)) * 2048 + t) = pk;
        }
      } else if (EPI == 5) {
        const float bia = (n < 1024) ? bias[n] : bias2[n - 1024];
        u16* dst = (n < 1024) ? outb : (u16*)outf;
        const int nn = n & 1023;
#pragma unroll
        for (int e = 0; e < 4; ++e)
          dst[(size_t)(mbase + e) * 1024 + nn] = f2b(acc[mi][ni][e] + bia);
      } else {  // EPI == 2
        const float bia = bias[n];
#pragma unroll
        for (int e = 0; e < 4; ++e) {
          const float v = acc[mi][ni][e] + bia;
          const float zc = fminf(fmaxf(1.5957691216f * (v + 0.044715f*v*v*v), -30.f), 30.f);
          outb[(size_t)(mbase + e) * N + n] = f2b(v / (1.f + __expf(-zc)));
        }
      }
    }
  }
}

// ======== 128x128 4-wave GEMM (N=1024 residual GEMMs), BK=32, 3-buffer, 2 blocks/CU ====
// out = addf + A*Wt^T + bias.  256 threads, 48KB dynamic LDS, grid (8, M/128) = 512 blocks.
__global__ __launch_bounds__(256, 2)
void gemm128t(const u16* __restrict__ A, const u16* __restrict__ Wt,
              const float* __restrict__ bias, const float* __restrict__ addf,
              float* __restrict__ outf, int K, int N) {
  extern __shared__ u16 lds[];
  const int tid = threadIdx.x;
  const int gx = gridDim.x;  // 8
  const int nwg = gx * (int)gridDim.y;
  int lid = (int)blockIdx.y * gx + (int)blockIdx.x;
  lid = (lid & 7) * (nwg >> 3) + (lid >> 3);     // XCD-chunked
  const int m0 = (lid / gx) << 7;
  const int n0 = (lid % gx) << 7;
  const int lane = tid & 63;
  const int wid = tid >> 6;
  const int wm = wid >> 1;          // 0..1 -> 64-row band
  const int wn = wid & 1;           // 0..1 -> 64-col band
  const int g = lane >> 4;
  const int lc = lane & 15;
  const int q = tid >> 2;           // staging row 0..63
  const int slot = tid & 3;
  const int scs = (slot ^ ((q >> 1) & 3)) << 3;
  const int so = (g ^ ((lc >> 1) & 3)) << 3;

  u16* Ab = lds;            // 3 x [128][32] = 24 KB
  u16* Bbase = lds + 12288; // 3 x [128][32] = 24 KB
  u16 *Ac = Ab, *An = Ab + 4096, *Aw = Ab + 8192;
  u16 *Bc = Bbase, *Bn = Bbase + 4096, *Bw = Bbase + 8192;

  auto stage = [&](int kt, u16* At, u16* Bt) {
    const int kb = (kt << 5) + scs;
    GLD16(A + (size_t)(m0 + q) * K + kb,       At + q*32 + slot*8);
    GLD16(A + (size_t)(m0 + 64 + q) * K + kb,  At + (64 + q)*32 + slot*8);
    GLD16(Wt + (size_t)(n0 + q) * K + kb,      Bt + q*32 + slot*8);
    GLD16(Wt + (size_t)(n0 + 64 + q) * K + kb, Bt + (64 + q)*32 + slot*8);
  };

  f32x4 acc[4][4];
#pragma unroll
  for (int i = 0; i < 4; ++i)
#pragma unroll
    for (int j = 0; j < 4; ++j)
#pragma unroll
      for (int e = 0; e < 4; ++e) acc[i][j][e] = 0.f;

  const int KT = K >> 5;
  stage(0, Ac, Bc);
  stage(1, An, Bn);

  for (int kt = 0; kt < KT; ++kt) {
    if (kt + 1 < KT) wait_vmcnt<4>();
    else             wait_vmcnt<0>();
    wg_barrier();
    bf16x8 af[4], bfr[4];
#pragma unroll
    for (int i = 0; i < 4; ++i)
      af[i] = *(const bf16x8*)(Ac + (wm*64 + i*16 + lc)*32 + so);
#pragma unroll
    for (int j = 0; j < 4; ++j)
      bfr[j] = *(const bf16x8*)(Bc + (wn*64 + j*16 + lc)*32 + so);
    if (kt + 2 < KT) stage(kt + 2, Aw, Bw);
    __builtin_amdgcn_s_setprio(1);
#pragma unroll
    for (int i = 0; i < 4; ++i)
#pragma unroll
      for (int j = 0; j < 4; ++j)
        acc[i][j] = __builtin_amdgcn_mfma_f32_16x16x32_bf16(af[i], bfr[j], acc[i][j], 0, 0, 0);
    __builtin_amdgcn_s_setprio(0);
    u16* t;
    t = Ac; Ac = An; An = Aw; Aw = t;
    t = Bc; Bc = Bn; Bn = Bw; Bw = t;
  }

#pragma unroll
  for (int mi = 0; mi < 4; ++mi) {
#pragma unroll
    for (int ni = 0; ni < 4; ++ni) {
      const int n = n0 + wn*64 + ni*16 + lc;
      const int mbase = m0 + wm*64 + mi*16 + (g << 2);
      const float bia = bias[n];
#pragma unroll
      for (int e = 0; e < 4; ++e) {
        const size_t idx = (size_t)(mbase + e) * N + n;
        outf[idx] = addf[idx] + acc[mi][ni][e] + bia;
      }
    }
  }
}

// ---------------- RG-LRU chunked scan (bf16 z,u inputs): h_t = g*h_{t-1} + (1-g)*u ----
__global__ __launch_bounds__(256)
void scan1_k(const u16* __restrict__ zpre, const u16* __restrict__ u,
             float* __restrict__ aggA, float* __restrict__ aggB) {
  const int d = blockIdx.x * 256 + threadIdx.x;
  const int c = blockIdx.y, b = blockIdx.z;
  const size_t base = ((size_t)b * TT + (size_t)c * CHUNK) * DD + d;
  float a = 1.f, acc = 0.f;
  for (int t = 0; t < CHUNK; ++t) {
    const float gl = 1.f / (1.f + __expf(-b2f(zpre[base + (size_t)t * DD])));
    const float ul = b2f(u[base + (size_t)t * DD]);
    acc = gl * acc + (1.f - gl) * ul;
    a *= gl;
  }
  const size_t o = ((size_t)b * NCHUNK + c) * DD + d;
  aggA[o] = a; aggB[o] = acc;
}

__global__ __launch_bounds__(256)
void scan2_k(const float* __restrict__ aggA, const float* __restrict__ aggB,
             float* __restrict__ carry) {
  const int idx = blockIdx.x * 256 + threadIdx.x;  // b*DD + d
  const int b = idx >> 10, d = idx & 1023;
  float h = 0.f;
  for (int c = 0; c < NCHUNK; ++c) {
    const size_t o = ((size_t)b * NCHUNK + c) * DD + d;
    carry[o] = h;
    h = aggA[o] * h + aggB[o];
  }
}

__global__ __launch_bounds__(256)
void scan3_k(const u16* __restrict__ zpre, const u16* __restrict__ u,
             const float* __restrict__ carry, u16* __restrict__ hout) {
  const int d = blockIdx.x * 256 + threadIdx.x;
  const int c = blockIdx.y, b = blockIdx.z;
  const size_t base = ((size_t)b * TT + (size_t)c * CHUNK) * DD + d;
  float h = carry[((size_t)b * NCHUNK + c) * DD + d];
  for (int t = 0; t < CHUNK; ++t) {
    const float gl = 1.f / (1.f + __expf(-b2f(zpre[base + (size_t)t * DD])));
    const float ul = b2f(u[base + (size_t)t * DD]);
    h = gl * h + (1.f - gl) * ul;
    hout[base + (size_t)t * DD] = f2b(h);
  }
}

// ---------------- MFMA local-window attention ----------------
__global__ __launch_bounds__(256)
void attn_mfma(const u16* __restrict__ qkb, const u16* __restrict__ vt,
               u16* __restrict__ y) {
  __shared__ u16 kv[16384];
  __shared__ u16 pb[4][16][200];
  const int tid = threadIdx.x;
  const int lane = tid & 63;
  const int wid = tid >> 6;
  const int g = lane >> 4;
  const int lc = lane & 15;
  const int t0 = blockIdx.x << 6;
  const int bh = blockIdx.y;
  const int bT = (bh >> 2) * TT;
  const int h = bh & 3;

  bf16x8 afq[8];
  {
    const u16* qg = qkb + (size_t)(bT + t0 + wid*16 + lc) * 2048 + h*256 + g*8;
#pragma unroll
    for (int ks = 0; ks < 8; ++ks)
      afq[ks] = __builtin_bit_cast(bf16x8, *(const uint4*)(qg + ks*32));
  }

  f32x4 sc[12];
#pragma unroll
  for (int f = 0; f < 12; ++f)
#pragma unroll
    for (int e = 0; e < 4; ++e) sc[f][e] = 0.f;

  const int koff = 1024 + h*256;
#pragma unroll
  for (int c = 0; c < 3; ++c) {
    const int j0 = t0 + (c - 2) * 64;
    if (j0 < 0) {
#pragma unroll
      for (int nt = 0; nt < 4; ++nt)
#pragma unroll
        for (int e = 0; e < 4; ++e) sc[c*4+nt][e] = -1e30f;
      continue;
    }
    __syncthreads();
    {
      const u16* kg = qkb + (size_t)(bT + j0) * 2048 + koff;
#pragma unroll
      for (int i = 0; i < 8; ++i) {
        const int o16 = i*256 + tid;
        const int slab = o16 >> 8, key = (o16 >> 2) & 63, ds = o16 & 3;
        GLD16(kg + (size_t)key*2048 + slab*32 + ds*8, kv + o16*8);
      }
    }
    __syncthreads();
#pragma unroll
    for (int nt = 0; nt < 4; ++nt) {
      f32x4 s = sc[c*4+nt];
#pragma unroll
      for (int ks = 0; ks < 8; ++ks) {
        const bf16x8 kb = *(const bf16x8*)(kv + ks*2048 + (nt*16 + lc)*32 + g*8);
        s = __builtin_amdgcn_mfma_f32_16x16x32_bf16(afq[ks], kb, s, 0, 0, 0);
      }
      sc[c*4+nt] = s;
    }
#pragma unroll
    for (int nt = 0; nt < 4; ++nt)
#pragma unroll
      for (int e = 0; e < 4; ++e) {
        const int tl = wid*16 + g*4 + e;
        const int jl = nt*16 + lc;
        const bool ok = (c == 1) || (c == 2 ? (jl <= tl) : (jl >= tl + 1));
        sc[c*4+nt][e] = ok ? sc[c*4+nt][e] * 0.0625f : -1e30f;
      }
  }

#pragma unroll
  for (int e = 0; e < 4; ++e) {
    float m = -1e30f;
#pragma unroll
    for (int f = 0; f < 12; ++f) m = fmaxf(m, sc[f][e]);
    m = fmaxf(m, __shfl_xor(m, 1)); m = fmaxf(m, __shfl_xor(m, 2));
    m = fmaxf(m, __shfl_xor(m, 4)); m = fmaxf(m, __shfl_xor(m, 8));
    float s = 0.f;
#pragma unroll
    for (int f = 0; f < 12; ++f) { const float p = __expf(sc[f][e] - m); sc[f][e] = p; s += p; }
    s += __shfl_xor(s, 1); s += __shfl_xor(s, 2);
    s += __shfl_xor(s, 4); s += __shfl_xor(s, 8);
    const float is = 1.f / s;
#pragma unroll
    for (int f = 0; f < 12; ++f) sc[f][e] *= is;
  }
#pragma unroll
  for (int c = 0; c < 3; ++c)
#pragma unroll
    for (int nt = 0; nt < 4; ++nt)
#pragma unroll
      for (int e = 0; e < 4; ++e)
        pb[wid][g*4 + e][c*64 + nt*16 + lc] = f2b(sc[c*4+nt][e]);

  f32x4 acc[16];
#pragma unroll
  for (int nt = 0; nt < 16; ++nt)
#pragma unroll
    for (int e = 0; e < 4; ++e) acc[nt][e] = 0.f;

  const u16* vg = vt + (size_t)bh * 256 * 2048;
#pragma unroll
  for (int c = 0; c < 3; ++c) {
    const int j0 = t0 + (c - 2) * 64;
    if (j0 < 0) continue;
    __syncthreads();
#pragma unroll
    for (int i = 0; i < 8; ++i) {
      const int o16 = i*256 + tid;
      const int dim = o16 >> 3, slot = o16 & 7;
      const int ss = slot ^ (dim & 7);
      GLD16(vg + (size_t)dim*2048 + j0 + ss*8, kv + o16*8);
    }
    __syncthreads();
#pragma unroll
    for (int ks = 0; ks < 2; ++ks) {
      const bf16x8 pa = *(const bf16x8*)&pb[wid][lc][(c*2 + ks)*32 + g*8];
#pragma unroll
      for (int nt = 0; nt < 16; ++nt) {
        const int dim = nt*16 + lc;
        int boff = dim*128 + ks*64 + g*16;
        boff ^= (dim & 7) << 4;
        const bf16x8 vb = *(const bf16x8*)((const char*)kv + boff);
        acc[nt] = __builtin_amdgcn_mfma_f32_16x16x32_bf16(pa, vb, acc[nt], 0, 0, 0);
      }
    }
  }

#pragma unroll
  for (int nt = 0; nt < 16; ++nt)
#pragma unroll
    for (int e = 0; e < 4; ++e) {
      const int tok = bT + t0 + wid*16 + g*4 + e;
      y[(size_t)tok * 1024 + h*256 + nt*16 + lc] = f2b(acc[nt][e]);
    }
}

// ---------------- host orchestration ----------------
extern "C" void kernel_launch(void* const* d_in, const int* in_sizes, int n_in,
                              void* d_out, int out_size, void* d_ws, size_t ws_size,
                              hipStream_t stream) {
  const float* x_in      = (const float*)d_in[0];
  const float* ln1_s     = (const float*)d_in[1];
  const float* ln1_b     = (const float*)d_in[2];
  const float* ln2_s     = (const float*)d_in[3];
  const float* ln2_b     = (const float*)d_in[4];
  const float* ln3_s     = (const float*)d_in[5];
  const float* ln3_b     = (const float*)d_in[6];
  const float* rg_in_w   = (const float*)d_in[7];
  const float* rg_in_b   = (const float*)d_in[8];
  const float* rg_gate_w = (const float*)d_in[9];
  const float* rg_gate_b = (const float*)d_in[10];
  const float* rg_out_w  = (const float*)d_in[11];
  const float* rg_out_b  = (const float*)d_in[12];
  const float* qkv_w     = (const float*)d_in[13];
  const float* qkv_b     = (const float*)d_in[14];
  const float* attn_out_w= (const float*)d_in[15];
  const float* attn_out_b= (const float*)d_in[16];
  const float* mlp_w1    = (const float*)d_in[17];
  const float* mlp_b1    = (const float*)d_in[18];
  const float* mlp_w2    = (const float*)d_in[19];
  const float* mlp_b2    = (const float*)d_in[20];

  hipFuncSetAttribute((const void*)&gemm256t<5>, hipFuncAttributeMaxDynamicSharedMemorySize, 73728);
  hipFuncSetAttribute((const void*)&gemm256t<4>, hipFuncAttributeMaxDynamicSharedMemorySize, 73728);
  hipFuncSetAttribute((const void*)&gemm256t<2>, hipFuncAttributeMaxDynamicSharedMemorySize, 73728);
  hipFuncSetAttribute((const void*)&gemm128t,    hipFuncAttributeMaxDynamicSharedMemorySize, 49152);

  float* x = (float*)d_out;
  char* ws = (char*)d_ws;
  u16*  wt     = (u16*)ws;                          // 62,914,560 B (bf16 transposed weights)
  u16*  xn     = (u16*)(ws + 62914560);             // 16,777,216 B
  char* bigS   = ws + 62914560 + 16777216;          // 67,108,864 B
  char* smallS = bigS + 67108864;                   // 16,777,216 B
  float* aggA  = (float*)(smallS + 16777216);
  float* aggB  = aggA + (size_t)BB * NCHUNK * DD;
  float* carry = aggB + (size_t)BB * NCHUNK * DD;

  u16* ubuf = (u16*)bigS;                           // RG phase (bf16)
  u16* zbuf = (u16*)(bigS + 33554432);              // pre-sigmoid gate, bf16
  u16* qkb  = (u16*)bigS;                           // attn phase: [8192][2048] QK
  u16* vtb  = (u16*)(bigS + 33554432);              // attn phase: V transposed, 16MB
  u16* hid  = (u16*)bigS;                           // MLP phase
  u16* hbuf = (u16*)smallS;
  u16* ybuf = (u16*)smallS;

  const size_t LW = 15728640;
  const dim3 tb(32, 8);
  // batched over both layers via blockIdx.z
  transpose_cvt<<<dim3(32, 32, 2),  tb, 0, stream>>>(rg_in_w,    wt + 0,        DD, DD,   DD*DD,   LW);
  transpose_cvt<<<dim3(32, 32, 2),  tb, 0, stream>>>(rg_gate_w,  wt + 1048576,  DD, DD,   DD*DD,   LW);
  transpose_cvt<<<dim3(32, 32, 2),  tb, 0, stream>>>(rg_out_w,   wt + 2097152,  DD, DD,   DD*DD,   LW);
  transpose_cvt<<<dim3(96, 32, 2),  tb, 0, stream>>>(qkv_w,      wt + 3145728,  DD, 3072, DD*3072, LW);
  transpose_cvt<<<dim3(32, 32, 2),  tb, 0, stream>>>(attn_out_w, wt + 6291456,  DD, DD,   DD*DD,   LW);
  transpose_cvt<<<dim3(128, 32, 2), tb, 0, stream>>>(mlp_w1,     wt + 7340032,  DD, 4096, DD*4096, LW);
  transpose_cvt<<<dim3(32, 128, 2), tb, 0, stream>>>(mlp_w2,     wt + 11534336, 4096, DD, 4096*DD, LW);

  for (int l = 0; l < NLAYER; ++l) {
    u16* base = wt + (size_t)l * LW;
    const float* xsrc = (l == 0) ? x_in : x;   // residual source before rg_out writes x
    // ---- RG-LRU block (rg_in + rg_gate fused; u and pre-sigmoid z stored bf16)
    ln_k<<<MM, 256, 0, stream>>>(xsrc, ln1_s + l*DD, ln1_b + l*DD, xn);
    gemm256t<5><<<dim3(16, 32), 512, 73728, stream>>>(xn, base + 0, rg_in_b + l*DD, rg_gate_b + l*DD,
                                                      (float*)zbuf, ubuf, DD, 2048);
    scan1_k<<<dim3(4, NCHUNK, BB), 256, 0, stream>>>(zbuf, ubuf, aggA, aggB);
    scan2_k<<<16, 256, 0, stream>>>(aggA, aggB, carry);
    scan3_k<<<dim3(4, NCHUNK, BB), 256, 0, stream>>>(zbuf, ubuf, carry, hbuf);
    gemm128t<<<dim3(8, 64), 256, 49152, stream>>>(hbuf, base + 2097152, rg_out_b + l*DD,
                                                  xsrc, x, DD, 1024);
    // ---- local attention block
    ln_k<<<MM, 256, 0, stream>>>(x, ln2_s + l*DD, ln2_b + l*DD, xn);
    gemm256t<4><<<dim3(24, 32), 512, 73728, stream>>>(xn, base + 3145728, qkv_b + l*3072, nullptr,
                                                      (float*)vtb, qkb, DD, 3072);
    attn_mfma<<<dim3(TT/64, BB*HH), 256, 0, stream>>>(qkb, vtb, ybuf);
    gemm128t<<<dim3(8, 64), 256, 49152, stream>>>(ybuf, base + 6291456, attn_out_b + l*DD,
                                                  x, x, DD, 1024);
    // ---- MLP block
    ln_k<<<MM, 256, 0, stream>>>(x, ln3_s + l*DD, ln3_b + l*DD, xn);
    gemm256t<2><<<dim3(32, 32), 512, 73728, stream>>>(xn, base + 7340032, mlp_b1 + l*4096, nullptr,
                                                      nullptr, hid, DD, 4096);
    gemm128t<<<dim3(8, 64), 256, 49152, stream>>>(hid, base + 11534336, mlp_b2 + l*DD,
                                                  x, x, 4096, 1024);
  }
}